// Round 9
// baseline (819.615 us; speedup 1.0000x reference)
//
#include <hip/hip_runtime.h>
#include <math.h>

// KME attention. B=2 S=1024 M=8 D=64 H=8 NF=64
// Round 9: k_flash -> pipelined producer/consumer. 640 threads = 10 waves:
// 2 producers (scores/softmax/repack, run ONE CHUNK AHEAD) + 8 consumers
// (rescale+PV, 128 cols each). P double-buffered in LDS; one barrier/phase;
// K DMA depth-2 with per-wave counted vmcnt. Other kernels unchanged.
//
// ws layout (bytes), 80 MiB total:
//   qrh  @ 0MB   4MB  ushort [bh][s][128]          (natural)
//   qrl  @ 4MB   4MB
//   krh  @ 8MB   4MB  swizzled-chunk layout [bh][ch=32][8192B]
//   krl  @12MB   4MB
//   vthi @16MB  16MB  [bh][ch=32][half=2][c=512][32B], inner=c*32+part2*16
//   vtlo @32MB  16MB
//   ao   @48MB  32MB  f32 [b][s][m][512]

#define B_ 2
#define S_ 1024
#define H_ 8

typedef __attribute__((ext_vector_type(8))) short short8;
typedef __attribute__((ext_vector_type(16))) float f32x16;
union U4B8 { uint4 u; short8 v; };

#define SBAR() __builtin_amdgcn_s_barrier()
#define SCHED0() __builtin_amdgcn_sched_barrier(0)
#define MEMFENCE() asm volatile("" ::: "memory")

__device__ inline unsigned cvt_pk_bf16(float a, float b) {
  unsigned r;
  asm("v_cvt_pk_bf16_f32 %0, %1, %2" : "=v"(r) : "v"(a), "v"(b));
  return r;
}
__device__ inline void bsplit(float v, unsigned short &h, unsigned short &l) {
  unsigned hw = cvt_pk_bf16(v, 0.f);
  float hf = __uint_as_float(hw << 16);
  unsigned lw = cvt_pk_bf16(v - hf, 0.f);
  h = (unsigned short)hw; l = (unsigned short)lw;
}
__device__ inline void split8(const float* v, unsigned* hw, unsigned* lw) {
#pragma unroll
  for (int p = 0; p < 4; ++p) {
    const float a = v[2 * p], b = v[2 * p + 1];
    const unsigned h = cvt_pk_bf16(a, b);
    const float ra = a - __uint_as_float(h << 16);
    const float rb = b - __uint_as_float(h & 0xffff0000u);
    hw[p] = h;
    lw[p] = cvt_pk_bf16(ra, rb);
  }
}

// ---------------------------------------------------------------------------
// MFMA projection + RoPE + RFF encode (unchanged from R8).
// ---------------------------------------------------------------------------
__global__ __launch_bounds__(256, 2) void k_proj_rff(
    const float* __restrict__ q_atoms, const float* __restrict__ q_logw,
    const float* __restrict__ k_atoms, const float* __restrict__ k_logw,
    const float* __restrict__ Wq, const float* __restrict__ Wk,
    const float* __restrict__ freqb, const float* __restrict__ logbw,
    const float* __restrict__ cosT, const float* __restrict__ sinT,
    char* __restrict__ qoh, char* __restrict__ qol,
    char* __restrict__ koh, char* __restrict__ kol)
{
  const int sblk = blockIdx.x * 64;
  const int h = blockIdx.y, z = blockIdx.z;
  const int qk = z >> 1, b = z & 1;
  const float* atoms = qk ? k_atoms : q_atoms;
  const float* logw  = qk ? k_logw : q_logw;
  const float* W     = qk ? Wk : Wq;
  char* oh = qk ? koh : qoh;
  char* ol = qk ? kol : qol;

  const int tid = threadIdx.x;
  const int w = tid >> 6, lane = tid & 63;
  const int lrow = lane & 31, lhi = lane >> 5;

  __shared__ float Cs[64 * 65];
  __shared__ float Sn[64 * 65];
  __shared__ float Wm[64 * 8];
  __shared__ __align__(16) char FT[2][4][2][1024];
  __shared__ __align__(16) char Ob[4][2][1024];

  for (int i = tid; i < 4096; i += 256) {
    const int sl = i >> 6, d = i & 63;
    Cs[sl * 65 + d] = cosT[(sblk + sl) * 64 + d];
    Sn[sl * 65 + d] = sinT[(sblk + sl) * 64 + d];
  }
  if (tid < 64) {
    const float* lw = logw + (size_t)(b * S_ + sblk + tid) * 8;
    float mx = lw[0];
    for (int m = 1; m < 8; ++m) mx = fmaxf(mx, lw[m]);
    float e[8], sum = 0.f;
    for (int m = 0; m < 8; ++m) { e[m] = __expf(lw[m] - mx); sum += e[m]; }
    const float inv = 1.0f / sum;
    for (int m = 0; m < 8; ++m) Wm[tid * 8 + m] = e[m] * inv;
  }
  const float fscale = __expf(-logbw[h]);
  {
    const int ftw = w & 1;
#pragma unroll
    for (int kk = 0; kk < 2; ++kk) {
      const int ks2 = (w >> 1) + kk * 2;
      float v[8];
#pragma unroll
      for (int j = 0; j < 8; ++j)
        v[j] = freqb[h * 4096 + (ks2 * 16 + lhi * 8 + j) * 64 + ftw * 32 + lrow] * fscale;
      unsigned hw[4], lw2[4];
      split8(v, hw, lw2);
      *(uint4*)&FT[ftw][ks2][0][lane * 16] = make_uint4(hw[0], hw[1], hw[2], hw[3]);
      *(uint4*)&FT[ftw][ks2][1][lane * 16] = make_uint4(lw2[0], lw2[1], lw2[2], lw2[3]);
    }
  }
  unsigned wAh[2][4][4], wAl[2][4][4];
#pragma unroll
  for (int wt = 0; wt < 2; ++wt)
#pragma unroll
    for (int ks = 0; ks < 4; ++ks) {
      const float* wp = W + h * 4096 + (wt * 32 + lrow) * 64 + ks * 16 + lhi * 8;
      float v[8];
      const float4 a = *(const float4*)wp;
      const float4 b2 = *(const float4*)(wp + 4);
      v[0] = a.x; v[1] = a.y; v[2] = a.z; v[3] = a.w;
      v[4] = b2.x; v[5] = b2.y; v[6] = b2.z; v[7] = b2.w;
      split8(v, wAh[wt][ks], wAl[wt][ks]);
    }
  __syncthreads();

  const int bh = b * H_ + h;
  char* obh = &Ob[w][0][0];
  char* obl = &Ob[w][1][0];

  for (int it = 0; it < 4; ++it) {
    const int t = w * 4 + it;
    const float* arow = atoms + ((size_t)(b * S_ + sblk) * 8 + t * 32 + lrow) * 64;
    unsigned aBh[4][4], aBl[4][4];
#pragma unroll
    for (int ks = 0; ks < 4; ++ks) {
      float v[8];
      const float4 a = *(const float4*)(arow + ks * 16 + lhi * 8);
      const float4 b2 = *(const float4*)(arow + ks * 16 + lhi * 8 + 4);
      v[0] = a.x; v[1] = a.y; v[2] = a.z; v[3] = a.w;
      v[4] = b2.x; v[5] = b2.y; v[6] = b2.z; v[7] = b2.w;
      split8(v, aBh[ks], aBl[ks]);
    }

    f32x16 y0, y1;
#pragma unroll
    for (int r = 0; r < 16; ++r) { y0[r] = 0.f; y1[r] = 0.f; }
    __builtin_amdgcn_s_setprio(1);
#pragma unroll
    for (int ks = 0; ks < 4; ++ks) {
      U4B8 a0h, a0l, a1h, a1l, bh2, bl2;
      a0h.u = make_uint4(wAh[0][ks][0], wAh[0][ks][1], wAh[0][ks][2], wAh[0][ks][3]);
      a0l.u = make_uint4(wAl[0][ks][0], wAl[0][ks][1], wAl[0][ks][2], wAl[0][ks][3]);
      a1h.u = make_uint4(wAh[1][ks][0], wAh[1][ks][1], wAh[1][ks][2], wAh[1][ks][3]);
      a1l.u = make_uint4(wAl[1][ks][0], wAl[1][ks][1], wAl[1][ks][2], wAl[1][ks][3]);
      bh2.u = make_uint4(aBh[ks][0], aBh[ks][1], aBh[ks][2], aBh[ks][3]);
      bl2.u = make_uint4(aBl[ks][0], aBl[ks][1], aBl[ks][2], aBl[ks][3]);
      y0 = __builtin_amdgcn_mfma_f32_32x32x16_bf16(a0h.v, bh2.v, y0, 0, 0, 0);
      y1 = __builtin_amdgcn_mfma_f32_32x32x16_bf16(a1h.v, bh2.v, y1, 0, 0, 0);
      y0 = __builtin_amdgcn_mfma_f32_32x32x16_bf16(a0l.v, bh2.v, y0, 0, 0, 0);
      y1 = __builtin_amdgcn_mfma_f32_32x32x16_bf16(a1l.v, bh2.v, y1, 0, 0, 0);
      y0 = __builtin_amdgcn_mfma_f32_32x32x16_bf16(a0h.v, bl2.v, y0, 0, 0, 0);
      y1 = __builtin_amdgcn_mfma_f32_32x32x16_bf16(a1h.v, bl2.v, y1, 0, 0, 0);
    }
    __builtin_amdgcn_s_setprio(0);

    const int sloc = t * 4 + (lrow >> 3);
    const int sld = sloc * 65;
    float yr0[16], yr1[16];
#pragma unroll
    for (int r = 0; r < 16; ++r) {
      const int dd = (r & 3) + 8 * (r >> 2) + 4 * lhi;
      const float c0 = Cs[sld + dd],      s0v = Sn[sld + dd];
      const float c1 = Cs[sld + dd + 32], s1v = Sn[sld + dd + 32];
      yr0[r] = y0[r] * c0 - y1[r] * s0v;
      yr1[r] = y1[r] * c1 + y0[r] * s1v;
    }

    unsigned Bh[4][4], Bl[4][4];
    {
      const float* src[2] = { yr0, yr1 };
#pragma unroll
      for (int st = 0; st < 2; ++st) {
#pragma unroll
        for (int half = 0; half < 2; ++half) {
          const int ks2 = st * 2 + half;
          const float* q = src[st] + half * 8;
          unsigned ph[4], pl[4];
          split8(q, ph, pl);
          {
            const unsigned t0 = lhi ? ph[0] : ph[2];
            const unsigned r0 = (unsigned)__shfl_xor((int)t0, 32);
            const unsigned t1 = lhi ? ph[1] : ph[3];
            const unsigned r1 = (unsigned)__shfl_xor((int)t1, 32);
            Bh[ks2][0] = lhi ? r0 : ph[0];
            Bh[ks2][1] = lhi ? r1 : ph[1];
            Bh[ks2][2] = lhi ? ph[2] : r0;
            Bh[ks2][3] = lhi ? ph[3] : r1;
          }
          {
            const unsigned t0 = lhi ? pl[0] : pl[2];
            const unsigned r0 = (unsigned)__shfl_xor((int)t0, 32);
            const unsigned t1 = lhi ? pl[1] : pl[3];
            const unsigned r1 = (unsigned)__shfl_xor((int)t1, 32);
            Bl[ks2][0] = lhi ? r0 : pl[0];
            Bl[ks2][1] = lhi ? r1 : pl[1];
            Bl[ks2][2] = lhi ? pl[2] : r0;
            Bl[ks2][3] = lhi ? pl[3] : r1;
          }
        }
      }
    }

    f32x16 d0, d1;
#pragma unroll
    for (int r = 0; r < 16; ++r) { d0[r] = 0.f; d1[r] = 0.f; }
    __builtin_amdgcn_s_setprio(1);
#pragma unroll
    for (int ks2 = 0; ks2 < 4; ++ks2) {
      U4B8 a0h, a0l, a1h, a1l, bh2, bl2;
      a0h.u = *(const uint4*)&FT[0][ks2][0][lane * 16];
      a0l.u = *(const uint4*)&FT[0][ks2][1][lane * 16];
      a1h.u = *(const uint4*)&FT[1][ks2][0][lane * 16];
      a1l.u = *(const uint4*)&FT[1][ks2][1][lane * 16];
      bh2.u = make_uint4(Bh[ks2][0], Bh[ks2][1], Bh[ks2][2], Bh[ks2][3]);
      bl2.u = make_uint4(Bl[ks2][0], Bl[ks2][1], Bl[ks2][2], Bl[ks2][3]);
      d0 = __builtin_amdgcn_mfma_f32_32x32x16_bf16(a0h.v, bh2.v, d0, 0, 0, 0);
      d1 = __builtin_amdgcn_mfma_f32_32x32x16_bf16(a1h.v, bh2.v, d1, 0, 0, 0);
      d0 = __builtin_amdgcn_mfma_f32_32x32x16_bf16(a0l.v, bh2.v, d0, 0, 0, 0);
      d1 = __builtin_amdgcn_mfma_f32_32x32x16_bf16(a1l.v, bh2.v, d1, 0, 0, 0);
      d0 = __builtin_amdgcn_mfma_f32_32x32x16_bf16(a0h.v, bl2.v, d0, 0, 0, 0);
      d1 = __builtin_amdgcn_mfma_f32_32x32x16_bf16(a1h.v, bl2.v, d1, 0, 0, 0);
    }
    __builtin_amdgcn_s_setprio(0);

    const float wt = Wm[sloc * 8 + (lrow & 7)];
    float oc[32], os[32];
#pragma unroll
    for (int r = 0; r < 32; ++r) {
      const float pr = (r < 16) ? d0[r] : d1[r - 16];
      float sv, cv;
      __sincosf(pr, &sv, &cv);
      oc[r] = wt * cv;
      os[r] = wt * sv;
    }
#pragma unroll
    for (int r = 0; r < 32; ++r) {
      oc[r] += __shfl_xor(oc[r], 1); os[r] += __shfl_xor(os[r], 1);
      oc[r] += __shfl_xor(oc[r], 2); os[r] += __shfl_xor(os[r], 2);
      oc[r] += __shfl_xor(oc[r], 4); os[r] += __shfl_xor(os[r], 4);
    }

    const int m = lrow & 7, srel = lrow >> 3;
#pragma unroll
    for (int rr2 = 0; rr2 < 4; ++rr2) {
      const int r = m * 4 + rr2;
      const int f = (r & 3) + 8 * ((r >> 2) & 3) + 4 * lhi + ((r >> 4) << 5);
      unsigned short hh, ll;
      bsplit(oc[r] * 0.125f, hh, ll);
      *(unsigned short*)(obh + srel * 256 + f * 2) = hh;
      *(unsigned short*)(obl + srel * 256 + f * 2) = ll;
      bsplit(os[r] * 0.125f, hh, ll);
      *(unsigned short*)(obh + srel * 256 + 128 + f * 2) = hh;
      *(unsigned short*)(obl + srel * 256 + 128 + f * 2) = ll;
    }
    const uint4 vh = *(const uint4*)(obh + lane * 16);
    const uint4 vl = *(const uint4*)(obl + lane * 16);
    const int srow = sblk + t * 4 + (lane >> 4);
    if (!qk) {
      const size_t off = ((size_t)bh * S_ + srow) * 256 + (lane & 15) * 16;
      *(uint4*)(oh + off) = vh;
      *(uint4*)(ol + off) = vl;
    } else {
      const int klr = srow & 31, ch = srow >> 5;
      const unsigned inner = (unsigned)(((klr << 8) + (lane & 15) * 16) ^ ((klr & 7) << 4));
      const size_t off = (size_t)bh * 262144 + (size_t)ch * 8192 + inner;
      *(uint4*)(oh + off) = vh;
      *(uint4*)(ol + off) = vl;
    }
  }
}

// ---------------------------------------------------------------------------
// V projection (unchanged).
// ---------------------------------------------------------------------------
__global__ __launch_bounds__(256) void k_proj_v(
    const float* __restrict__ atoms, const float* __restrict__ W,
    char* __restrict__ vthi, char* __restrict__ vtlo)
{
  const int s0 = blockIdx.x * 8;
  const int h  = blockIdx.y;
  const int b  = blockIdx.z;
  const int tid = threadIdx.x;
  const int w = tid >> 6, lane = tid & 63;

  __shared__ __align__(16) float Wt[64 * 65];
  __shared__ __align__(16) float As[8 * 8 * 64];
  __shared__ __align__(16) float T[8 * 517];

  for (int i = tid; i < 4096; i += 256) {
    const int dd = i >> 6, d = i & 63;
    Wt[d * 65 + dd] = W[h * 4096 + i];
  }
  for (int i = tid; i < 4096; i += 256)
    As[i] = atoms[(size_t)(b * S_ + s0) * 512 + i];
  __syncthreads();

  float acc[16];
#pragma unroll
  for (int i = 0; i < 16; ++i) acc[i] = 0.f;
#pragma unroll
  for (int d4 = 0; d4 < 16; ++d4) {
    const float w0 = Wt[(4 * d4 + 0) * 65 + lane];
    const float w1 = Wt[(4 * d4 + 1) * 65 + lane];
    const float w2 = Wt[(4 * d4 + 2) * 65 + lane];
    const float w3 = Wt[(4 * d4 + 3) * 65 + lane];
#pragma unroll
    for (int smi = 0; smi < 16; ++smi) {
      const float4 a = *(const float4*)&As[(w * 16 + smi) * 64 + 4 * d4];
      acc[smi] = fmaf(a.x, w0, fmaf(a.y, w1, fmaf(a.z, w2, fmaf(a.w, w3, acc[smi]))));
    }
  }
#pragma unroll
  for (int smi = 0; smi < 16; ++smi)
    T[(w * 2 + (smi >> 3)) * 517 + (smi & 7) * 64 + lane] = acc[smi];
  __syncthreads();

  const int bh = b * H_ + h;
  const int ch = s0 >> 5, half = (s0 >> 4) & 1, part2 = (s0 >> 3) & 1;
  const size_t base = (size_t)bh * 1048576 + (size_t)ch * 32768 + half * 16384;
#pragma unroll
  for (int j = 0; j < 2; ++j) {
    const int c = tid + j * 256;
    float v[8];
#pragma unroll
    for (int s = 0; s < 8; ++s) v[s] = T[s * 517 + c];
    unsigned hw[4], lw[4];
#pragma unroll
    for (int p = 0; p < 4; ++p) {
      const float a = v[2 * p], bb = v[2 * p + 1];
      const unsigned hword = cvt_pk_bf16(a, bb);
      const float ra = a - __uint_as_float(hword << 16);
      const float rb = bb - __uint_as_float(hword & 0xffff0000u);
      hw[p] = hword;
      lw[p] = cvt_pk_bf16(ra, rb);
    }
    const unsigned inner = (unsigned)(c * 32 + part2 * 16);
    *(uint4*)(vthi + base + inner) = make_uint4(hw[0], hw[1], hw[2], hw[3]);
    *(uint4*)(vtlo + base + inner) = make_uint4(lw[0], lw[1], lw[2], lw[3]);
  }
}

// ---------------------------------------------------------------------------
// Pipelined producer/consumer MFMA flash attention.
// 640 threads = 10 waves. Producers w=0 (qt0), w=5 (qt1): scores(ch+1) while
// consumers (w in {1,2,3,4}=qt0, {6,7,8,9}=qt1; 128 cols each) PV(ch).
// P double-buffered in LDS; one barrier per phase; K DMA depth 2.
// ---------------------------------------------------------------------------
__global__ __launch_bounds__(640, 1) void k_flash(
    const unsigned short* __restrict__ qrh, const unsigned short* __restrict__ qrl,
    const char* __restrict__ krh, const char* __restrict__ krl,
    const char* __restrict__ vthi, const char* __restrict__ vtlo,
    float* __restrict__ ao)
{
  __shared__ __align__(16) char Ksm[32768];     // K buf0 (hi|lo), buf1 (hi|lo)
  __shared__ __align__(16) char PAsm[16384];    // [buf][qt][4 frag][64 lane][16B]
  __shared__ float Ssc[2][2][32];               // [buf][qt][qrow]
  __shared__ float Slinv[2][32];

  char* Khi0 = Ksm;
  char* Klo0 = Ksm + 8192;
  char* Khi1 = Ksm + 16384;
  char* Klo1 = Ksm + 24576;

  const int tid = threadIdx.x;
  const int w = tid >> 6, lane = tid & 63;
  const int lrow = lane & 31, lhi = lane >> 5;
  const bool prod = (w == 0) || (w == 5);
  const bool cons = !prod;
  const int qt = prod ? (w == 5) : (w >= 6);
  const int cw2 = cons ? (qt ? (w - 6) : (w - 1)) : 0;

  const int phys = blockIdx.x;
  const int x = phys & 7, j = phys >> 3;
  const int bh = (x << 1) | (j >> 4);
  const int qb = j & 15;
  const int b = bh >> 3, h = bh & 7;
  const int qbase = qb * 64 + qt * 32;

  // Q fragments: producers only
  uint4 qfh[8], qfl[8];
  if (prod) {
    const size_t rowb = ((size_t)bh * S_ + qbase + lrow) * 128;
#pragma unroll
    for (int fs = 0; fs < 8; ++fs) {
      const size_t e = rowb + fs * 16 + lhi * 8;
      qfh[fs] = *(const uint4*)(qrh + e);
      qfl[fs] = *(const uint4*)(qrl + e);
    }
  }

  const char* vh_c = vthi + (size_t)bh * 1048576;
  const char* vl_c = vtlo + (size_t)bh * 1048576;
  const char* kh_c = krh + (size_t)bh * 262144;
  const char* kl_c = krl + (size_t)bh * 262144;

  auto issue_k = [&](int ch) {              // waves 0..7 only; dst buf = ch&1
    char* dh = (ch & 1) ? Khi1 : Khi0;
    char* dl = (ch & 1) ? Klo1 : Klo0;
    const size_t g = (size_t)ch * 8192;
    __builtin_amdgcn_global_load_lds(kh_c + g + tid * 16, dh + (w << 10), 16, 0, 0);
    __builtin_amdgcn_global_load_lds(kl_c + g + tid * 16, dl + (w << 10), 16, 0, 0);
  };

  const unsigned vbase = (unsigned)((cw2 * 128 + lrow) * 32 + lhi * 16);
  uint4 vAh[4], vAl[4], vBh[4], vBl[4];
  auto load_vA = [&](int ch) {
    const size_t g = (size_t)ch * 32768 + vbase;
#pragma unroll
    for (int cf = 0; cf < 4; ++cf) {
      vAh[cf] = *(const uint4*)(vh_c + g + cf * 1024);
      vAl[cf] = *(const uint4*)(vl_c + g + cf * 1024);
    }
  };
  auto load_vB = [&](int ch) {
    const size_t g = (size_t)ch * 32768 + 16384 + vbase;
#pragma unroll
    for (int cf = 0; cf < 4; ++cf) {
      vBh[cf] = *(const uint4*)(vh_c + g + cf * 1024);
      vBl[cf] = *(const uint4*)(vl_c + g + cf * 1024);
    }
  };

  f32x16 acc[4];
#pragma unroll
  for (int i = 0; i < 4; ++i)
#pragma unroll
    for (int r = 0; r < 16; ++r) acc[i][r] = 0.f;
  float m_run = -1e30f, l_run = 0.f;

  // Producer: compute scores(ch) from K buf ch&1, publish P(ch)+Ssc.
  auto produce = [&](int ch) {
    const char* kh = (ch & 1) ? Khi1 : Khi0;
    const char* kl = (ch & 1) ? Klo1 : Klo0;
    f32x16 s0, s1;
#pragma unroll
    for (int r = 0; r < 16; ++r) { s0[r] = 0.f; s1[r] = 0.f; }
    __builtin_amdgcn_s_setprio(1);
#pragma unroll
    for (int fs = 0; fs < 8; ++fs) {
      const unsigned kaddr = (unsigned)((lrow * 256 + fs * 32 + lhi * 16) ^ ((lrow & 7) << 4));
      U4B8 khf, klf, qh, ql;
      khf.u = *(const uint4*)(kh + kaddr);
      klf.u = *(const uint4*)(kl + kaddr);
      qh.u = qfh[fs]; ql.u = qfl[fs];
      if (fs & 1) {
        s1 = __builtin_amdgcn_mfma_f32_32x32x16_bf16(khf.v, qh.v, s1, 0, 0, 0);
        s1 = __builtin_amdgcn_mfma_f32_32x32x16_bf16(klf.v, qh.v, s1, 0, 0, 0);
        s1 = __builtin_amdgcn_mfma_f32_32x32x16_bf16(khf.v, ql.v, s1, 0, 0, 0);
      } else {
        s0 = __builtin_amdgcn_mfma_f32_32x32x16_bf16(khf.v, qh.v, s0, 0, 0, 0);
        s0 = __builtin_amdgcn_mfma_f32_32x32x16_bf16(klf.v, qh.v, s0, 0, 0, 0);
        s0 = __builtin_amdgcn_mfma_f32_32x32x16_bf16(khf.v, ql.v, s0, 0, 0, 0);
      }
    }
    __builtin_amdgcn_s_setprio(0);
    float s[16];
#pragma unroll
    for (int r = 0; r < 16; ++r) s[r] = s0[r] + s1[r];

    float mx = s[0];
#pragma unroll
    for (int r = 1; r < 16; ++r) mx = fmaxf(mx, s[r]);
    mx = fmaxf(mx, __shfl_xor(mx, 32));
    float sc = 1.0f;
    if (!__all(mx <= m_run + 8.f)) {
      const float mnew = fmaxf(m_run, mx);
      sc = __expf(m_run - mnew);
      l_run *= sc;
      m_run = mnew;
    }
    float p[16];
#pragma unroll
    for (int r = 0; r < 16; ++r) p[r] = __expf(s[r] - m_run);
    float rs = 0.f;
#pragma unroll
    for (int r = 0; r < 16; ++r) rs += p[r];
    rs += __shfl_xor(rs, 32);
    l_run += rs;

    unsigned wh[8], wl[8];
#pragma unroll
    for (int i = 0; i < 8; ++i) {
      const float a = p[2 * i], c2 = p[2 * i + 1];
      const unsigned hword = cvt_pk_bf16(a, c2);
      const float ra = a - __uint_as_float(hword << 16);
      const float rc = c2 - __uint_as_float(hword & 0xffff0000u);
      wh[i] = hword;
      wl[i] = cvt_pk_bf16(ra, rc);
    }
    auto mix = [&](unsigned &lo_w, unsigned &hi_w) {
      const unsigned t = lhi ? lo_w : hi_w;
      const unsigned r = (unsigned)__shfl_xor((int)t, 32);
      lo_w = lhi ? r : lo_w;
      hi_w = lhi ? hi_w : r;
    };
    mix(wh[0], wh[2]); mix(wh[1], wh[3]); mix(wh[4], wh[6]); mix(wh[5], wh[7]);
    mix(wl[0], wl[2]); mix(wl[1], wl[3]); mix(wl[4], wl[6]); mix(wl[5], wl[7]);

    char* pb = PAsm + ((size_t)(ch & 1) * 2 + qt) * 4096;
    *(uint4*)(pb + 0 * 1024 + lane * 16) = make_uint4(wh[0], wh[1], wh[2], wh[3]);
    *(uint4*)(pb + 1 * 1024 + lane * 16) = make_uint4(wh[4], wh[5], wh[6], wh[7]);
    *(uint4*)(pb + 2 * 1024 + lane * 16) = make_uint4(wl[0], wl[1], wl[2], wl[3]);
    *(uint4*)(pb + 3 * 1024 + lane * 16) = make_uint4(wl[4], wl[5], wl[6], wl[7]);
    if (lane < 32) Ssc[ch & 1][qt][lrow] = sc;
  };

  // ---- prologue ----
  if (w < 8) { issue_k(0); issue_k(1); }
  if (cons) { load_vA(0); load_vB(0); }
  if (prod) { asm volatile("s_waitcnt vmcnt(2)" ::: "memory"); }        // K0 landed (own)
  else if (w < 8) { asm volatile("s_waitcnt vmcnt(18)" ::: "memory"); } // K0 landed, K1+V in flight
  SCHED0(); SBAR(); MEMFENCE();
  if (prod) produce(0);
  asm volatile("s_waitcnt lgkmcnt(0)" ::: "memory");
  SCHED0(); SBAR(); MEMFENCE();

  // ---- phase loop: PV(ch) || scores(ch+1) ----
  for (int ch = 0; ch < 32; ++ch) {
    if (ch < 30 && w < 8) { SCHED0(); issue_k(ch + 2); SCHED0(); }

    if (prod) {
      if (ch < 31) produce(ch + 1);
      else if (lane < 32) Slinv[qt][lrow] = 1.0f / l_run;
    } else {
      // fetch P(ch) + scale, rescale acc, PV
      U4B8 pah0, pah1, pal0, pal1;
      {
        const char* pb = PAsm + ((size_t)(ch & 1) * 2 + qt) * 4096;
        pah0.u = *(const uint4*)(pb + 0 * 1024 + lane * 16);
        pah1.u = *(const uint4*)(pb + 1 * 1024 + lane * 16);
        pal0.u = *(const uint4*)(pb + 2 * 1024 + lane * 16);
        pal1.u = *(const uint4*)(pb + 3 * 1024 + lane * 16);
      }
      float scr[16];
#pragma unroll
      for (int r = 0; r < 16; ++r)
        scr[r] = Ssc[ch & 1][qt][(r & 3) + 8 * (r >> 2) + 4 * lhi];
#pragma unroll
      for (int i = 0; i < 4; ++i)
#pragma unroll
        for (int r = 0; r < 16; ++r) acc[i][r] *= scr[r];

      __builtin_amdgcn_s_setprio(1);
#pragma unroll
      for (int cf = 0; cf < 4; ++cf) {
        U4B8 vh, vl2;
        vh.u = vAh[cf]; vl2.u = vAl[cf];
        acc[cf] = __builtin_amdgcn_mfma_f32_32x32x16_bf16(pah0.v, vh.v,  acc[cf], 0, 0, 0);
        acc[cf] = __builtin_amdgcn_mfma_f32_32x32x16_bf16(pal0.v, vh.v,  acc[cf], 0, 0, 0);
        acc[cf] = __builtin_amdgcn_mfma_f32_32x32x16_bf16(pah0.v, vl2.v, acc[cf], 0, 0, 0);
      }
      __builtin_amdgcn_s_setprio(0);
      if (ch < 31) load_vA(ch + 1);

      __builtin_amdgcn_s_setprio(1);
#pragma unroll
      for (int cf = 0; cf < 4; ++cf) {
        U4B8 vh, vl2;
        vh.u = vBh[cf]; vl2.u = vBl[cf];
        acc[cf] = __builtin_amdgcn_mfma_f32_32x32x16_bf16(pah1.v, vh.v,  acc[cf], 0, 0, 0);
        acc[cf] = __builtin_amdgcn_mfma_f32_32x32x16_bf16(pal1.v, vh.v,  acc[cf], 0, 0, 0);
        acc[cf] = __builtin_amdgcn_mfma_f32_32x32x16_bf16(pah1.v, vl2.v, acc[cf], 0, 0, 0);
      }
      __builtin_amdgcn_s_setprio(0);
      if (ch < 31) load_vB(ch + 1);
    }

    // end-of-phase: drain this phase's K DMA (keep V in flight), P visible
    if (prod) { asm volatile("s_waitcnt vmcnt(0)" ::: "memory"); }
    else if (w < 8) {
      if (ch < 30) { asm volatile("s_waitcnt vmcnt(16)" ::: "memory"); }
      else { asm volatile("s_waitcnt vmcnt(16)" ::: "memory"); }
    }
    asm volatile("s_waitcnt lgkmcnt(0)" ::: "memory");
    SCHED0(); SBAR(); MEMFENCE();
  }

  // ---- epilogue (consumers store) ----
  if (cons) {
    float lr[16];
#pragma unroll
    for (int r = 0; r < 16; ++r)
      lr[r] = Slinv[qt][(r & 3) + 8 * (r >> 2) + 4 * lhi];
#pragma unroll
    for (int cf = 0; cf < 4; ++cf) {
      const int c = cw2 * 128 + cf * 32 + lrow;
      const int m = c >> 6, dd = c & 63;
#pragma unroll
      for (int r = 0; r < 16; ++r) {
        const int qr = (r & 3) + 8 * (r >> 2) + 4 * lhi;
        const int srow = qbase + qr;
        const size_t off = (((size_t)(b * S_ + srow)) * 8 + m) * 512 + h * 64 + dd;
        ao[off] = acc[cf][r] * lr[r];
      }
    }
  }
}

// ---------------------------------------------------------------------------
// out_atoms = ao @ Wo^T + fused log-weight delta (unchanged).
// ---------------------------------------------------------------------------
__global__ __launch_bounds__(256) void k_out(
    const float* __restrict__ ao, const float* __restrict__ Wo,
    const float* __restrict__ Ww, const float* __restrict__ qlw,
    float* __restrict__ out)
{
  const int s2 = blockIdx.x;
  const int b = blockIdx.z;
  const int s0 = s2 * 2;
  const int tid = threadIdx.x, w = tid >> 6, lane = tid & 63;

  __shared__ __align__(16) float As[16 * 512];
  __shared__ __align__(16) float WoS[64 * 65];
  __shared__ float Os[16 * 64];

  const float* abase = ao + (size_t)((b * S_ + s0) * 8) * 512;
#pragma unroll
  for (int j = 0; j < 8; ++j) {
    const int i = tid + 256 * j;
    *(float4*)&As[4 * i] = *(const float4*)&abase[4 * i];
  }
  float acc[4] = {0.f, 0.f, 0.f, 0.f};
  for (int ft = 0; ft < 8; ++ft) {
    __syncthreads();
    for (int i = tid; i < 4096; i += 256) {
      const int dwo = i >> 6, fi = i & 63;
      WoS[fi * 65 + dwo] = Wo[dwo * 512 + ft * 64 + fi];
    }
    __syncthreads();
#pragma unroll 8
    for (int fi = 0; fi < 64; ++fi) {
      const float wv = WoS[fi * 65 + lane];
      const int f = ft * 64 + fi;
#pragma unroll
      for (int ri = 0; ri < 4; ++ri)
        acc[ri] = fmaf(As[(w * 4 + ri) * 512 + f], wv, acc[ri]);
    }
  }
#pragma unroll
  for (int ri = 0; ri < 4; ++ri) {
    const int row = w * 4 + ri;
    const int R = (b * S_ + s0) * 8 + row;
    out[(size_t)R * 64 + lane] = acc[ri];
    Os[row * 64 + lane] = acc[ri];
  }
  __syncthreads();
  if (w < 2) {
    float mean = 0.f;
#pragma unroll
    for (int m = 0; m < 8; ++m) mean += Os[(w * 8 + m) * 64 + lane];
    mean *= 0.125f;
    float dsel = 0.f;
#pragma unroll
    for (int mw = 0; mw < 8; ++mw) {
      float part = mean * Ww[mw * 64 + lane];
      part += __shfl_xor(part, 1);
      part += __shfl_xor(part, 2);
      part += __shfl_xor(part, 4);
      part += __shfl_xor(part, 8);
      part += __shfl_xor(part, 16);
      part += __shfl_xor(part, 32);
      if (lane == mw) dsel = part;
    }
    if (lane < 8) {
      const int idx = (b * S_ + s0 + w) * 8 + lane;
      out[1048576 + idx] = qlw[idx] + dsel;
    }
  }
}

// ---------------------------------------------------------------------------
extern "C" void kernel_launch(void* const* d_in, const int* in_sizes, int n_in,
                              void* d_out, int out_size, void* d_ws, size_t ws_size,
                              hipStream_t stream)
{
  const float* q_atoms = (const float*)d_in[0];
  const float* q_logw  = (const float*)d_in[1];
  const float* k_atoms = (const float*)d_in[2];
  const float* k_logw  = (const float*)d_in[3];
  const float* v_atoms = (const float*)d_in[4];
  const float* cosT  = (const float*)d_in[6];
  const float* sinT  = (const float*)d_in[7];
  const float* Wq    = (const float*)d_in[8];
  const float* Wk    = (const float*)d_in[9];
  const float* Wv    = (const float*)d_in[10];
  const float* Wo    = (const float*)d_in[11];
  const float* Ww    = (const float*)d_in[12];
  const float* logbw = (const float*)d_in[13];
  const float* rffb  = (const float*)d_in[14];
  float* out = (float*)d_out;

  char* wsb = (char*)d_ws;
  char* qrh = wsb;
  char* qrl = wsb + (4u << 20);
  char* krh = wsb + (8u << 20);
  char* krl = wsb + (12u << 20);
  char* vthi = wsb + (16u << 20);
  char* vtlo = wsb + (32u << 20);
  float* ao = (float*)(wsb + (48u << 20));

  const dim3 blk(256);
  k_proj_rff<<<dim3(16, 8, 4), blk, 0, stream>>>(q_atoms, q_logw, k_atoms, k_logw,
                                                 Wq, Wk, rffb, logbw, cosT, sinT,
                                                 qrh, qrl, krh, krl);
  k_proj_v  <<<dim3(128, 8, 2), blk, 0, stream>>>(v_atoms, Wv, vthi, vtlo);
  k_flash   <<<dim3(256), dim3(640), 0, stream>>>((const unsigned short*)qrh, (const unsigned short*)qrl,
                                                  krh, krl, vthi, vtlo, ao);
  k_out     <<<dim3(512, 1, 2), blk, 0, stream>>>(ao, Wo, Ww, q_logw, out);
}

// Round 10
// 209.114 us; speedup vs baseline: 3.9195x; 3.9195x over previous
//
#include <hip/hip_runtime.h>
#include <math.h>

// KME attention. B=2 S=1024 M=8 D=64 H=8 NF=64
// Round 10: REVERT k_flash to R8 (R9's 10-wave producer/consumer spilled:
// VGPR 84, 3.3GB scratch traffic). NEW: k_out MFMA-ized (split-bf16 3x,
// verified fragment conventions), 128 rows/block, Wo frags chunk-staged in
// LDS, ao frags from global, Os LDS bounce + fused log-weight delta.
//
// ws layout (bytes), 80 MiB total:
//   qrh  @ 0MB   4MB  ushort [bh][s][128]          (natural)
//   qrl  @ 4MB   4MB
//   krh  @ 8MB   4MB  swizzled-chunk layout [bh][ch=32][8192B]
//   krl  @12MB   4MB
//   vthi @16MB  16MB  [bh][ch=32][half=2][c=512][32B], inner=c*32+part2*16
//   vtlo @32MB  16MB
//   ao   @48MB  32MB  f32 [b][s][m][512]

#define B_ 2
#define S_ 1024
#define H_ 8

typedef __attribute__((ext_vector_type(8))) short short8;
typedef __attribute__((ext_vector_type(16))) float f32x16;
union U4B8 { uint4 u; short8 v; };

#define SBAR() __builtin_amdgcn_s_barrier()
#define SCHED0() __builtin_amdgcn_sched_barrier(0)
#define MEMFENCE() asm volatile("" ::: "memory")

__device__ inline unsigned cvt_pk_bf16(float a, float b) {
  unsigned r;
  asm("v_cvt_pk_bf16_f32 %0, %1, %2" : "=v"(r) : "v"(a), "v"(b));
  return r;
}
__device__ inline void bsplit(float v, unsigned short &h, unsigned short &l) {
  unsigned hw = cvt_pk_bf16(v, 0.f);
  float hf = __uint_as_float(hw << 16);
  unsigned lw = cvt_pk_bf16(v - hf, 0.f);
  h = (unsigned short)hw; l = (unsigned short)lw;
}
__device__ inline void split8(const float* v, unsigned* hw, unsigned* lw) {
#pragma unroll
  for (int p = 0; p < 4; ++p) {
    const float a = v[2 * p], b = v[2 * p + 1];
    const unsigned h = cvt_pk_bf16(a, b);
    const float ra = a - __uint_as_float(h << 16);
    const float rb = b - __uint_as_float(h & 0xffff0000u);
    hw[p] = h;
    lw[p] = cvt_pk_bf16(ra, rb);
  }
}

// ---------------------------------------------------------------------------
// MFMA projection + RoPE + RFF encode (unchanged from R8).
// ---------------------------------------------------------------------------
__global__ __launch_bounds__(256, 2) void k_proj_rff(
    const float* __restrict__ q_atoms, const float* __restrict__ q_logw,
    const float* __restrict__ k_atoms, const float* __restrict__ k_logw,
    const float* __restrict__ Wq, const float* __restrict__ Wk,
    const float* __restrict__ freqb, const float* __restrict__ logbw,
    const float* __restrict__ cosT, const float* __restrict__ sinT,
    char* __restrict__ qoh, char* __restrict__ qol,
    char* __restrict__ koh, char* __restrict__ kol)
{
  const int sblk = blockIdx.x * 64;
  const int h = blockIdx.y, z = blockIdx.z;
  const int qk = z >> 1, b = z & 1;
  const float* atoms = qk ? k_atoms : q_atoms;
  const float* logw  = qk ? k_logw : q_logw;
  const float* W     = qk ? Wk : Wq;
  char* oh = qk ? koh : qoh;
  char* ol = qk ? kol : qol;

  const int tid = threadIdx.x;
  const int w = tid >> 6, lane = tid & 63;
  const int lrow = lane & 31, lhi = lane >> 5;

  __shared__ float Cs[64 * 65];
  __shared__ float Sn[64 * 65];
  __shared__ float Wm[64 * 8];
  __shared__ __align__(16) char FT[2][4][2][1024];
  __shared__ __align__(16) char Ob[4][2][1024];

  for (int i = tid; i < 4096; i += 256) {
    const int sl = i >> 6, d = i & 63;
    Cs[sl * 65 + d] = cosT[(sblk + sl) * 64 + d];
    Sn[sl * 65 + d] = sinT[(sblk + sl) * 64 + d];
  }
  if (tid < 64) {
    const float* lw = logw + (size_t)(b * S_ + sblk + tid) * 8;
    float mx = lw[0];
    for (int m = 1; m < 8; ++m) mx = fmaxf(mx, lw[m]);
    float e[8], sum = 0.f;
    for (int m = 0; m < 8; ++m) { e[m] = __expf(lw[m] - mx); sum += e[m]; }
    const float inv = 1.0f / sum;
    for (int m = 0; m < 8; ++m) Wm[tid * 8 + m] = e[m] * inv;
  }
  const float fscale = __expf(-logbw[h]);
  {
    const int ftw = w & 1;
#pragma unroll
    for (int kk = 0; kk < 2; ++kk) {
      const int ks2 = (w >> 1) + kk * 2;
      float v[8];
#pragma unroll
      for (int j = 0; j < 8; ++j)
        v[j] = freqb[h * 4096 + (ks2 * 16 + lhi * 8 + j) * 64 + ftw * 32 + lrow] * fscale;
      unsigned hw[4], lw2[4];
      split8(v, hw, lw2);
      *(uint4*)&FT[ftw][ks2][0][lane * 16] = make_uint4(hw[0], hw[1], hw[2], hw[3]);
      *(uint4*)&FT[ftw][ks2][1][lane * 16] = make_uint4(lw2[0], lw2[1], lw2[2], lw2[3]);
    }
  }
  unsigned wAh[2][4][4], wAl[2][4][4];
#pragma unroll
  for (int wt = 0; wt < 2; ++wt)
#pragma unroll
    for (int ks = 0; ks < 4; ++ks) {
      const float* wp = W + h * 4096 + (wt * 32 + lrow) * 64 + ks * 16 + lhi * 8;
      float v[8];
      const float4 a = *(const float4*)wp;
      const float4 b2 = *(const float4*)(wp + 4);
      v[0] = a.x; v[1] = a.y; v[2] = a.z; v[3] = a.w;
      v[4] = b2.x; v[5] = b2.y; v[6] = b2.z; v[7] = b2.w;
      split8(v, wAh[wt][ks], wAl[wt][ks]);
    }
  __syncthreads();

  const int bh = b * H_ + h;
  char* obh = &Ob[w][0][0];
  char* obl = &Ob[w][1][0];

  for (int it = 0; it < 4; ++it) {
    const int t = w * 4 + it;
    const float* arow = atoms + ((size_t)(b * S_ + sblk) * 8 + t * 32 + lrow) * 64;
    unsigned aBh[4][4], aBl[4][4];
#pragma unroll
    for (int ks = 0; ks < 4; ++ks) {
      float v[8];
      const float4 a = *(const float4*)(arow + ks * 16 + lhi * 8);
      const float4 b2 = *(const float4*)(arow + ks * 16 + lhi * 8 + 4);
      v[0] = a.x; v[1] = a.y; v[2] = a.z; v[3] = a.w;
      v[4] = b2.x; v[5] = b2.y; v[6] = b2.z; v[7] = b2.w;
      split8(v, aBh[ks], aBl[ks]);
    }

    f32x16 y0, y1;
#pragma unroll
    for (int r = 0; r < 16; ++r) { y0[r] = 0.f; y1[r] = 0.f; }
    __builtin_amdgcn_s_setprio(1);
#pragma unroll
    for (int ks = 0; ks < 4; ++ks) {
      U4B8 a0h, a0l, a1h, a1l, bh2, bl2;
      a0h.u = make_uint4(wAh[0][ks][0], wAh[0][ks][1], wAh[0][ks][2], wAh[0][ks][3]);
      a0l.u = make_uint4(wAl[0][ks][0], wAl[0][ks][1], wAl[0][ks][2], wAl[0][ks][3]);
      a1h.u = make_uint4(wAh[1][ks][0], wAh[1][ks][1], wAh[1][ks][2], wAh[1][ks][3]);
      a1l.u = make_uint4(wAl[1][ks][0], wAl[1][ks][1], wAl[1][ks][2], wAl[1][ks][3]);
      bh2.u = make_uint4(aBh[ks][0], aBh[ks][1], aBh[ks][2], aBh[ks][3]);
      bl2.u = make_uint4(aBl[ks][0], aBl[ks][1], aBl[ks][2], aBl[ks][3]);
      y0 = __builtin_amdgcn_mfma_f32_32x32x16_bf16(a0h.v, bh2.v, y0, 0, 0, 0);
      y1 = __builtin_amdgcn_mfma_f32_32x32x16_bf16(a1h.v, bh2.v, y1, 0, 0, 0);
      y0 = __builtin_amdgcn_mfma_f32_32x32x16_bf16(a0l.v, bh2.v, y0, 0, 0, 0);
      y1 = __builtin_amdgcn_mfma_f32_32x32x16_bf16(a1l.v, bh2.v, y1, 0, 0, 0);
      y0 = __builtin_amdgcn_mfma_f32_32x32x16_bf16(a0h.v, bl2.v, y0, 0, 0, 0);
      y1 = __builtin_amdgcn_mfma_f32_32x32x16_bf16(a1h.v, bl2.v, y1, 0, 0, 0);
    }
    __builtin_amdgcn_s_setprio(0);

    const int sloc = t * 4 + (lrow >> 3);
    const int sld = sloc * 65;
    float yr0[16], yr1[16];
#pragma unroll
    for (int r = 0; r < 16; ++r) {
      const int dd = (r & 3) + 8 * (r >> 2) + 4 * lhi;
      const float c0 = Cs[sld + dd],      s0v = Sn[sld + dd];
      const float c1 = Cs[sld + dd + 32], s1v = Sn[sld + dd + 32];
      yr0[r] = y0[r] * c0 - y1[r] * s0v;
      yr1[r] = y1[r] * c1 + y0[r] * s1v;
    }

    unsigned Bh[4][4], Bl[4][4];
    {
      const float* src[2] = { yr0, yr1 };
#pragma unroll
      for (int st = 0; st < 2; ++st) {
#pragma unroll
        for (int half = 0; half < 2; ++half) {
          const int ks2 = st * 2 + half;
          const float* q = src[st] + half * 8;
          unsigned ph[4], pl[4];
          split8(q, ph, pl);
          {
            const unsigned t0 = lhi ? ph[0] : ph[2];
            const unsigned r0 = (unsigned)__shfl_xor((int)t0, 32);
            const unsigned t1 = lhi ? ph[1] : ph[3];
            const unsigned r1 = (unsigned)__shfl_xor((int)t1, 32);
            Bh[ks2][0] = lhi ? r0 : ph[0];
            Bh[ks2][1] = lhi ? r1 : ph[1];
            Bh[ks2][2] = lhi ? ph[2] : r0;
            Bh[ks2][3] = lhi ? ph[3] : r1;
          }
          {
            const unsigned t0 = lhi ? pl[0] : pl[2];
            const unsigned r0 = (unsigned)__shfl_xor((int)t0, 32);
            const unsigned t1 = lhi ? pl[1] : pl[3];
            const unsigned r1 = (unsigned)__shfl_xor((int)t1, 32);
            Bl[ks2][0] = lhi ? r0 : pl[0];
            Bl[ks2][1] = lhi ? r1 : pl[1];
            Bl[ks2][2] = lhi ? pl[2] : r0;
            Bl[ks2][3] = lhi ? pl[3] : r1;
          }
        }
      }
    }

    f32x16 d0, d1;
#pragma unroll
    for (int r = 0; r < 16; ++r) { d0[r] = 0.f; d1[r] = 0.f; }
    __builtin_amdgcn_s_setprio(1);
#pragma unroll
    for (int ks2 = 0; ks2 < 4; ++ks2) {
      U4B8 a0h, a0l, a1h, a1l, bh2, bl2;
      a0h.u = *(const uint4*)&FT[0][ks2][0][lane * 16];
      a0l.u = *(const uint4*)&FT[0][ks2][1][lane * 16];
      a1h.u = *(const uint4*)&FT[1][ks2][0][lane * 16];
      a1l.u = *(const uint4*)&FT[1][ks2][1][lane * 16];
      bh2.u = make_uint4(Bh[ks2][0], Bh[ks2][1], Bh[ks2][2], Bh[ks2][3]);
      bl2.u = make_uint4(Bl[ks2][0], Bl[ks2][1], Bl[ks2][2], Bl[ks2][3]);
      d0 = __builtin_amdgcn_mfma_f32_32x32x16_bf16(a0h.v, bh2.v, d0, 0, 0, 0);
      d1 = __builtin_amdgcn_mfma_f32_32x32x16_bf16(a1h.v, bh2.v, d1, 0, 0, 0);
      d0 = __builtin_amdgcn_mfma_f32_32x32x16_bf16(a0l.v, bh2.v, d0, 0, 0, 0);
      d1 = __builtin_amdgcn_mfma_f32_32x32x16_bf16(a1l.v, bh2.v, d1, 0, 0, 0);
      d0 = __builtin_amdgcn_mfma_f32_32x32x16_bf16(a0h.v, bl2.v, d0, 0, 0, 0);
      d1 = __builtin_amdgcn_mfma_f32_32x32x16_bf16(a1h.v, bl2.v, d1, 0, 0, 0);
    }
    __builtin_amdgcn_s_setprio(0);

    const float wt = Wm[sloc * 8 + (lrow & 7)];
    float oc[32], os[32];
#pragma unroll
    for (int r = 0; r < 32; ++r) {
      const float pr = (r < 16) ? d0[r] : d1[r - 16];
      float sv, cv;
      __sincosf(pr, &sv, &cv);
      oc[r] = wt * cv;
      os[r] = wt * sv;
    }
#pragma unroll
    for (int r = 0; r < 32; ++r) {
      oc[r] += __shfl_xor(oc[r], 1); os[r] += __shfl_xor(os[r], 1);
      oc[r] += __shfl_xor(oc[r], 2); os[r] += __shfl_xor(os[r], 2);
      oc[r] += __shfl_xor(oc[r], 4); os[r] += __shfl_xor(os[r], 4);
    }

    const int m = lrow & 7, srel = lrow >> 3;
#pragma unroll
    for (int rr2 = 0; rr2 < 4; ++rr2) {
      const int r = m * 4 + rr2;
      const int f = (r & 3) + 8 * ((r >> 2) & 3) + 4 * lhi + ((r >> 4) << 5);
      unsigned short hh, ll;
      bsplit(oc[r] * 0.125f, hh, ll);
      *(unsigned short*)(obh + srel * 256 + f * 2) = hh;
      *(unsigned short*)(obl + srel * 256 + f * 2) = ll;
      bsplit(os[r] * 0.125f, hh, ll);
      *(unsigned short*)(obh + srel * 256 + 128 + f * 2) = hh;
      *(unsigned short*)(obl + srel * 256 + 128 + f * 2) = ll;
    }
    const uint4 vh = *(const uint4*)(obh + lane * 16);
    const uint4 vl = *(const uint4*)(obl + lane * 16);
    const int srow = sblk + t * 4 + (lane >> 4);
    if (!qk) {
      const size_t off = ((size_t)bh * S_ + srow) * 256 + (lane & 15) * 16;
      *(uint4*)(oh + off) = vh;
      *(uint4*)(ol + off) = vl;
    } else {
      const int klr = srow & 31, ch = srow >> 5;
      const unsigned inner = (unsigned)(((klr << 8) + (lane & 15) * 16) ^ ((klr & 7) << 4));
      const size_t off = (size_t)bh * 262144 + (size_t)ch * 8192 + inner;
      *(uint4*)(oh + off) = vh;
      *(uint4*)(ol + off) = vl;
    }
  }
}

// ---------------------------------------------------------------------------
// V projection (unchanged).
// ---------------------------------------------------------------------------
__global__ __launch_bounds__(256) void k_proj_v(
    const float* __restrict__ atoms, const float* __restrict__ W,
    char* __restrict__ vthi, char* __restrict__ vtlo)
{
  const int s0 = blockIdx.x * 8;
  const int h  = blockIdx.y;
  const int b  = blockIdx.z;
  const int tid = threadIdx.x;
  const int w = tid >> 6, lane = tid & 63;

  __shared__ __align__(16) float Wt[64 * 65];
  __shared__ __align__(16) float As[8 * 8 * 64];
  __shared__ __align__(16) float T[8 * 517];

  for (int i = tid; i < 4096; i += 256) {
    const int dd = i >> 6, d = i & 63;
    Wt[d * 65 + dd] = W[h * 4096 + i];
  }
  for (int i = tid; i < 4096; i += 256)
    As[i] = atoms[(size_t)(b * S_ + s0) * 512 + i];
  __syncthreads();

  float acc[16];
#pragma unroll
  for (int i = 0; i < 16; ++i) acc[i] = 0.f;
#pragma unroll
  for (int d4 = 0; d4 < 16; ++d4) {
    const float w0 = Wt[(4 * d4 + 0) * 65 + lane];
    const float w1 = Wt[(4 * d4 + 1) * 65 + lane];
    const float w2 = Wt[(4 * d4 + 2) * 65 + lane];
    const float w3 = Wt[(4 * d4 + 3) * 65 + lane];
#pragma unroll
    for (int smi = 0; smi < 16; ++smi) {
      const float4 a = *(const float4*)&As[(w * 16 + smi) * 64 + 4 * d4];
      acc[smi] = fmaf(a.x, w0, fmaf(a.y, w1, fmaf(a.z, w2, fmaf(a.w, w3, acc[smi]))));
    }
  }
#pragma unroll
  for (int smi = 0; smi < 16; ++smi)
    T[(w * 2 + (smi >> 3)) * 517 + (smi & 7) * 64 + lane] = acc[smi];
  __syncthreads();

  const int bh = b * H_ + h;
  const int ch = s0 >> 5, half = (s0 >> 4) & 1, part2 = (s0 >> 3) & 1;
  const size_t base = (size_t)bh * 1048576 + (size_t)ch * 32768 + half * 16384;
#pragma unroll
  for (int j = 0; j < 2; ++j) {
    const int c = tid + j * 256;
    float v[8];
#pragma unroll
    for (int s = 0; s < 8; ++s) v[s] = T[s * 517 + c];
    unsigned hw[4], lw[4];
#pragma unroll
    for (int p = 0; p < 4; ++p) {
      const float a = v[2 * p], bb = v[2 * p + 1];
      const unsigned hword = cvt_pk_bf16(a, bb);
      const float ra = a - __uint_as_float(hword << 16);
      const float rb = bb - __uint_as_float(hword & 0xffff0000u);
      hw[p] = hword;
      lw[p] = cvt_pk_bf16(ra, rb);
    }
    const unsigned inner = (unsigned)(c * 32 + part2 * 16);
    *(uint4*)(vthi + base + inner) = make_uint4(hw[0], hw[1], hw[2], hw[3]);
    *(uint4*)(vtlo + base + inner) = make_uint4(lw[0], lw[1], lw[2], lw[3]);
  }
}

// ---------------------------------------------------------------------------
// MFMA flash attention, producer/consumer P-share (EXACT R8 revert).
// ---------------------------------------------------------------------------
__global__ __launch_bounds__(512, 1) void k_flash(
    const unsigned short* __restrict__ qrh, const unsigned short* __restrict__ qrl,
    const char* __restrict__ krh, const char* __restrict__ krl,
    const char* __restrict__ vthi, const char* __restrict__ vtlo,
    float* __restrict__ ao)
{
  __shared__ __align__(16) char Ksm[32768];
  __shared__ __align__(16) char PAsm[8192];
  __shared__ float Ssc[2][32];
  __shared__ float Slinv[2][32];

  char* Khi0 = Ksm;
  char* Klo0 = Ksm + 8192;
  char* Khi1 = Ksm + 16384;
  char* Klo1 = Ksm + 24576;

  const int tid = threadIdx.x;
  const int w = tid >> 6, lane = tid & 63;
  const int lrow = lane & 31, lhi = lane >> 5;
  const int cw = w & 3, qt = w >> 2;
  const bool prod = (w == 0) || (w == 5);

  const int phys = blockIdx.x;
  const int x = phys & 7, j = phys >> 3;
  const int bh = (x << 1) | (j >> 4);
  const int qb = j & 15;
  const int b = bh >> 3, h = bh & 7;
  const int qbase = qb * 64 + qt * 32;

  uint4 qfh[8], qfl[8];
  if (prod) {
    const size_t rowb = ((size_t)bh * S_ + qbase + lrow) * 128;
#pragma unroll
    for (int fs = 0; fs < 8; ++fs) {
      const size_t e = rowb + fs * 16 + lhi * 8;
      qfh[fs] = *(const uint4*)(qrh + e);
      qfl[fs] = *(const uint4*)(qrl + e);
    }
  }

  const char* vh_c = vthi + (size_t)bh * 1048576;
  const char* vl_c = vtlo + (size_t)bh * 1048576;
  const char* kh_c = krh + (size_t)bh * 262144;
  const char* kl_c = krl + (size_t)bh * 262144;

  auto issue_k = [&](int ch, char* dh, char* dl) {
    const size_t g = (size_t)ch * 8192;
    __builtin_amdgcn_global_load_lds(kh_c + g + tid * 16, dh + (w << 10), 16, 0, 0);
    __builtin_amdgcn_global_load_lds(kl_c + g + tid * 16, dl + (w << 10), 16, 0, 0);
  };

  const unsigned vbase = (unsigned)((cw * 128 + lrow) * 32 + lhi * 16);
  uint4 vAh[4], vAl[4], vBh[4], vBl[4];
  auto load_vA = [&](int ch) {
    const size_t g = (size_t)ch * 32768 + vbase;
#pragma unroll
    for (int cf = 0; cf < 4; ++cf) {
      vAh[cf] = *(const uint4*)(vh_c + g + cf * 1024);
      vAl[cf] = *(const uint4*)(vl_c + g + cf * 1024);
    }
  };
  auto load_vB = [&](int ch) {
    const size_t g = (size_t)ch * 32768 + 16384 + vbase;
#pragma unroll
    for (int cf = 0; cf < 4; ++cf) {
      vBh[cf] = *(const uint4*)(vh_c + g + cf * 1024);
      vBl[cf] = *(const uint4*)(vl_c + g + cf * 1024);
    }
  };

  f32x16 acc[4];
#pragma unroll
  for (int i = 0; i < 4; ++i)
#pragma unroll
    for (int r = 0; r < 16; ++r) acc[i][r] = 0.f;
  float m_run = -1e30f, l_run = 0.f;

  issue_k(0, Khi0, Klo0);
  load_vA(0);
  load_vB(0);
  asm volatile("s_waitcnt vmcnt(16)" ::: "memory");
  SBAR(); MEMFENCE();

  for (int ch = 0; ch < 32; ++ch) {
    const char* kh = (ch & 1) ? Khi1 : Khi0;
    const char* kl = (ch & 1) ? Klo1 : Klo0;
    if (ch < 31) {
      SCHED0();
      issue_k(ch + 1, (ch & 1) ? Khi0 : Khi1, (ch & 1) ? Klo0 : Klo1);
      SCHED0();
    }

    if (prod) {
      f32x16 s0, s1;
#pragma unroll
      for (int r = 0; r < 16; ++r) { s0[r] = 0.f; s1[r] = 0.f; }
      __builtin_amdgcn_s_setprio(1);
#pragma unroll
      for (int fs = 0; fs < 8; ++fs) {
        const unsigned kaddr = (unsigned)((lrow * 256 + fs * 32 + lhi * 16) ^ ((lrow & 7) << 4));
        U4B8 khf, klf, qh, ql;
        khf.u = *(const uint4*)(kh + kaddr);
        klf.u = *(const uint4*)(kl + kaddr);
        qh.u = qfh[fs]; ql.u = qfl[fs];
        if (fs & 1) {
          s1 = __builtin_amdgcn_mfma_f32_32x32x16_bf16(khf.v, qh.v, s1, 0, 0, 0);
          s1 = __builtin_amdgcn_mfma_f32_32x32x16_bf16(klf.v, qh.v, s1, 0, 0, 0);
          s1 = __builtin_amdgcn_mfma_f32_32x32x16_bf16(khf.v, ql.v, s1, 0, 0, 0);
        } else {
          s0 = __builtin_amdgcn_mfma_f32_32x32x16_bf16(khf.v, qh.v, s0, 0, 0, 0);
          s0 = __builtin_amdgcn_mfma_f32_32x32x16_bf16(klf.v, qh.v, s0, 0, 0, 0);
          s0 = __builtin_amdgcn_mfma_f32_32x32x16_bf16(khf.v, ql.v, s0, 0, 0, 0);
        }
      }
      __builtin_amdgcn_s_setprio(0);
      float s[16];
#pragma unroll
      for (int r = 0; r < 16; ++r) s[r] = s0[r] + s1[r];

      float mx = s[0];
#pragma unroll
      for (int r = 1; r < 16; ++r) mx = fmaxf(mx, s[r]);
      mx = fmaxf(mx, __shfl_xor(mx, 32));
      float sc = 1.0f;
      if (!__all(mx <= m_run + 8.f)) {
        const float mnew = fmaxf(m_run, mx);
        sc = __expf(m_run - mnew);
        l_run *= sc;
        m_run = mnew;
      }
      float p[16];
#pragma unroll
      for (int r = 0; r < 16; ++r) p[r] = __expf(s[r] - m_run);
      float rs = 0.f;
#pragma unroll
      for (int r = 0; r < 16; ++r) rs += p[r];
      rs += __shfl_xor(rs, 32);
      l_run += rs;

      unsigned wh[8], wl[8];
#pragma unroll
      for (int i = 0; i < 8; ++i) {
        const float a = p[2 * i], c2 = p[2 * i + 1];
        const unsigned hword = cvt_pk_bf16(a, c2);
        const float ra = a - __uint_as_float(hword << 16);
        const float rc = c2 - __uint_as_float(hword & 0xffff0000u);
        wh[i] = hword;
        wl[i] = cvt_pk_bf16(ra, rc);
      }
      auto mix = [&](unsigned &lo_w, unsigned &hi_w) {
        const unsigned t = lhi ? lo_w : hi_w;
        const unsigned r = (unsigned)__shfl_xor((int)t, 32);
        lo_w = lhi ? r : lo_w;
        hi_w = lhi ? hi_w : r;
      };
      mix(wh[0], wh[2]); mix(wh[1], wh[3]); mix(wh[4], wh[6]); mix(wh[5], wh[7]);
      mix(wl[0], wl[2]); mix(wl[1], wl[3]); mix(wl[4], wl[6]); mix(wl[5], wl[7]);

      char* pb = PAsm + qt * 4096;
      *(uint4*)(pb + 0 * 1024 + lane * 16) = make_uint4(wh[0], wh[1], wh[2], wh[3]);
      *(uint4*)(pb + 1 * 1024 + lane * 16) = make_uint4(wh[4], wh[5], wh[6], wh[7]);
      *(uint4*)(pb + 2 * 1024 + lane * 16) = make_uint4(wl[0], wl[1], wl[2], wl[3]);
      *(uint4*)(pb + 3 * 1024 + lane * 16) = make_uint4(wl[4], wl[5], wl[6], wl[7]);
      if (lane < 32) Ssc[qt][lrow] = sc;
    }
    asm volatile("s_waitcnt lgkmcnt(0)" ::: "memory");
    SCHED0();
    SBAR(); MEMFENCE();

    U4B8 pah0, pah1, pal0, pal1;
    {
      const char* pb = PAsm + qt * 4096;
      pah0.u = *(const uint4*)(pb + 0 * 1024 + lane * 16);
      pah1.u = *(const uint4*)(pb + 1 * 1024 + lane * 16);
      pal0.u = *(const uint4*)(pb + 2 * 1024 + lane * 16);
      pal1.u = *(const uint4*)(pb + 3 * 1024 + lane * 16);
    }
    float scr[16];
#pragma unroll
    for (int r = 0; r < 16; ++r)
      scr[r] = Ssc[qt][(r & 3) + 8 * (r >> 2) + 4 * lhi];
#pragma unroll
    for (int i = 0; i < 4; ++i)
#pragma unroll
      for (int r = 0; r < 16; ++r) acc[i][r] *= scr[r];

    __builtin_amdgcn_s_setprio(1);
#pragma unroll
    for (int cf = 0; cf < 4; ++cf) {
      U4B8 vh, vl2;
      vh.u = vAh[cf]; vl2.u = vAl[cf];
      acc[cf] = __builtin_amdgcn_mfma_f32_32x32x16_bf16(pah0.v, vh.v,  acc[cf], 0, 0, 0);
      acc[cf] = __builtin_amdgcn_mfma_f32_32x32x16_bf16(pal0.v, vh.v,  acc[cf], 0, 0, 0);
      acc[cf] = __builtin_amdgcn_mfma_f32_32x32x16_bf16(pah0.v, vl2.v, acc[cf], 0, 0, 0);
    }
    __builtin_amdgcn_s_setprio(0);
    if (ch < 31) load_vA(ch + 1);

    __builtin_amdgcn_s_setprio(1);
#pragma unroll
    for (int cf = 0; cf < 4; ++cf) {
      U4B8 vh, vl2;
      vh.u = vBh[cf]; vl2.u = vBl[cf];
      acc[cf] = __builtin_amdgcn_mfma_f32_32x32x16_bf16(pah1.v, vh.v,  acc[cf], 0, 0, 0);
      acc[cf] = __builtin_amdgcn_mfma_f32_32x32x16_bf16(pal1.v, vh.v,  acc[cf], 0, 0, 0);
      acc[cf] = __builtin_amdgcn_mfma_f32_32x32x16_bf16(pah1.v, vl2.v, acc[cf], 0, 0, 0);
    }
    __builtin_amdgcn_s_setprio(0);
    if (ch < 31) {
      load_vB(ch + 1);
      SCHED0();
      asm volatile("s_waitcnt vmcnt(16)" ::: "memory");
      SBAR(); MEMFENCE();
    }
  }

  if (prod && lane < 32) Slinv[qt][lrow] = 1.0f / l_run;
  asm volatile("s_waitcnt lgkmcnt(0)" ::: "memory");
  SBAR(); MEMFENCE();
  float lr[16];
#pragma unroll
  for (int r = 0; r < 16; ++r)
    lr[r] = Slinv[qt][(r & 3) + 8 * (r >> 2) + 4 * lhi];
#pragma unroll
  for (int cf = 0; cf < 4; ++cf) {
    const int c = cw * 128 + cf * 32 + lrow;
    const int m = c >> 6, dd = c & 63;
#pragma unroll
    for (int r = 0; r < 16; ++r) {
      const int qr = (r & 3) + 8 * (r >> 2) + 4 * lhi;
      const int srow = qbase + qr;
      const size_t off = (((size_t)(b * S_ + srow)) * 8 + m) * 512 + h * 64 + dd;
      ao[off] = acc[cf][r] * lr[r];
    }
  }
}

// ---------------------------------------------------------------------------
// k_out MFMA: out[R][d] = sum_f ao[R][f] * Wo[d][f]; R = b*8192 + s*8 + m.
// Block = 128 R rows, 4 waves (one 32-row R-tile each), both 32-d tiles.
// A = Wo frags (split-bf16) chunk-staged in LDS (4 ks/chunk, 8 chunks);
// B = ao frags loaded from global per wave, split in-register. 3-mfma split.
// Epilogue: Os[128][68] LDS bounce -> coalesced stores + fused lw delta.
// ---------------------------------------------------------------------------
__global__ __launch_bounds__(256) void k_out(
    const float* __restrict__ ao, const float* __restrict__ Wo,
    const float* __restrict__ Ww, const float* __restrict__ qlw,
    float* __restrict__ out)
{
  const int tid = threadIdx.x;
  const int w = tid >> 6, lane = tid & 63;
  const int lrow = lane & 31, lhi = lane >> 5;
  const int Rblk = blockIdx.x * 128;

  __shared__ __align__(16) char WoF[4][2][2][1024]; // [ks_loc][dt][hi/lo][lane16B]
  __shared__ __align__(16) float Os[128 * 68];

  f32x16 acc[2];
#pragma unroll
  for (int i = 0; i < 2; ++i)
#pragma unroll
    for (int r = 0; r < 16; ++r) acc[i][r] = 0.f;

  const float* brow = ao + (size_t)(Rblk + w * 32 + lrow) * 512;

  for (int chunk = 0; chunk < 8; ++chunk) {
    __syncthreads();   // WAR: previous chunk's WoF reads done
    // stage: wave w stages ks_loc=w for dt=0,1
#pragma unroll
    for (int dt = 0; dt < 2; ++dt) {
      const float* wp = Wo + (size_t)(dt * 32 + lrow) * 512 + (chunk * 4 + w) * 16 + lhi * 8;
      float v[8];
      const float4 a = *(const float4*)wp;
      const float4 b2 = *(const float4*)(wp + 4);
      v[0] = a.x; v[1] = a.y; v[2] = a.z; v[3] = a.w;
      v[4] = b2.x; v[5] = b2.y; v[6] = b2.z; v[7] = b2.w;
      unsigned hw[4], lw2[4];
      split8(v, hw, lw2);
      *(uint4*)&WoF[w][dt][0][lane * 16] = make_uint4(hw[0], hw[1], hw[2], hw[3]);
      *(uint4*)&WoF[w][dt][1][lane * 16] = make_uint4(lw2[0], lw2[1], lw2[2], lw2[3]);
    }
    __syncthreads();

#pragma unroll
    for (int kl = 0; kl < 4; ++kl) {
      // B-frag: ao row (Rblk + w*32 + lrow), k = (chunk*4+kl)*16 + lhi*8 + j
      float v[8];
      const float4 a = *(const float4*)(brow + (chunk * 4 + kl) * 16 + lhi * 8);
      const float4 b2 = *(const float4*)(brow + (chunk * 4 + kl) * 16 + lhi * 8 + 4);
      v[0] = a.x; v[1] = a.y; v[2] = a.z; v[3] = a.w;
      v[4] = b2.x; v[5] = b2.y; v[6] = b2.z; v[7] = b2.w;
      unsigned bhw[4], blw[4];
      split8(v, bhw, blw);
      U4B8 bh2, bl2;
      bh2.u = make_uint4(bhw[0], bhw[1], bhw[2], bhw[3]);
      bl2.u = make_uint4(blw[0], blw[1], blw[2], blw[3]);
      __builtin_amdgcn_s_setprio(1);
#pragma unroll
      for (int dt = 0; dt < 2; ++dt) {
        U4B8 ah, al;
        ah.u = *(const uint4*)&WoF[kl][dt][0][lane * 16];
        al.u = *(const uint4*)&WoF[kl][dt][1][lane * 16];
        acc[dt] = __builtin_amdgcn_mfma_f32_32x32x16_bf16(ah.v, bh2.v, acc[dt], 0, 0, 0);
        acc[dt] = __builtin_amdgcn_mfma_f32_32x32x16_bf16(al.v, bh2.v, acc[dt], 0, 0, 0);
        acc[dt] = __builtin_amdgcn_mfma_f32_32x32x16_bf16(ah.v, bl2.v, acc[dt], 0, 0, 0);
      }
      __builtin_amdgcn_s_setprio(0);
    }
  }

  // ---- bounce D[d][R] -> Os[R_local][d] ----
  __syncthreads();   // WoF reads done (reuse barrier before Os writes is fine)
#pragma unroll
  for (int dt = 0; dt < 2; ++dt)
#pragma unroll
    for (int r = 0; r < 16; ++r) {
      const int d = dt * 32 + (r & 3) + 8 * (r >> 2) + 4 * lhi;
      Os[(w * 32 + lrow) * 68 + d] = acc[dt][r];
    }
  __syncthreads();

  // ---- coalesced out_atoms stores ----
#pragma unroll
  for (int jj = 0; jj < 8; ++jj) {
    const int i = tid + 256 * jj;           // 2048 float4 total
    const int r = i >> 4, c4 = (i & 15) * 4;
    const float4 v = *(const float4*)&Os[r * 68 + c4];
    *(float4*)&out[(size_t)(Rblk + r) * 64 + c4] = v;
  }

  // ---- fused log-weight delta: wave w handles s-groups w*4 .. w*4+3 ----
#pragma unroll
  for (int gi = 0; gi < 4; ++gi) {
    const int g = w * 4 + gi;
    float mean = 0.f;
#pragma unroll
    for (int m = 0; m < 8; ++m) mean += Os[(g * 8 + m) * 68 + lane];
    mean *= 0.125f;
    float dsel = 0.f;
#pragma unroll
    for (int mw = 0; mw < 8; ++mw) {
      float part = mean * Ww[mw * 64 + lane];
      part += __shfl_xor(part, 1);
      part += __shfl_xor(part, 2);
      part += __shfl_xor(part, 4);
      part += __shfl_xor(part, 8);
      part += __shfl_xor(part, 16);
      part += __shfl_xor(part, 32);
      if (lane == mw) dsel = part;
    }
    if (lane < 8) {
      const int idx = Rblk + g * 8 + lane;
      out[1048576 + idx] = qlw[idx] + dsel;
    }
  }
}

// ---------------------------------------------------------------------------
extern "C" void kernel_launch(void* const* d_in, const int* in_sizes, int n_in,
                              void* d_out, int out_size, void* d_ws, size_t ws_size,
                              hipStream_t stream)
{
  const float* q_atoms = (const float*)d_in[0];
  const float* q_logw  = (const float*)d_in[1];
  const float* k_atoms = (const float*)d_in[2];
  const float* k_logw  = (const float*)d_in[3];
  const float* v_atoms = (const float*)d_in[4];
  const float* cosT  = (const float*)d_in[6];
  const float* sinT  = (const float*)d_in[7];
  const float* Wq    = (const float*)d_in[8];
  const float* Wk    = (const float*)d_in[9];
  const float* Wv    = (const float*)d_in[10];
  const float* Wo    = (const float*)d_in[11];
  const float* Ww    = (const float*)d_in[12];
  const float* logbw = (const float*)d_in[13];
  const float* rffb  = (const float*)d_in[14];
  float* out = (float*)d_out;

  char* wsb = (char*)d_ws;
  char* qrh = wsb;
  char* qrl = wsb + (4u << 20);
  char* krh = wsb + (8u << 20);
  char* krl = wsb + (12u << 20);
  char* vthi = wsb + (16u << 20);
  char* vtlo = wsb + (32u << 20);
  float* ao = (float*)(wsb + (48u << 20));

  const dim3 blk(256);
  k_proj_rff<<<dim3(16, 8, 4), blk, 0, stream>>>(q_atoms, q_logw, k_atoms, k_logw,
                                                 Wq, Wk, rffb, logbw, cosT, sinT,
                                                 qrh, qrl, krh, krl);
  k_proj_v  <<<dim3(128, 8, 2), blk, 0, stream>>>(v_atoms, Wv, vthi, vtlo);
  k_flash   <<<dim3(256), dim3(512), 0, stream>>>((const unsigned short*)qrh, (const unsigned short*)qrl,
                                                  krh, krl, vthi, vtlo, ao);
  k_out     <<<dim3(128), blk, 0, stream>>>(ao, Wo, Ww, q_logw, out);
}

// Round 11
// 192.405 us; speedup vs baseline: 4.2599x; 1.0868x over previous
//
#include <hip/hip_runtime.h>
#include <math.h>

// KME attention. B=2 S=1024 M=8 D=64 H=8 NF=64
// Round 11: k_flash de-duplicates V traffic: each wave owns 64 columns and
// computes PV for BOTH q-tiles with shared V registers (V bytes/chunk halved:
// 128->64KB per CU). acc=[qt][cf], P fragments read for both qt. Producer /
// softmax / publish identical to R8. Other kernels unchanged.
//
// ws layout (bytes), 80 MiB total:
//   qrh  @ 0MB   4MB  ushort [bh][s][128]          (natural)
//   qrl  @ 4MB   4MB
//   krh  @ 8MB   4MB  swizzled-chunk layout [bh][ch=32][8192B]
//   krl  @12MB   4MB
//   vthi @16MB  16MB  [bh][ch=32][half=2][c=512][32B], inner=c*32+part2*16
//   vtlo @32MB  16MB
//   ao   @48MB  32MB  f32 [b][s][m][512]

#define B_ 2
#define S_ 1024
#define H_ 8

typedef __attribute__((ext_vector_type(8))) short short8;
typedef __attribute__((ext_vector_type(16))) float f32x16;
union U4B8 { uint4 u; short8 v; };

#define SBAR() __builtin_amdgcn_s_barrier()
#define SCHED0() __builtin_amdgcn_sched_barrier(0)
#define MEMFENCE() asm volatile("" ::: "memory")

__device__ inline unsigned cvt_pk_bf16(float a, float b) {
  unsigned r;
  asm("v_cvt_pk_bf16_f32 %0, %1, %2" : "=v"(r) : "v"(a), "v"(b));
  return r;
}
__device__ inline void bsplit(float v, unsigned short &h, unsigned short &l) {
  unsigned hw = cvt_pk_bf16(v, 0.f);
  float hf = __uint_as_float(hw << 16);
  unsigned lw = cvt_pk_bf16(v - hf, 0.f);
  h = (unsigned short)hw; l = (unsigned short)lw;
}
__device__ inline void split8(const float* v, unsigned* hw, unsigned* lw) {
#pragma unroll
  for (int p = 0; p < 4; ++p) {
    const float a = v[2 * p], b = v[2 * p + 1];
    const unsigned h = cvt_pk_bf16(a, b);
    const float ra = a - __uint_as_float(h << 16);
    const float rb = b - __uint_as_float(h & 0xffff0000u);
    hw[p] = h;
    lw[p] = cvt_pk_bf16(ra, rb);
  }
}

// ---------------------------------------------------------------------------
// MFMA projection + RoPE + RFF encode (unchanged from R8).
// ---------------------------------------------------------------------------
__global__ __launch_bounds__(256, 2) void k_proj_rff(
    const float* __restrict__ q_atoms, const float* __restrict__ q_logw,
    const float* __restrict__ k_atoms, const float* __restrict__ k_logw,
    const float* __restrict__ Wq, const float* __restrict__ Wk,
    const float* __restrict__ freqb, const float* __restrict__ logbw,
    const float* __restrict__ cosT, const float* __restrict__ sinT,
    char* __restrict__ qoh, char* __restrict__ qol,
    char* __restrict__ koh, char* __restrict__ kol)
{
  const int sblk = blockIdx.x * 64;
  const int h = blockIdx.y, z = blockIdx.z;
  const int qk = z >> 1, b = z & 1;
  const float* atoms = qk ? k_atoms : q_atoms;
  const float* logw  = qk ? k_logw : q_logw;
  const float* W     = qk ? Wk : Wq;
  char* oh = qk ? koh : qoh;
  char* ol = qk ? kol : qol;

  const int tid = threadIdx.x;
  const int w = tid >> 6, lane = tid & 63;
  const int lrow = lane & 31, lhi = lane >> 5;

  __shared__ float Cs[64 * 65];
  __shared__ float Sn[64 * 65];
  __shared__ float Wm[64 * 8];
  __shared__ __align__(16) char FT[2][4][2][1024];
  __shared__ __align__(16) char Ob[4][2][1024];

  for (int i = tid; i < 4096; i += 256) {
    const int sl = i >> 6, d = i & 63;
    Cs[sl * 65 + d] = cosT[(sblk + sl) * 64 + d];
    Sn[sl * 65 + d] = sinT[(sblk + sl) * 64 + d];
  }
  if (tid < 64) {
    const float* lw = logw + (size_t)(b * S_ + sblk + tid) * 8;
    float mx = lw[0];
    for (int m = 1; m < 8; ++m) mx = fmaxf(mx, lw[m]);
    float e[8], sum = 0.f;
    for (int m = 0; m < 8; ++m) { e[m] = __expf(lw[m] - mx); sum += e[m]; }
    const float inv = 1.0f / sum;
    for (int m = 0; m < 8; ++m) Wm[tid * 8 + m] = e[m] * inv;
  }
  const float fscale = __expf(-logbw[h]);
  {
    const int ftw = w & 1;
#pragma unroll
    for (int kk = 0; kk < 2; ++kk) {
      const int ks2 = (w >> 1) + kk * 2;
      float v[8];
#pragma unroll
      for (int j = 0; j < 8; ++j)
        v[j] = freqb[h * 4096 + (ks2 * 16 + lhi * 8 + j) * 64 + ftw * 32 + lrow] * fscale;
      unsigned hw[4], lw2[4];
      split8(v, hw, lw2);
      *(uint4*)&FT[ftw][ks2][0][lane * 16] = make_uint4(hw[0], hw[1], hw[2], hw[3]);
      *(uint4*)&FT[ftw][ks2][1][lane * 16] = make_uint4(lw2[0], lw2[1], lw2[2], lw2[3]);
    }
  }
  unsigned wAh[2][4][4], wAl[2][4][4];
#pragma unroll
  for (int wt = 0; wt < 2; ++wt)
#pragma unroll
    for (int ks = 0; ks < 4; ++ks) {
      const float* wp = W + h * 4096 + (wt * 32 + lrow) * 64 + ks * 16 + lhi * 8;
      float v[8];
      const float4 a = *(const float4*)wp;
      const float4 b2 = *(const float4*)(wp + 4);
      v[0] = a.x; v[1] = a.y; v[2] = a.z; v[3] = a.w;
      v[4] = b2.x; v[5] = b2.y; v[6] = b2.z; v[7] = b2.w;
      split8(v, wAh[wt][ks], wAl[wt][ks]);
    }
  __syncthreads();

  const int bh = b * H_ + h;
  char* obh = &Ob[w][0][0];
  char* obl = &Ob[w][1][0];

  for (int it = 0; it < 4; ++it) {
    const int t = w * 4 + it;
    const float* arow = atoms + ((size_t)(b * S_ + sblk) * 8 + t * 32 + lrow) * 64;
    unsigned aBh[4][4], aBl[4][4];
#pragma unroll
    for (int ks = 0; ks < 4; ++ks) {
      float v[8];
      const float4 a = *(const float4*)(arow + ks * 16 + lhi * 8);
      const float4 b2 = *(const float4*)(arow + ks * 16 + lhi * 8 + 4);
      v[0] = a.x; v[1] = a.y; v[2] = a.z; v[3] = a.w;
      v[4] = b2.x; v[5] = b2.y; v[6] = b2.z; v[7] = b2.w;
      split8(v, aBh[ks], aBl[ks]);
    }

    f32x16 y0, y1;
#pragma unroll
    for (int r = 0; r < 16; ++r) { y0[r] = 0.f; y1[r] = 0.f; }
    __builtin_amdgcn_s_setprio(1);
#pragma unroll
    for (int ks = 0; ks < 4; ++ks) {
      U4B8 a0h, a0l, a1h, a1l, bh2, bl2;
      a0h.u = make_uint4(wAh[0][ks][0], wAh[0][ks][1], wAh[0][ks][2], wAh[0][ks][3]);
      a0l.u = make_uint4(wAl[0][ks][0], wAl[0][ks][1], wAl[0][ks][2], wAl[0][ks][3]);
      a1h.u = make_uint4(wAh[1][ks][0], wAh[1][ks][1], wAh[1][ks][2], wAh[1][ks][3]);
      a1l.u = make_uint4(wAl[1][ks][0], wAl[1][ks][1], wAl[1][ks][2], wAl[1][ks][3]);
      bh2.u = make_uint4(aBh[ks][0], aBh[ks][1], aBh[ks][2], aBh[ks][3]);
      bl2.u = make_uint4(aBl[ks][0], aBl[ks][1], aBl[ks][2], aBl[ks][3]);
      y0 = __builtin_amdgcn_mfma_f32_32x32x16_bf16(a0h.v, bh2.v, y0, 0, 0, 0);
      y1 = __builtin_amdgcn_mfma_f32_32x32x16_bf16(a1h.v, bh2.v, y1, 0, 0, 0);
      y0 = __builtin_amdgcn_mfma_f32_32x32x16_bf16(a0l.v, bh2.v, y0, 0, 0, 0);
      y1 = __builtin_amdgcn_mfma_f32_32x32x16_bf16(a1l.v, bh2.v, y1, 0, 0, 0);
      y0 = __builtin_amdgcn_mfma_f32_32x32x16_bf16(a0h.v, bl2.v, y0, 0, 0, 0);
      y1 = __builtin_amdgcn_mfma_f32_32x32x16_bf16(a1h.v, bl2.v, y1, 0, 0, 0);
    }
    __builtin_amdgcn_s_setprio(0);

    const int sloc = t * 4 + (lrow >> 3);
    const int sld = sloc * 65;
    float yr0[16], yr1[16];
#pragma unroll
    for (int r = 0; r < 16; ++r) {
      const int dd = (r & 3) + 8 * (r >> 2) + 4 * lhi;
      const float c0 = Cs[sld + dd],      s0v = Sn[sld + dd];
      const float c1 = Cs[sld + dd + 32], s1v = Sn[sld + dd + 32];
      yr0[r] = y0[r] * c0 - y1[r] * s0v;
      yr1[r] = y1[r] * c1 + y0[r] * s1v;
    }

    unsigned Bh[4][4], Bl[4][4];
    {
      const float* src[2] = { yr0, yr1 };
#pragma unroll
      for (int st = 0; st < 2; ++st) {
#pragma unroll
        for (int half = 0; half < 2; ++half) {
          const int ks2 = st * 2 + half;
          const float* q = src[st] + half * 8;
          unsigned ph[4], pl[4];
          split8(q, ph, pl);
          {
            const unsigned t0 = lhi ? ph[0] : ph[2];
            const unsigned r0 = (unsigned)__shfl_xor((int)t0, 32);
            const unsigned t1 = lhi ? ph[1] : ph[3];
            const unsigned r1 = (unsigned)__shfl_xor((int)t1, 32);
            Bh[ks2][0] = lhi ? r0 : ph[0];
            Bh[ks2][1] = lhi ? r1 : ph[1];
            Bh[ks2][2] = lhi ? ph[2] : r0;
            Bh[ks2][3] = lhi ? ph[3] : r1;
          }
          {
            const unsigned t0 = lhi ? pl[0] : pl[2];
            const unsigned r0 = (unsigned)__shfl_xor((int)t0, 32);
            const unsigned t1 = lhi ? pl[1] : pl[3];
            const unsigned r1 = (unsigned)__shfl_xor((int)t1, 32);
            Bl[ks2][0] = lhi ? r0 : pl[0];
            Bl[ks2][1] = lhi ? r1 : pl[1];
            Bl[ks2][2] = lhi ? pl[2] : r0;
            Bl[ks2][3] = lhi ? pl[3] : r1;
          }
        }
      }
    }

    f32x16 d0, d1;
#pragma unroll
    for (int r = 0; r < 16; ++r) { d0[r] = 0.f; d1[r] = 0.f; }
    __builtin_amdgcn_s_setprio(1);
#pragma unroll
    for (int ks2 = 0; ks2 < 4; ++ks2) {
      U4B8 a0h, a0l, a1h, a1l, bh2, bl2;
      a0h.u = *(const uint4*)&FT[0][ks2][0][lane * 16];
      a0l.u = *(const uint4*)&FT[0][ks2][1][lane * 16];
      a1h.u = *(const uint4*)&FT[1][ks2][0][lane * 16];
      a1l.u = *(const uint4*)&FT[1][ks2][1][lane * 16];
      bh2.u = make_uint4(Bh[ks2][0], Bh[ks2][1], Bh[ks2][2], Bh[ks2][3]);
      bl2.u = make_uint4(Bl[ks2][0], Bl[ks2][1], Bl[ks2][2], Bl[ks2][3]);
      d0 = __builtin_amdgcn_mfma_f32_32x32x16_bf16(a0h.v, bh2.v, d0, 0, 0, 0);
      d1 = __builtin_amdgcn_mfma_f32_32x32x16_bf16(a1h.v, bh2.v, d1, 0, 0, 0);
      d0 = __builtin_amdgcn_mfma_f32_32x32x16_bf16(a0l.v, bh2.v, d0, 0, 0, 0);
      d1 = __builtin_amdgcn_mfma_f32_32x32x16_bf16(a1l.v, bh2.v, d1, 0, 0, 0);
      d0 = __builtin_amdgcn_mfma_f32_32x32x16_bf16(a0h.v, bl2.v, d0, 0, 0, 0);
      d1 = __builtin_amdgcn_mfma_f32_32x32x16_bf16(a1h.v, bl2.v, d1, 0, 0, 0);
    }
    __builtin_amdgcn_s_setprio(0);

    const float wt = Wm[sloc * 8 + (lrow & 7)];
    float oc[32], os[32];
#pragma unroll
    for (int r = 0; r < 32; ++r) {
      const float pr = (r < 16) ? d0[r] : d1[r - 16];
      float sv, cv;
      __sincosf(pr, &sv, &cv);
      oc[r] = wt * cv;
      os[r] = wt * sv;
    }
#pragma unroll
    for (int r = 0; r < 32; ++r) {
      oc[r] += __shfl_xor(oc[r], 1); os[r] += __shfl_xor(os[r], 1);
      oc[r] += __shfl_xor(oc[r], 2); os[r] += __shfl_xor(os[r], 2);
      oc[r] += __shfl_xor(oc[r], 4); os[r] += __shfl_xor(os[r], 4);
    }

    const int m = lrow & 7, srel = lrow >> 3;
#pragma unroll
    for (int rr2 = 0; rr2 < 4; ++rr2) {
      const int r = m * 4 + rr2;
      const int f = (r & 3) + 8 * ((r >> 2) & 3) + 4 * lhi + ((r >> 4) << 5);
      unsigned short hh, ll;
      bsplit(oc[r] * 0.125f, hh, ll);
      *(unsigned short*)(obh + srel * 256 + f * 2) = hh;
      *(unsigned short*)(obl + srel * 256 + f * 2) = ll;
      bsplit(os[r] * 0.125f, hh, ll);
      *(unsigned short*)(obh + srel * 256 + 128 + f * 2) = hh;
      *(unsigned short*)(obl + srel * 256 + 128 + f * 2) = ll;
    }
    const uint4 vh = *(const uint4*)(obh + lane * 16);
    const uint4 vl = *(const uint4*)(obl + lane * 16);
    const int srow = sblk + t * 4 + (lane >> 4);
    if (!qk) {
      const size_t off = ((size_t)bh * S_ + srow) * 256 + (lane & 15) * 16;
      *(uint4*)(oh + off) = vh;
      *(uint4*)(ol + off) = vl;
    } else {
      const int klr = srow & 31, ch = srow >> 5;
      const unsigned inner = (unsigned)(((klr << 8) + (lane & 15) * 16) ^ ((klr & 7) << 4));
      const size_t off = (size_t)bh * 262144 + (size_t)ch * 8192 + inner;
      *(uint4*)(oh + off) = vh;
      *(uint4*)(ol + off) = vl;
    }
  }
}

// ---------------------------------------------------------------------------
// V projection (unchanged).
// ---------------------------------------------------------------------------
__global__ __launch_bounds__(256) void k_proj_v(
    const float* __restrict__ atoms, const float* __restrict__ W,
    char* __restrict__ vthi, char* __restrict__ vtlo)
{
  const int s0 = blockIdx.x * 8;
  const int h  = blockIdx.y;
  const int b  = blockIdx.z;
  const int tid = threadIdx.x;
  const int w = tid >> 6, lane = tid & 63;

  __shared__ __align__(16) float Wt[64 * 65];
  __shared__ __align__(16) float As[8 * 8 * 64];
  __shared__ __align__(16) float T[8 * 517];

  for (int i = tid; i < 4096; i += 256) {
    const int dd = i >> 6, d = i & 63;
    Wt[d * 65 + dd] = W[h * 4096 + i];
  }
  for (int i = tid; i < 4096; i += 256)
    As[i] = atoms[(size_t)(b * S_ + s0) * 512 + i];
  __syncthreads();

  float acc[16];
#pragma unroll
  for (int i = 0; i < 16; ++i) acc[i] = 0.f;
#pragma unroll
  for (int d4 = 0; d4 < 16; ++d4) {
    const float w0 = Wt[(4 * d4 + 0) * 65 + lane];
    const float w1 = Wt[(4 * d4 + 1) * 65 + lane];
    const float w2 = Wt[(4 * d4 + 2) * 65 + lane];
    const float w3 = Wt[(4 * d4 + 3) * 65 + lane];
#pragma unroll
    for (int smi = 0; smi < 16; ++smi) {
      const float4 a = *(const float4*)&As[(w * 16 + smi) * 64 + 4 * d4];
      acc[smi] = fmaf(a.x, w0, fmaf(a.y, w1, fmaf(a.z, w2, fmaf(a.w, w3, acc[smi]))));
    }
  }
#pragma unroll
  for (int smi = 0; smi < 16; ++smi)
    T[(w * 2 + (smi >> 3)) * 517 + (smi & 7) * 64 + lane] = acc[smi];
  __syncthreads();

  const int bh = b * H_ + h;
  const int ch = s0 >> 5, half = (s0 >> 4) & 1, part2 = (s0 >> 3) & 1;
  const size_t base = (size_t)bh * 1048576 + (size_t)ch * 32768 + half * 16384;
#pragma unroll
  for (int j = 0; j < 2; ++j) {
    const int c = tid + j * 256;
    float v[8];
#pragma unroll
    for (int s = 0; s < 8; ++s) v[s] = T[s * 517 + c];
    unsigned hw[4], lw[4];
#pragma unroll
    for (int p = 0; p < 4; ++p) {
      const float a = v[2 * p], bb = v[2 * p + 1];
      const unsigned hword = cvt_pk_bf16(a, bb);
      const float ra = a - __uint_as_float(hword << 16);
      const float rb = bb - __uint_as_float(hword & 0xffff0000u);
      hw[p] = hword;
      lw[p] = cvt_pk_bf16(ra, rb);
    }
    const unsigned inner = (unsigned)(c * 32 + part2 * 16);
    *(uint4*)(vthi + base + inner) = make_uint4(hw[0], hw[1], hw[2], hw[3]);
    *(uint4*)(vtlo + base + inner) = make_uint4(lw[0], lw[1], lw[2], lw[3]);
  }
}

// ---------------------------------------------------------------------------
// MFMA flash attention, producer/consumer P-share; wave owns 64 cols, serves
// BOTH q-tiles with shared V registers (V traffic halved vs R8).
// ---------------------------------------------------------------------------
__global__ __launch_bounds__(512, 1) void k_flash(
    const unsigned short* __restrict__ qrh, const unsigned short* __restrict__ qrl,
    const char* __restrict__ krh, const char* __restrict__ krl,
    const char* __restrict__ vthi, const char* __restrict__ vtlo,
    float* __restrict__ ao)
{
  __shared__ __align__(16) char Ksm[32768];
  __shared__ __align__(16) char PAsm[8192];
  __shared__ float Ssc[2][32];
  __shared__ float Slinv[2][32];

  char* Khi0 = Ksm;
  char* Klo0 = Ksm + 8192;
  char* Khi1 = Ksm + 16384;
  char* Klo1 = Ksm + 24576;

  const int tid = threadIdx.x;
  const int w = tid >> 6, lane = tid & 63;
  const int lrow = lane & 31, lhi = lane >> 5;
  const bool prod = (w == 0) || (w == 5);
  const int pqt = (w == 5) ? 1 : 0;            // producer's q-tile

  const int phys = blockIdx.x;
  const int x = phys & 7, j = phys >> 3;
  const int bh = (x << 1) | (j >> 4);
  const int qb = j & 15;
  const int b = bh >> 3, h = bh & 7;
  const int qb64 = qb * 64;

  // Q fragments: producers only
  uint4 qfh[8], qfl[8];
  if (prod) {
    const size_t rowb = ((size_t)bh * S_ + qb64 + pqt * 32 + lrow) * 128;
#pragma unroll
    for (int fs = 0; fs < 8; ++fs) {
      const size_t e = rowb + fs * 16 + lhi * 8;
      qfh[fs] = *(const uint4*)(qrh + e);
      qfl[fs] = *(const uint4*)(qrl + e);
    }
  }

  const char* vh_c = vthi + (size_t)bh * 1048576;
  const char* vl_c = vtlo + (size_t)bh * 1048576;
  const char* kh_c = krh + (size_t)bh * 262144;
  const char* kl_c = krl + (size_t)bh * 262144;

  auto issue_k = [&](int ch, char* dh, char* dl) {
    const size_t g = (size_t)ch * 8192;
    __builtin_amdgcn_global_load_lds(kh_c + g + tid * 16, dh + (w << 10), 16, 0, 0);
    __builtin_amdgcn_global_load_lds(kl_c + g + tid * 16, dl + (w << 10), 16, 0, 0);
  };

  // wave owns 64 cols: c = w*64 + cf*32 + lrow, cf in {0,1}
  const unsigned vbase = (unsigned)((w * 64 + lrow) * 32 + lhi * 16);
  uint4 vAh[2], vAl[2], vBh[2], vBl[2];
  auto load_vA = [&](int ch) {
    const size_t g = (size_t)ch * 32768 + vbase;
#pragma unroll
    for (int cf = 0; cf < 2; ++cf) {
      vAh[cf] = *(const uint4*)(vh_c + g + cf * 1024);
      vAl[cf] = *(const uint4*)(vl_c + g + cf * 1024);
    }
  };
  auto load_vB = [&](int ch) {
    const size_t g = (size_t)ch * 32768 + 16384 + vbase;
#pragma unroll
    for (int cf = 0; cf < 2; ++cf) {
      vBh[cf] = *(const uint4*)(vh_c + g + cf * 1024);
      vBl[cf] = *(const uint4*)(vl_c + g + cf * 1024);
    }
  };

  f32x16 acc[4];                                // [qt*2+cf]
#pragma unroll
  for (int i = 0; i < 4; ++i)
#pragma unroll
    for (int r = 0; r < 16; ++r) acc[i][r] = 0.f;
  float m_run = -1e30f, l_run = 0.f;

  issue_k(0, Khi0, Klo0);
  load_vA(0);
  load_vB(0);
  asm volatile("s_waitcnt vmcnt(8)" ::: "memory");   // K(0) landed (2 oldest)
  SBAR(); MEMFENCE();

  for (int ch = 0; ch < 32; ++ch) {
    const char* kh = (ch & 1) ? Khi1 : Khi0;
    const char* kl = (ch & 1) ? Klo1 : Klo0;
    if (ch < 31) {
      SCHED0();
      issue_k(ch + 1, (ch & 1) ? Khi0 : Khi1, (ch & 1) ? Klo0 : Klo1);
      SCHED0();
    }

    if (prod) {
      f32x16 s0, s1;
#pragma unroll
      for (int r = 0; r < 16; ++r) { s0[r] = 0.f; s1[r] = 0.f; }
      __builtin_amdgcn_s_setprio(1);
#pragma unroll
      for (int fs = 0; fs < 8; ++fs) {
        const unsigned kaddr = (unsigned)((lrow * 256 + fs * 32 + lhi * 16) ^ ((lrow & 7) << 4));
        U4B8 khf, klf, qh, ql;
        khf.u = *(const uint4*)(kh + kaddr);
        klf.u = *(const uint4*)(kl + kaddr);
        qh.u = qfh[fs]; ql.u = qfl[fs];
        if (fs & 1) {
          s1 = __builtin_amdgcn_mfma_f32_32x32x16_bf16(khf.v, qh.v, s1, 0, 0, 0);
          s1 = __builtin_amdgcn_mfma_f32_32x32x16_bf16(klf.v, qh.v, s1, 0, 0, 0);
          s1 = __builtin_amdgcn_mfma_f32_32x32x16_bf16(khf.v, ql.v, s1, 0, 0, 0);
        } else {
          s0 = __builtin_amdgcn_mfma_f32_32x32x16_bf16(khf.v, qh.v, s0, 0, 0, 0);
          s0 = __builtin_amdgcn_mfma_f32_32x32x16_bf16(klf.v, qh.v, s0, 0, 0, 0);
          s0 = __builtin_amdgcn_mfma_f32_32x32x16_bf16(khf.v, ql.v, s0, 0, 0, 0);
        }
      }
      __builtin_amdgcn_s_setprio(0);
      float s[16];
#pragma unroll
      for (int r = 0; r < 16; ++r) s[r] = s0[r] + s1[r];

      float mx = s[0];
#pragma unroll
      for (int r = 1; r < 16; ++r) mx = fmaxf(mx, s[r]);
      mx = fmaxf(mx, __shfl_xor(mx, 32));
      float sc = 1.0f;
      if (!__all(mx <= m_run + 8.f)) {
        const float mnew = fmaxf(m_run, mx);
        sc = __expf(m_run - mnew);
        l_run *= sc;
        m_run = mnew;
      }
      float p[16];
#pragma unroll
      for (int r = 0; r < 16; ++r) p[r] = __expf(s[r] - m_run);
      float rs = 0.f;
#pragma unroll
      for (int r = 0; r < 16; ++r) rs += p[r];
      rs += __shfl_xor(rs, 32);
      l_run += rs;

      unsigned wh[8], wl[8];
#pragma unroll
      for (int i = 0; i < 8; ++i) {
        const float a = p[2 * i], c2 = p[2 * i + 1];
        const unsigned hword = cvt_pk_bf16(a, c2);
        const float ra = a - __uint_as_float(hword << 16);
        const float rc = c2 - __uint_as_float(hword & 0xffff0000u);
        wh[i] = hword;
        wl[i] = cvt_pk_bf16(ra, rc);
      }
      auto mix = [&](unsigned &lo_w, unsigned &hi_w) {
        const unsigned t = lhi ? lo_w : hi_w;
        const unsigned r = (unsigned)__shfl_xor((int)t, 32);
        lo_w = lhi ? r : lo_w;
        hi_w = lhi ? hi_w : r;
      };
      mix(wh[0], wh[2]); mix(wh[1], wh[3]); mix(wh[4], wh[6]); mix(wh[5], wh[7]);
      mix(wl[0], wl[2]); mix(wl[1], wl[3]); mix(wl[4], wl[6]); mix(wl[5], wl[7]);

      char* pb = PAsm + pqt * 4096;
      *(uint4*)(pb + 0 * 1024 + lane * 16) = make_uint4(wh[0], wh[1], wh[2], wh[3]);
      *(uint4*)(pb + 1 * 1024 + lane * 16) = make_uint4(wh[4], wh[5], wh[6], wh[7]);
      *(uint4*)(pb + 2 * 1024 + lane * 16) = make_uint4(wl[0], wl[1], wl[2], wl[3]);
      *(uint4*)(pb + 3 * 1024 + lane * 16) = make_uint4(wl[4], wl[5], wl[6], wl[7]);
      if (lane < 32) Ssc[pqt][lrow] = sc;
    }
    asm volatile("s_waitcnt lgkmcnt(0)" ::: "memory");
    SCHED0();
    SBAR(); MEMFENCE();

    // ---- all waves: fetch P for BOTH qt + rescale ----
    U4B8 pah0[2], pah1[2], pal0[2], pal1[2];
#pragma unroll
    for (int qt = 0; qt < 2; ++qt) {
      const char* pb = PAsm + qt * 4096;
      pah0[qt].u = *(const uint4*)(pb + 0 * 1024 + lane * 16);
      pah1[qt].u = *(const uint4*)(pb + 1 * 1024 + lane * 16);
      pal0[qt].u = *(const uint4*)(pb + 2 * 1024 + lane * 16);
      pal1[qt].u = *(const uint4*)(pb + 3 * 1024 + lane * 16);
    }
#pragma unroll
    for (int qt = 0; qt < 2; ++qt) {
      float scr[16];
#pragma unroll
      for (int r = 0; r < 16; ++r)
        scr[r] = Ssc[qt][(r & 3) + 8 * (r >> 2) + 4 * lhi];
#pragma unroll
      for (int cf = 0; cf < 2; ++cf)
#pragma unroll
        for (int r = 0; r < 16; ++r) acc[qt * 2 + cf][r] *= scr[r];
    }

    // ---- PV half A (k 0..15), shared V regs across qt ----
    __builtin_amdgcn_s_setprio(1);
#pragma unroll
    for (int qt = 0; qt < 2; ++qt)
#pragma unroll
      for (int cf = 0; cf < 2; ++cf) {
        acc[qt * 2 + cf] = __builtin_amdgcn_mfma_f32_32x32x16_bf16(pah0[qt].v, ((U4B8*)vAh)[cf].v, acc[qt * 2 + cf], 0, 0, 0);
        acc[qt * 2 + cf] = __builtin_amdgcn_mfma_f32_32x32x16_bf16(pal0[qt].v, ((U4B8*)vAh)[cf].v, acc[qt * 2 + cf], 0, 0, 0);
        acc[qt * 2 + cf] = __builtin_amdgcn_mfma_f32_32x32x16_bf16(pah0[qt].v, ((U4B8*)vAl)[cf].v, acc[qt * 2 + cf], 0, 0, 0);
      }
    __builtin_amdgcn_s_setprio(0);
    if (ch < 31) load_vA(ch + 1);

    // ---- PV half B (k 16..31) ----
    __builtin_amdgcn_s_setprio(1);
#pragma unroll
    for (int qt = 0; qt < 2; ++qt)
#pragma unroll
      for (int cf = 0; cf < 2; ++cf) {
        acc[qt * 2 + cf] = __builtin_amdgcn_mfma_f32_32x32x16_bf16(pah1[qt].v, ((U4B8*)vBh)[cf].v, acc[qt * 2 + cf], 0, 0, 0);
        acc[qt * 2 + cf] = __builtin_amdgcn_mfma_f32_32x32x16_bf16(pal1[qt].v, ((U4B8*)vBh)[cf].v, acc[qt * 2 + cf], 0, 0, 0);
        acc[qt * 2 + cf] = __builtin_amdgcn_mfma_f32_32x32x16_bf16(pah1[qt].v, ((U4B8*)vBl)[cf].v, acc[qt * 2 + cf], 0, 0, 0);
      }
    __builtin_amdgcn_s_setprio(0);
    if (ch < 31) {
      load_vB(ch + 1);
      // outstanding: K(ch+1) x2 oldest + vA4 + vB4 = 10 -> drain K only
      SCHED0();
      asm volatile("s_waitcnt vmcnt(8)" ::: "memory");
      SBAR(); MEMFENCE();
    }
  }

  // ---- epilogue: share 1/l, normalize + store both qt ----
  if (prod && lane < 32) Slinv[pqt][lrow] = 1.0f / l_run;
  asm volatile("s_waitcnt lgkmcnt(0)" ::: "memory");
  SBAR(); MEMFENCE();
#pragma unroll
  for (int qt = 0; qt < 2; ++qt) {
    float lr[16];
#pragma unroll
    for (int r = 0; r < 16; ++r)
      lr[r] = Slinv[qt][(r & 3) + 8 * (r >> 2) + 4 * lhi];
#pragma unroll
    for (int cf = 0; cf < 2; ++cf) {
      const int c = w * 64 + cf * 32 + lrow;
      const int m = c >> 6, dd = c & 63;
#pragma unroll
      for (int r = 0; r < 16; ++r) {
        const int qr = (r & 3) + 8 * (r >> 2) + 4 * lhi;
        const int srow = qb64 + qt * 32 + qr;
        const size_t off = (((size_t)(b * S_ + srow)) * 8 + m) * 512 + h * 64 + dd;
        ao[off] = acc[qt * 2 + cf][r] * lr[r];
      }
    }
  }
}

// ---------------------------------------------------------------------------
// k_out MFMA (unchanged from R10).
// ---------------------------------------------------------------------------
__global__ __launch_bounds__(256) void k_out(
    const float* __restrict__ ao, const float* __restrict__ Wo,
    const float* __restrict__ Ww, const float* __restrict__ qlw,
    float* __restrict__ out)
{
  const int tid = threadIdx.x;
  const int w = tid >> 6, lane = tid & 63;
  const int lrow = lane & 31, lhi = lane >> 5;
  const int Rblk = blockIdx.x * 128;

  __shared__ __align__(16) char WoF[4][2][2][1024];
  __shared__ __align__(16) float Os[128 * 68];

  f32x16 acc[2];
#pragma unroll
  for (int i = 0; i < 2; ++i)
#pragma unroll
    for (int r = 0; r < 16; ++r) acc[i][r] = 0.f;

  const float* brow = ao + (size_t)(Rblk + w * 32 + lrow) * 512;

  for (int chunk = 0; chunk < 8; ++chunk) {
    __syncthreads();
#pragma unroll
    for (int dt = 0; dt < 2; ++dt) {
      const float* wp = Wo + (size_t)(dt * 32 + lrow) * 512 + (chunk * 4 + w) * 16 + lhi * 8;
      float v[8];
      const float4 a = *(const float4*)wp;
      const float4 b2 = *(const float4*)(wp + 4);
      v[0] = a.x; v[1] = a.y; v[2] = a.z; v[3] = a.w;
      v[4] = b2.x; v[5] = b2.y; v[6] = b2.z; v[7] = b2.w;
      unsigned hw[4], lw2[4];
      split8(v, hw, lw2);
      *(uint4*)&WoF[w][dt][0][lane * 16] = make_uint4(hw[0], hw[1], hw[2], hw[3]);
      *(uint4*)&WoF[w][dt][1][lane * 16] = make_uint4(lw2[0], lw2[1], lw2[2], lw2[3]);
    }
    __syncthreads();

#pragma unroll
    for (int kl = 0; kl < 4; ++kl) {
      float v[8];
      const float4 a = *(const float4*)(brow + (chunk * 4 + kl) * 16 + lhi * 8);
      const float4 b2 = *(const float4*)(brow + (chunk * 4 + kl) * 16 + lhi * 8 + 4);
      v[0] = a.x; v[1] = a.y; v[2] = a.z; v[3] = a.w;
      v[4] = b2.x; v[5] = b2.y; v[6] = b2.z; v[7] = b2.w;
      unsigned bhw[4], blw[4];
      split8(v, bhw, blw);
      U4B8 bh2, bl2;
      bh2.u = make_uint4(bhw[0], bhw[1], bhw[2], bhw[3]);
      bl2.u = make_uint4(blw[0], blw[1], blw[2], blw[3]);
      __builtin_amdgcn_s_setprio(1);
#pragma unroll
      for (int dt = 0; dt < 2; ++dt) {
        U4B8 ah, al;
        ah.u = *(const uint4*)&WoF[kl][dt][0][lane * 16];
        al.u = *(const uint4*)&WoF[kl][dt][1][lane * 16];
        acc[dt] = __builtin_amdgcn_mfma_f32_32x32x16_bf16(ah.v, bh2.v, acc[dt], 0, 0, 0);
        acc[dt] = __builtin_amdgcn_mfma_f32_32x32x16_bf16(al.v, bh2.v, acc[dt], 0, 0, 0);
        acc[dt] = __builtin_amdgcn_mfma_f32_32x32x16_bf16(ah.v, bl2.v, acc[dt], 0, 0, 0);
      }
      __builtin_amdgcn_s_setprio(0);
    }
  }

  __syncthreads();
#pragma unroll
  for (int dt = 0; dt < 2; ++dt)
#pragma unroll
    for (int r = 0; r < 16; ++r) {
      const int d = dt * 32 + (r & 3) + 8 * (r >> 2) + 4 * lhi;
      Os[(w * 32 + lrow) * 68 + d] = acc[dt][r];
    }
  __syncthreads();

#pragma unroll
  for (int jj = 0; jj < 8; ++jj) {
    const int i = tid + 256 * jj;
    const int r = i >> 4, c4 = (i & 15) * 4;
    const float4 v = *(const float4*)&Os[r * 68 + c4];
    *(float4*)&out[(size_t)(Rblk + r) * 64 + c4] = v;
  }

#pragma unroll
  for (int gi = 0; gi < 4; ++gi) {
    const int g = w * 4 + gi;
    float mean = 0.f;
#pragma unroll
    for (int m = 0; m < 8; ++m) mean += Os[(g * 8 + m) * 68 + lane];
    mean *= 0.125f;
    float dsel = 0.f;
#pragma unroll
    for (int mw = 0; mw < 8; ++mw) {
      float part = mean * Ww[mw * 64 + lane];
      part += __shfl_xor(part, 1);
      part += __shfl_xor(part, 2);
      part += __shfl_xor(part, 4);
      part += __shfl_xor(part, 8);
      part += __shfl_xor(part, 16);
      part += __shfl_xor(part, 32);
      if (lane == mw) dsel = part;
    }
    if (lane < 8) {
      const int idx = Rblk + g * 8 + lane;
      out[1048576 + idx] = qlw[idx] + dsel;
    }
  }
}

// ---------------------------------------------------------------------------
extern "C" void kernel_launch(void* const* d_in, const int* in_sizes, int n_in,
                              void* d_out, int out_size, void* d_ws, size_t ws_size,
                              hipStream_t stream)
{
  const float* q_atoms = (const float*)d_in[0];
  const float* q_logw  = (const float*)d_in[1];
  const float* k_atoms = (const float*)d_in[2];
  const float* k_logw  = (const float*)d_in[3];
  const float* v_atoms = (const float*)d_in[4];
  const float* cosT  = (const float*)d_in[6];
  const float* sinT  = (const float*)d_in[7];
  const float* Wq    = (const float*)d_in[8];
  const float* Wk    = (const float*)d_in[9];
  const float* Wv    = (const float*)d_in[10];
  const float* Wo    = (const float*)d_in[11];
  const float* Ww    = (const float*)d_in[12];
  const float* logbw = (const float*)d_in[13];
  const float* rffb  = (const float*)d_in[14];
  float* out = (float*)d_out;

  char* wsb = (char*)d_ws;
  char* qrh = wsb;
  char* qrl = wsb + (4u << 20);
  char* krh = wsb + (8u << 20);
  char* krl = wsb + (12u << 20);
  char* vthi = wsb + (16u << 20);
  char* vtlo = wsb + (32u << 20);
  float* ao = (float*)(wsb + (48u << 20));

  const dim3 blk(256);
  k_proj_rff<<<dim3(16, 8, 4), blk, 0, stream>>>(q_atoms, q_logw, k_atoms, k_logw,
                                                 Wq, Wk, rffb, logbw, cosT, sinT,
                                                 qrh, qrl, krh, krl);
  k_proj_v  <<<dim3(128, 8, 2), blk, 0, stream>>>(v_atoms, Wv, vthi, vtlo);
  k_flash   <<<dim3(256), dim3(512), 0, stream>>>((const unsigned short*)qrh, (const unsigned short*)qrl,
                                                  krh, krl, vthi, vtlo, ao);
  k_out     <<<dim3(128), blk, 0, stream>>>(ao, Wo, Ww, q_logw, out);
}

// Round 12
// 181.686 us; speedup vs baseline: 4.5112x; 1.0590x over previous
//
#include <hip/hip_runtime.h>
#include <math.h>

// KME attention. B=2 S=1024 M=8 D=64 H=8 NF=64
// Round 12:
//  - k_flash: 512 blocks x 256 threads (32 q rows/block, 1 producer wave +
//    4x128-col PV waves, P-share, K dbuf 32KB, LDS 36.5KB) -> 2 blocks/CU;
//    cross-block TLP hides the producer-phase barrier bubbles.
//  - k_proj_v: MFMA-ized (proj_rff GEMM1 clone + unchanged split/transpose
//    writer, wave-local T bounce).
//
// ws layout (bytes), 80 MiB total:
//   qrh  @ 0MB   4MB  ushort [bh][s][128]          (natural)
//   qrl  @ 4MB   4MB
//   krh  @ 8MB   4MB  swizzled-chunk layout [bh][ch=32][8192B]
//   krl  @12MB   4MB
//   vthi @16MB  16MB  [bh][ch=32][half=2][c=512][32B], inner=c*32+part2*16
//   vtlo @32MB  16MB
//   ao   @48MB  32MB  f32 [b][s][m][512]

#define B_ 2
#define S_ 1024
#define H_ 8

typedef __attribute__((ext_vector_type(8))) short short8;
typedef __attribute__((ext_vector_type(16))) float f32x16;
union U4B8 { uint4 u; short8 v; };

#define SBAR() __builtin_amdgcn_s_barrier()
#define SCHED0() __builtin_amdgcn_sched_barrier(0)
#define MEMFENCE() asm volatile("" ::: "memory")

__device__ inline unsigned cvt_pk_bf16(float a, float b) {
  unsigned r;
  asm("v_cvt_pk_bf16_f32 %0, %1, %2" : "=v"(r) : "v"(a), "v"(b));
  return r;
}
__device__ inline void bsplit(float v, unsigned short &h, unsigned short &l) {
  unsigned hw = cvt_pk_bf16(v, 0.f);
  float hf = __uint_as_float(hw << 16);
  unsigned lw = cvt_pk_bf16(v - hf, 0.f);
  h = (unsigned short)hw; l = (unsigned short)lw;
}
__device__ inline void split8(const float* v, unsigned* hw, unsigned* lw) {
#pragma unroll
  for (int p = 0; p < 4; ++p) {
    const float a = v[2 * p], b = v[2 * p + 1];
    const unsigned h = cvt_pk_bf16(a, b);
    const float ra = a - __uint_as_float(h << 16);
    const float rb = b - __uint_as_float(h & 0xffff0000u);
    hw[p] = h;
    lw[p] = cvt_pk_bf16(ra, rb);
  }
}

// ---------------------------------------------------------------------------
// MFMA projection + RoPE + RFF encode (unchanged from R8).
// ---------------------------------------------------------------------------
__global__ __launch_bounds__(256, 2) void k_proj_rff(
    const float* __restrict__ q_atoms, const float* __restrict__ q_logw,
    const float* __restrict__ k_atoms, const float* __restrict__ k_logw,
    const float* __restrict__ Wq, const float* __restrict__ Wk,
    const float* __restrict__ freqb, const float* __restrict__ logbw,
    const float* __restrict__ cosT, const float* __restrict__ sinT,
    char* __restrict__ qoh, char* __restrict__ qol,
    char* __restrict__ koh, char* __restrict__ kol)
{
  const int sblk = blockIdx.x * 64;
  const int h = blockIdx.y, z = blockIdx.z;
  const int qk = z >> 1, b = z & 1;
  const float* atoms = qk ? k_atoms : q_atoms;
  const float* logw  = qk ? k_logw : q_logw;
  const float* W     = qk ? Wk : Wq;
  char* oh = qk ? koh : qoh;
  char* ol = qk ? kol : qol;

  const int tid = threadIdx.x;
  const int w = tid >> 6, lane = tid & 63;
  const int lrow = lane & 31, lhi = lane >> 5;

  __shared__ float Cs[64 * 65];
  __shared__ float Sn[64 * 65];
  __shared__ float Wm[64 * 8];
  __shared__ __align__(16) char FT[2][4][2][1024];
  __shared__ __align__(16) char Ob[4][2][1024];

  for (int i = tid; i < 4096; i += 256) {
    const int sl = i >> 6, d = i & 63;
    Cs[sl * 65 + d] = cosT[(sblk + sl) * 64 + d];
    Sn[sl * 65 + d] = sinT[(sblk + sl) * 64 + d];
  }
  if (tid < 64) {
    const float* lw = logw + (size_t)(b * S_ + sblk + tid) * 8;
    float mx = lw[0];
    for (int m = 1; m < 8; ++m) mx = fmaxf(mx, lw[m]);
    float e[8], sum = 0.f;
    for (int m = 0; m < 8; ++m) { e[m] = __expf(lw[m] - mx); sum += e[m]; }
    const float inv = 1.0f / sum;
    for (int m = 0; m < 8; ++m) Wm[tid * 8 + m] = e[m] * inv;
  }
  const float fscale = __expf(-logbw[h]);
  {
    const int ftw = w & 1;
#pragma unroll
    for (int kk = 0; kk < 2; ++kk) {
      const int ks2 = (w >> 1) + kk * 2;
      float v[8];
#pragma unroll
      for (int j = 0; j < 8; ++j)
        v[j] = freqb[h * 4096 + (ks2 * 16 + lhi * 8 + j) * 64 + ftw * 32 + lrow] * fscale;
      unsigned hw[4], lw2[4];
      split8(v, hw, lw2);
      *(uint4*)&FT[ftw][ks2][0][lane * 16] = make_uint4(hw[0], hw[1], hw[2], hw[3]);
      *(uint4*)&FT[ftw][ks2][1][lane * 16] = make_uint4(lw2[0], lw2[1], lw2[2], lw2[3]);
    }
  }
  unsigned wAh[2][4][4], wAl[2][4][4];
#pragma unroll
  for (int wt = 0; wt < 2; ++wt)
#pragma unroll
    for (int ks = 0; ks < 4; ++ks) {
      const float* wp = W + h * 4096 + (wt * 32 + lrow) * 64 + ks * 16 + lhi * 8;
      float v[8];
      const float4 a = *(const float4*)wp;
      const float4 b2 = *(const float4*)(wp + 4);
      v[0] = a.x; v[1] = a.y; v[2] = a.z; v[3] = a.w;
      v[4] = b2.x; v[5] = b2.y; v[6] = b2.z; v[7] = b2.w;
      split8(v, wAh[wt][ks], wAl[wt][ks]);
    }
  __syncthreads();

  const int bh = b * H_ + h;
  char* obh = &Ob[w][0][0];
  char* obl = &Ob[w][1][0];

  for (int it = 0; it < 4; ++it) {
    const int t = w * 4 + it;
    const float* arow = atoms + ((size_t)(b * S_ + sblk) * 8 + t * 32 + lrow) * 64;
    unsigned aBh[4][4], aBl[4][4];
#pragma unroll
    for (int ks = 0; ks < 4; ++ks) {
      float v[8];
      const float4 a = *(const float4*)(arow + ks * 16 + lhi * 8);
      const float4 b2 = *(const float4*)(arow + ks * 16 + lhi * 8 + 4);
      v[0] = a.x; v[1] = a.y; v[2] = a.z; v[3] = a.w;
      v[4] = b2.x; v[5] = b2.y; v[6] = b2.z; v[7] = b2.w;
      split8(v, aBh[ks], aBl[ks]);
    }

    f32x16 y0, y1;
#pragma unroll
    for (int r = 0; r < 16; ++r) { y0[r] = 0.f; y1[r] = 0.f; }
    __builtin_amdgcn_s_setprio(1);
#pragma unroll
    for (int ks = 0; ks < 4; ++ks) {
      U4B8 a0h, a0l, a1h, a1l, bh2, bl2;
      a0h.u = make_uint4(wAh[0][ks][0], wAh[0][ks][1], wAh[0][ks][2], wAh[0][ks][3]);
      a0l.u = make_uint4(wAl[0][ks][0], wAl[0][ks][1], wAl[0][ks][2], wAl[0][ks][3]);
      a1h.u = make_uint4(wAh[1][ks][0], wAh[1][ks][1], wAh[1][ks][2], wAh[1][ks][3]);
      a1l.u = make_uint4(wAl[1][ks][0], wAl[1][ks][1], wAl[1][ks][2], wAl[1][ks][3]);
      bh2.u = make_uint4(aBh[ks][0], aBh[ks][1], aBh[ks][2], aBh[ks][3]);
      bl2.u = make_uint4(aBl[ks][0], aBl[ks][1], aBl[ks][2], aBl[ks][3]);
      y0 = __builtin_amdgcn_mfma_f32_32x32x16_bf16(a0h.v, bh2.v, y0, 0, 0, 0);
      y1 = __builtin_amdgcn_mfma_f32_32x32x16_bf16(a1h.v, bh2.v, y1, 0, 0, 0);
      y0 = __builtin_amdgcn_mfma_f32_32x32x16_bf16(a0l.v, bh2.v, y0, 0, 0, 0);
      y1 = __builtin_amdgcn_mfma_f32_32x32x16_bf16(a1l.v, bh2.v, y1, 0, 0, 0);
      y0 = __builtin_amdgcn_mfma_f32_32x32x16_bf16(a0h.v, bl2.v, y0, 0, 0, 0);
      y1 = __builtin_amdgcn_mfma_f32_32x32x16_bf16(a1h.v, bl2.v, y1, 0, 0, 0);
    }
    __builtin_amdgcn_s_setprio(0);

    const int sloc = t * 4 + (lrow >> 3);
    const int sld = sloc * 65;
    float yr0[16], yr1[16];
#pragma unroll
    for (int r = 0; r < 16; ++r) {
      const int dd = (r & 3) + 8 * (r >> 2) + 4 * lhi;
      const float c0 = Cs[sld + dd],      s0v = Sn[sld + dd];
      const float c1 = Cs[sld + dd + 32], s1v = Sn[sld + dd + 32];
      yr0[r] = y0[r] * c0 - y1[r] * s0v;
      yr1[r] = y1[r] * c1 + y0[r] * s1v;
    }

    unsigned Bh[4][4], Bl[4][4];
    {
      const float* src[2] = { yr0, yr1 };
#pragma unroll
      for (int st = 0; st < 2; ++st) {
#pragma unroll
        for (int half = 0; half < 2; ++half) {
          const int ks2 = st * 2 + half;
          const float* q = src[st] + half * 8;
          unsigned ph[4], pl[4];
          split8(q, ph, pl);
          {
            const unsigned t0 = lhi ? ph[0] : ph[2];
            const unsigned r0 = (unsigned)__shfl_xor((int)t0, 32);
            const unsigned t1 = lhi ? ph[1] : ph[3];
            const unsigned r1 = (unsigned)__shfl_xor((int)t1, 32);
            Bh[ks2][0] = lhi ? r0 : ph[0];
            Bh[ks2][1] = lhi ? r1 : ph[1];
            Bh[ks2][2] = lhi ? ph[2] : r0;
            Bh[ks2][3] = lhi ? ph[3] : r1;
          }
          {
            const unsigned t0 = lhi ? pl[0] : pl[2];
            const unsigned r0 = (unsigned)__shfl_xor((int)t0, 32);
            const unsigned t1 = lhi ? pl[1] : pl[3];
            const unsigned r1 = (unsigned)__shfl_xor((int)t1, 32);
            Bl[ks2][0] = lhi ? r0 : pl[0];
            Bl[ks2][1] = lhi ? r1 : pl[1];
            Bl[ks2][2] = lhi ? pl[2] : r0;
            Bl[ks2][3] = lhi ? pl[3] : r1;
          }
        }
      }
    }

    f32x16 d0, d1;
#pragma unroll
    for (int r = 0; r < 16; ++r) { d0[r] = 0.f; d1[r] = 0.f; }
    __builtin_amdgcn_s_setprio(1);
#pragma unroll
    for (int ks2 = 0; ks2 < 4; ++ks2) {
      U4B8 a0h, a0l, a1h, a1l, bh2, bl2;
      a0h.u = *(const uint4*)&FT[0][ks2][0][lane * 16];
      a0l.u = *(const uint4*)&FT[0][ks2][1][lane * 16];
      a1h.u = *(const uint4*)&FT[1][ks2][0][lane * 16];
      a1l.u = *(const uint4*)&FT[1][ks2][1][lane * 16];
      bh2.u = make_uint4(Bh[ks2][0], Bh[ks2][1], Bh[ks2][2], Bh[ks2][3]);
      bl2.u = make_uint4(Bl[ks2][0], Bl[ks2][1], Bl[ks2][2], Bl[ks2][3]);
      d0 = __builtin_amdgcn_mfma_f32_32x32x16_bf16(a0h.v, bh2.v, d0, 0, 0, 0);
      d1 = __builtin_amdgcn_mfma_f32_32x32x16_bf16(a1h.v, bh2.v, d1, 0, 0, 0);
      d0 = __builtin_amdgcn_mfma_f32_32x32x16_bf16(a0l.v, bh2.v, d0, 0, 0, 0);
      d1 = __builtin_amdgcn_mfma_f32_32x32x16_bf16(a1l.v, bh2.v, d1, 0, 0, 0);
      d0 = __builtin_amdgcn_mfma_f32_32x32x16_bf16(a0h.v, bl2.v, d0, 0, 0, 0);
      d1 = __builtin_amdgcn_mfma_f32_32x32x16_bf16(a1h.v, bl2.v, d1, 0, 0, 0);
    }
    __builtin_amdgcn_s_setprio(0);

    const float wt = Wm[sloc * 8 + (lrow & 7)];
    float oc[32], os[32];
#pragma unroll
    for (int r = 0; r < 32; ++r) {
      const float pr = (r < 16) ? d0[r] : d1[r - 16];
      float sv, cv;
      __sincosf(pr, &sv, &cv);
      oc[r] = wt * cv;
      os[r] = wt * sv;
    }
#pragma unroll
    for (int r = 0; r < 32; ++r) {
      oc[r] += __shfl_xor(oc[r], 1); os[r] += __shfl_xor(os[r], 1);
      oc[r] += __shfl_xor(oc[r], 2); os[r] += __shfl_xor(os[r], 2);
      oc[r] += __shfl_xor(oc[r], 4); os[r] += __shfl_xor(os[r], 4);
    }

    const int m = lrow & 7, srel = lrow >> 3;
#pragma unroll
    for (int rr2 = 0; rr2 < 4; ++rr2) {
      const int r = m * 4 + rr2;
      const int f = (r & 3) + 8 * ((r >> 2) & 3) + 4 * lhi + ((r >> 4) << 5);
      unsigned short hh, ll;
      bsplit(oc[r] * 0.125f, hh, ll);
      *(unsigned short*)(obh + srel * 256 + f * 2) = hh;
      *(unsigned short*)(obl + srel * 256 + f * 2) = ll;
      bsplit(os[r] * 0.125f, hh, ll);
      *(unsigned short*)(obh + srel * 256 + 128 + f * 2) = hh;
      *(unsigned short*)(obl + srel * 256 + 128 + f * 2) = ll;
    }
    const uint4 vh = *(const uint4*)(obh + lane * 16);
    const uint4 vl = *(const uint4*)(obl + lane * 16);
    const int srow = sblk + t * 4 + (lane >> 4);
    if (!qk) {
      const size_t off = ((size_t)bh * S_ + srow) * 256 + (lane & 15) * 16;
      *(uint4*)(oh + off) = vh;
      *(uint4*)(ol + off) = vl;
    } else {
      const int klr = srow & 31, ch = srow >> 5;
      const unsigned inner = (unsigned)(((klr << 8) + (lane & 15) * 16) ^ ((klr & 7) << 4));
      const size_t off = (size_t)bh * 262144 + (size_t)ch * 8192 + inner;
      *(uint4*)(oh + off) = vh;
      *(uint4*)(ol + off) = vl;
    }
  }
}

// ---------------------------------------------------------------------------
// V projection, MFMA (GEMM1 clone). Block = (b,h, 64 s). 4 waves x 4 tiles.
// Wave-local T bounce [8 s][520]; writer formulas unchanged from R11.
// ---------------------------------------------------------------------------
__global__ __launch_bounds__(256) void k_proj_v(
    const float* __restrict__ atoms, const float* __restrict__ W,
    char* __restrict__ vthi, char* __restrict__ vtlo)
{
  const int sblk = blockIdx.x * 64;
  const int h = blockIdx.y, b = blockIdx.z;
  const int tid = threadIdx.x;
  const int w = tid >> 6, lane = tid & 63;
  const int lrow = lane & 31, lhi = lane >> 5;

  __shared__ __align__(16) float T[4][8 * 520];

  unsigned wAh[2][4][4], wAl[2][4][4];
#pragma unroll
  for (int wt = 0; wt < 2; ++wt)
#pragma unroll
    for (int ks = 0; ks < 4; ++ks) {
      const float* wp = W + h * 4096 + (wt * 32 + lrow) * 64 + ks * 16 + lhi * 8;
      float v[8];
      const float4 a = *(const float4*)wp;
      const float4 b2 = *(const float4*)(wp + 4);
      v[0] = a.x; v[1] = a.y; v[2] = a.z; v[3] = a.w;
      v[4] = b2.x; v[5] = b2.y; v[6] = b2.z; v[7] = b2.w;
      split8(v, wAh[wt][ks], wAl[wt][ks]);
    }

  const int bh = b * H_ + h;
  float* Tw = &T[w][0];

  for (int p = 0; p < 2; ++p) {
#pragma unroll
    for (int half8 = 0; half8 < 2; ++half8) {
      const int t = w * 4 + p * 2 + half8;
      const float* arow = atoms + ((size_t)(b * S_ + sblk) * 8 + t * 32 + lrow) * 64;
      unsigned aBh[4][4], aBl[4][4];
#pragma unroll
      for (int ks = 0; ks < 4; ++ks) {
        float v[8];
        const float4 a = *(const float4*)(arow + ks * 16 + lhi * 8);
        const float4 b2 = *(const float4*)(arow + ks * 16 + lhi * 8 + 4);
        v[0] = a.x; v[1] = a.y; v[2] = a.z; v[3] = a.w;
        v[4] = b2.x; v[5] = b2.y; v[6] = b2.z; v[7] = b2.w;
        split8(v, aBh[ks], aBl[ks]);
      }

      f32x16 y0, y1;
#pragma unroll
      for (int r = 0; r < 16; ++r) { y0[r] = 0.f; y1[r] = 0.f; }
      __builtin_amdgcn_s_setprio(1);
#pragma unroll
      for (int ks = 0; ks < 4; ++ks) {
        U4B8 a0h, a0l, a1h, a1l, bh2, bl2;
        a0h.u = make_uint4(wAh[0][ks][0], wAh[0][ks][1], wAh[0][ks][2], wAh[0][ks][3]);
        a0l.u = make_uint4(wAl[0][ks][0], wAl[0][ks][1], wAl[0][ks][2], wAl[0][ks][3]);
        a1h.u = make_uint4(wAh[1][ks][0], wAh[1][ks][1], wAh[1][ks][2], wAh[1][ks][3]);
        a1l.u = make_uint4(wAl[1][ks][0], wAl[1][ks][1], wAl[1][ks][2], wAl[1][ks][3]);
        bh2.u = make_uint4(aBh[ks][0], aBh[ks][1], aBh[ks][2], aBh[ks][3]);
        bl2.u = make_uint4(aBl[ks][0], aBl[ks][1], aBl[ks][2], aBl[ks][3]);
        y0 = __builtin_amdgcn_mfma_f32_32x32x16_bf16(a0h.v, bh2.v, y0, 0, 0, 0);
        y1 = __builtin_amdgcn_mfma_f32_32x32x16_bf16(a1h.v, bh2.v, y1, 0, 0, 0);
        y0 = __builtin_amdgcn_mfma_f32_32x32x16_bf16(a0l.v, bh2.v, y0, 0, 0, 0);
        y1 = __builtin_amdgcn_mfma_f32_32x32x16_bf16(a1l.v, bh2.v, y1, 0, 0, 0);
        y0 = __builtin_amdgcn_mfma_f32_32x32x16_bf16(a0h.v, bl2.v, y0, 0, 0, 0);
        y1 = __builtin_amdgcn_mfma_f32_32x32x16_bf16(a1h.v, bl2.v, y1, 0, 0, 0);
      }
      __builtin_amdgcn_s_setprio(0);

      const int s_in = half8 * 4 + (lrow >> 3);
      const int m = lrow & 7;
#pragma unroll
      for (int r = 0; r < 16; ++r) {
        const int dd = (r & 3) + 8 * (r >> 2) + 4 * lhi;
        Tw[s_in * 520 + m * 64 + dd] = y0[r];
        Tw[s_in * 520 + m * 64 + dd + 32] = y1[r];
      }
    }
    // wave-local writer for this 8-s group (in-order LDS within wave)
    const int s0 = sblk + w * 16 + p * 8;
    const int ch = s0 >> 5, half = (s0 >> 4) & 1, part2 = (s0 >> 3) & 1;
    const size_t base = (size_t)bh * 1048576 + (size_t)ch * 32768 + half * 16384;
#pragma unroll
    for (int j = 0; j < 8; ++j) {
      const int c = j * 64 + lane;
      float v[8];
#pragma unroll
      for (int s = 0; s < 8; ++s) v[s] = Tw[s * 520 + c];
      unsigned hw[4], lw[4];
      split8(v, hw, lw);
      const unsigned inner = (unsigned)(c * 32 + part2 * 16);
      *(uint4*)(vthi + base + inner) = make_uint4(hw[0], hw[1], hw[2], hw[3]);
      *(uint4*)(vtlo + base + inner) = make_uint4(lw[0], lw[1], lw[2], lw[3]);
    }
  }
}

// ---------------------------------------------------------------------------
// MFMA flash attention. 512 blocks x 256 threads: block = (bh, 32 q rows).
// w0 = producer (scores/softmax/repack -> P-share LDS) + PV; 4 waves own
// 128 cols each. K dbuf 32KB via global_load_lds; V in regs (dbuf).
// LDS 36.5KB + launch_bounds(256,2) -> 2 blocks/CU (cross-block TLP hides
// producer-phase barrier bubbles).
// ---------------------------------------------------------------------------
__global__ __launch_bounds__(256, 2) void k_flash(
    const unsigned short* __restrict__ qrh, const unsigned short* __restrict__ qrl,
    const char* __restrict__ krh, const char* __restrict__ krl,
    const char* __restrict__ vthi, const char* __restrict__ vtlo,
    float* __restrict__ ao)
{
  __shared__ __align__(16) char Ksm[32768];
  __shared__ __align__(16) char PAsm[4096];
  __shared__ float Ssc[32];
  __shared__ float Slinv[32];

  char* Khi0 = Ksm;
  char* Klo0 = Ksm + 8192;
  char* Khi1 = Ksm + 16384;
  char* Klo1 = Ksm + 24576;

  const int tid = threadIdx.x;
  const int w = tid >> 6, lane = tid & 63;
  const int lrow = lane & 31, lhi = lane >> 5;
  const bool prod = (w == 0);

  const int phys = blockIdx.x;
  const int x = phys & 7, j = phys >> 3;          // x = XCD
  const int bh = (x << 1) | (j >> 5);             // 2 bh per XCD
  const int qb = j & 31;
  const int b = bh >> 3, h = bh & 7;
  const int qbase = qb * 32;

  // Q fragments: producer only
  uint4 qfh[8], qfl[8];
  if (prod) {
    const size_t rowb = ((size_t)bh * S_ + qbase + lrow) * 128;
#pragma unroll
    for (int fs = 0; fs < 8; ++fs) {
      const size_t e = rowb + fs * 16 + lhi * 8;
      qfh[fs] = *(const uint4*)(qrh + e);
      qfl[fs] = *(const uint4*)(qrl + e);
    }
  }

  const char* vh_c = vthi + (size_t)bh * 1048576;
  const char* vl_c = vtlo + (size_t)bh * 1048576;
  const char* kh_c = krh + (size_t)bh * 262144;
  const char* kl_c = krl + (size_t)bh * 262144;

  auto issue_k = [&](int ch, char* dh, char* dl) {
    const size_t g = (size_t)ch * 8192;
#pragma unroll
    for (int i = 0; i < 2; ++i) {
      __builtin_amdgcn_global_load_lds(kh_c + g + i * 4096 + tid * 16, dh + i * 4096 + (w << 10), 16, 0, 0);
      __builtin_amdgcn_global_load_lds(kl_c + g + i * 4096 + tid * 16, dl + i * 4096 + (w << 10), 16, 0, 0);
    }
  };

  // wave owns 128 cols: c = w*128 + cf*32 + lrow, cf in 0..3
  const unsigned vbase = (unsigned)((w * 128 + lrow) * 32 + lhi * 16);
  uint4 vAh[4], vAl[4], vBh[4], vBl[4];
  auto load_vA = [&](int ch) {
    const size_t g = (size_t)ch * 32768 + vbase;
#pragma unroll
    for (int cf = 0; cf < 4; ++cf) {
      vAh[cf] = *(const uint4*)(vh_c + g + cf * 1024);
      vAl[cf] = *(const uint4*)(vl_c + g + cf * 1024);
    }
  };
  auto load_vB = [&](int ch) {
    const size_t g = (size_t)ch * 32768 + 16384 + vbase;
#pragma unroll
    for (int cf = 0; cf < 4; ++cf) {
      vBh[cf] = *(const uint4*)(vh_c + g + cf * 1024);
      vBl[cf] = *(const uint4*)(vl_c + g + cf * 1024);
    }
  };

  f32x16 acc[4];
#pragma unroll
  for (int i = 0; i < 4; ++i)
#pragma unroll
    for (int r = 0; r < 16; ++r) acc[i][r] = 0.f;
  float m_run = -1e30f, l_run = 0.f;

  issue_k(0, Khi0, Klo0);          // 4 loads
  load_vA(0);                      // 8
  load_vB(0);                      // 8
  asm volatile("s_waitcnt vmcnt(16)" ::: "memory");   // K(0) landed
  SBAR(); MEMFENCE();

  for (int ch = 0; ch < 32; ++ch) {
    const char* kh = (ch & 1) ? Khi1 : Khi0;
    const char* kl = (ch & 1) ? Klo1 : Klo0;
    if (ch < 31) {
      SCHED0();
      issue_k(ch + 1, (ch & 1) ? Khi0 : Khi1, (ch & 1) ? Klo0 : Klo1);
      SCHED0();
    }

    if (prod) {
      f32x16 s0, s1;
#pragma unroll
      for (int r = 0; r < 16; ++r) { s0[r] = 0.f; s1[r] = 0.f; }
      __builtin_amdgcn_s_setprio(1);
#pragma unroll
      for (int fs = 0; fs < 8; ++fs) {
        const unsigned kaddr = (unsigned)((lrow * 256 + fs * 32 + lhi * 16) ^ ((lrow & 7) << 4));
        U4B8 khf, klf, qh, ql;
        khf.u = *(const uint4*)(kh + kaddr);
        klf.u = *(const uint4*)(kl + kaddr);
        qh.u = qfh[fs]; ql.u = qfl[fs];
        if (fs & 1) {
          s1 = __builtin_amdgcn_mfma_f32_32x32x16_bf16(khf.v, qh.v, s1, 0, 0, 0);
          s1 = __builtin_amdgcn_mfma_f32_32x32x16_bf16(klf.v, qh.v, s1, 0, 0, 0);
          s1 = __builtin_amdgcn_mfma_f32_32x32x16_bf16(khf.v, ql.v, s1, 0, 0, 0);
        } else {
          s0 = __builtin_amdgcn_mfma_f32_32x32x16_bf16(khf.v, qh.v, s0, 0, 0, 0);
          s0 = __builtin_amdgcn_mfma_f32_32x32x16_bf16(klf.v, qh.v, s0, 0, 0, 0);
          s0 = __builtin_amdgcn_mfma_f32_32x32x16_bf16(khf.v, ql.v, s0, 0, 0, 0);
        }
      }
      __builtin_amdgcn_s_setprio(0);
      float s[16];
#pragma unroll
      for (int r = 0; r < 16; ++r) s[r] = s0[r] + s1[r];

      float mx = s[0];
#pragma unroll
      for (int r = 1; r < 16; ++r) mx = fmaxf(mx, s[r]);
      mx = fmaxf(mx, __shfl_xor(mx, 32));
      float sc = 1.0f;
      if (!__all(mx <= m_run + 8.f)) {
        const float mnew = fmaxf(m_run, mx);
        sc = __expf(m_run - mnew);
        l_run *= sc;
        m_run = mnew;
      }
      float p[16];
#pragma unroll
      for (int r = 0; r < 16; ++r) p[r] = __expf(s[r] - m_run);
      float rs = 0.f;
#pragma unroll
      for (int r = 0; r < 16; ++r) rs += p[r];
      rs += __shfl_xor(rs, 32);
      l_run += rs;

      unsigned wh[8], wl[8];
#pragma unroll
      for (int i = 0; i < 8; ++i) {
        const float a = p[2 * i], c2 = p[2 * i + 1];
        const unsigned hword = cvt_pk_bf16(a, c2);
        const float ra = a - __uint_as_float(hword << 16);
        const float rc = c2 - __uint_as_float(hword & 0xffff0000u);
        wh[i] = hword;
        wl[i] = cvt_pk_bf16(ra, rc);
      }
      auto mix = [&](unsigned &lo_w, unsigned &hi_w) {
        const unsigned t = lhi ? lo_w : hi_w;
        const unsigned r = (unsigned)__shfl_xor((int)t, 32);
        lo_w = lhi ? r : lo_w;
        hi_w = lhi ? hi_w : r;
      };
      mix(wh[0], wh[2]); mix(wh[1], wh[3]); mix(wh[4], wh[6]); mix(wh[5], wh[7]);
      mix(wl[0], wl[2]); mix(wl[1], wl[3]); mix(wl[4], wl[6]); mix(wl[5], wl[7]);

      *(uint4*)(PAsm + 0 * 1024 + lane * 16) = make_uint4(wh[0], wh[1], wh[2], wh[3]);
      *(uint4*)(PAsm + 1 * 1024 + lane * 16) = make_uint4(wh[4], wh[5], wh[6], wh[7]);
      *(uint4*)(PAsm + 2 * 1024 + lane * 16) = make_uint4(wl[0], wl[1], wl[2], wl[3]);
      *(uint4*)(PAsm + 3 * 1024 + lane * 16) = make_uint4(wl[4], wl[5], wl[6], wl[7]);
      if (lane < 32) Ssc[lrow] = sc;
    }
    asm volatile("s_waitcnt lgkmcnt(0)" ::: "memory");
    SCHED0();
    SBAR(); MEMFENCE();            // P + sc visible

    U4B8 pah0, pah1, pal0, pal1;
    pah0.u = *(const uint4*)(PAsm + 0 * 1024 + lane * 16);
    pah1.u = *(const uint4*)(PAsm + 1 * 1024 + lane * 16);
    pal0.u = *(const uint4*)(PAsm + 2 * 1024 + lane * 16);
    pal1.u = *(const uint4*)(PAsm + 3 * 1024 + lane * 16);
    float scr[16];
#pragma unroll
    for (int r = 0; r < 16; ++r)
      scr[r] = Ssc[(r & 3) + 8 * (r >> 2) + 4 * lhi];
#pragma unroll
    for (int i = 0; i < 4; ++i)
#pragma unroll
      for (int r = 0; r < 16; ++r) acc[i][r] *= scr[r];

    // ---- PV half A (k 0..15) ----
    __builtin_amdgcn_s_setprio(1);
#pragma unroll
    for (int cf = 0; cf < 4; ++cf) {
      U4B8 vh, vl2;
      vh.u = vAh[cf]; vl2.u = vAl[cf];
      acc[cf] = __builtin_amdgcn_mfma_f32_32x32x16_bf16(pah0.v, vh.v,  acc[cf], 0, 0, 0);
      acc[cf] = __builtin_amdgcn_mfma_f32_32x32x16_bf16(pal0.v, vh.v,  acc[cf], 0, 0, 0);
      acc[cf] = __builtin_amdgcn_mfma_f32_32x32x16_bf16(pah0.v, vl2.v, acc[cf], 0, 0, 0);
    }
    __builtin_amdgcn_s_setprio(0);
    if (ch < 31) load_vA(ch + 1);

    // ---- PV half B (k 16..31) ----
    __builtin_amdgcn_s_setprio(1);
#pragma unroll
    for (int cf = 0; cf < 4; ++cf) {
      U4B8 vh, vl2;
      vh.u = vBh[cf]; vl2.u = vBl[cf];
      acc[cf] = __builtin_amdgcn_mfma_f32_32x32x16_bf16(pah1.v, vh.v,  acc[cf], 0, 0, 0);
      acc[cf] = __builtin_amdgcn_mfma_f32_32x32x16_bf16(pal1.v, vh.v,  acc[cf], 0, 0, 0);
      acc[cf] = __builtin_amdgcn_mfma_f32_32x32x16_bf16(pah1.v, vl2.v, acc[cf], 0, 0, 0);
    }
    __builtin_amdgcn_s_setprio(0);
    if (ch < 31) {
      load_vB(ch + 1);
      // outstanding: K(ch+1) x4 oldest + vA8 + vB8 = 20 -> drain K only
      SCHED0();
      asm volatile("s_waitcnt vmcnt(16)" ::: "memory");
      SBAR(); MEMFENCE();
    }
  }

  // ---- epilogue ----
  if (prod && lane < 32) Slinv[lrow] = 1.0f / l_run;
  asm volatile("s_waitcnt lgkmcnt(0)" ::: "memory");
  SBAR(); MEMFENCE();
  float lr[16];
#pragma unroll
  for (int r = 0; r < 16; ++r)
    lr[r] = Slinv[(r & 3) + 8 * (r >> 2) + 4 * lhi];
#pragma unroll
  for (int cf = 0; cf < 4; ++cf) {
    const int c = w * 128 + cf * 32 + lrow;
    const int m = c >> 6, dd = c & 63;
#pragma unroll
    for (int r = 0; r < 16; ++r) {
      const int qr = (r & 3) + 8 * (r >> 2) + 4 * lhi;
      const int srow = qbase + qr;
      const size_t off = (((size_t)(b * S_ + srow)) * 8 + m) * 512 + h * 64 + dd;
      ao[off] = acc[cf][r] * lr[r];
    }
  }
}

// ---------------------------------------------------------------------------
// k_out MFMA (unchanged from R10).
// ---------------------------------------------------------------------------
__global__ __launch_bounds__(256) void k_out(
    const float* __restrict__ ao, const float* __restrict__ Wo,
    const float* __restrict__ Ww, const float* __restrict__ qlw,
    float* __restrict__ out)
{
  const int tid = threadIdx.x;
  const int w = tid >> 6, lane = tid & 63;
  const int lrow = lane & 31, lhi = lane >> 5;
  const int Rblk = blockIdx.x * 128;

  __shared__ __align__(16) char WoF[4][2][2][1024];
  __shared__ __align__(16) float Os[128 * 68];

  f32x16 acc[2];
#pragma unroll
  for (int i = 0; i < 2; ++i)
#pragma unroll
    for (int r = 0; r < 16; ++r) acc[i][r] = 0.f;

  const float* brow = ao + (size_t)(Rblk + w * 32 + lrow) * 512;

  for (int chunk = 0; chunk < 8; ++chunk) {
    __syncthreads();
#pragma unroll
    for (int dt = 0; dt < 2; ++dt) {
      const float* wp = Wo + (size_t)(dt * 32 + lrow) * 512 + (chunk * 4 + w) * 16 + lhi * 8;
      float v[8];
      const float4 a = *(const float4*)wp;
      const float4 b2 = *(const float4*)(wp + 4);
      v[0] = a.x; v[1] = a.y; v[2] = a.z; v[3] = a.w;
      v[4] = b2.x; v[5] = b2.y; v[6] = b2.z; v[7] = b2.w;
      unsigned hw[4], lw2[4];
      split8(v, hw, lw2);
      *(uint4*)&WoF[w][dt][0][lane * 16] = make_uint4(hw[0], hw[1], hw[2], hw[3]);
      *(uint4*)&WoF[w][dt][1][lane * 16] = make_uint4(lw2[0], lw2[1], lw2[2], lw2[3]);
    }
    __syncthreads();

#pragma unroll
    for (int kl = 0; kl < 4; ++kl) {
      float v[8];
      const float4 a = *(const float4*)(brow + (chunk * 4 + kl) * 16 + lhi * 8);
      const float4 b2 = *(const float4*)(brow + (chunk * 4 + kl) * 16 + lhi * 8 + 4);
      v[0] = a.x; v[1] = a.y; v[2] = a.z; v[3] = a.w;
      v[4] = b2.x; v[5] = b2.y; v[6] = b2.z; v[7] = b2.w;
      unsigned bhw[4], blw[4];
      split8(v, bhw, blw);
      U4B8 bh2, bl2;
      bh2.u = make_uint4(bhw[0], bhw[1], bhw[2], bhw[3]);
      bl2.u = make_uint4(blw[0], blw[1], blw[2], blw[3]);
      __builtin_amdgcn_s_setprio(1);
#pragma unroll
      for (int dt = 0; dt < 2; ++dt) {
        U4B8 ah, al;
        ah.u = *(const uint4*)&WoF[kl][dt][0][lane * 16];
        al.u = *(const uint4*)&WoF[kl][dt][1][lane * 16];
        acc[dt] = __builtin_amdgcn_mfma_f32_32x32x16_bf16(ah.v, bh2.v, acc[dt], 0, 0, 0);
        acc[dt] = __builtin_amdgcn_mfma_f32_32x32x16_bf16(al.v, bh2.v, acc[dt], 0, 0, 0);
        acc[dt] = __builtin_amdgcn_mfma_f32_32x32x16_bf16(ah.v, bl2.v, acc[dt], 0, 0, 0);
      }
      __builtin_amdgcn_s_setprio(0);
    }
  }

  __syncthreads();
#pragma unroll
  for (int dt = 0; dt < 2; ++dt)
#pragma unroll
    for (int r = 0; r < 16; ++r) {
      const int d = dt * 32 + (r & 3) + 8 * (r >> 2) + 4 * lhi;
      Os[(w * 32 + lrow) * 68 + d] = acc[dt][r];
    }
  __syncthreads();

#pragma unroll
  for (int jj = 0; jj < 8; ++jj) {
    const int i = tid + 256 * jj;
    const int r = i >> 4, c4 = (i & 15) * 4;
    const float4 v = *(const float4*)&Os[r * 68 + c4];
    *(float4*)&out[(size_t)(Rblk + r) * 64 + c4] = v;
  }

#pragma unroll
  for (int gi = 0; gi < 4; ++gi) {
    const int g = w * 4 + gi;
    float mean = 0.f;
#pragma unroll
    for (int m = 0; m < 8; ++m) mean += Os[(g * 8 + m) * 68 + lane];
    mean *= 0.125f;
    float dsel = 0.f;
#pragma unroll
    for (int mw = 0; mw < 8; ++mw) {
      float part = mean * Ww[mw * 64 + lane];
      part += __shfl_xor(part, 1);
      part += __shfl_xor(part, 2);
      part += __shfl_xor(part, 4);
      part += __shfl_xor(part, 8);
      part += __shfl_xor(part, 16);
      part += __shfl_xor(part, 32);
      if (lane == mw) dsel = part;
    }
    if (lane < 8) {
      const int idx = Rblk + g * 8 + lane;
      out[1048576 + idx] = qlw[idx] + dsel;
    }
  }
}

// ---------------------------------------------------------------------------
extern "C" void kernel_launch(void* const* d_in, const int* in_sizes, int n_in,
                              void* d_out, int out_size, void* d_ws, size_t ws_size,
                              hipStream_t stream)
{
  const float* q_atoms = (const float*)d_in[0];
  const float* q_logw  = (const float*)d_in[1];
  const float* k_atoms = (const float*)d_in[2];
  const float* k_logw  = (const float*)d_in[3];
  const float* v_atoms = (const float*)d_in[4];
  const float* cosT  = (const float*)d_in[6];
  const float* sinT  = (const float*)d_in[7];
  const float* Wq    = (const float*)d_in[8];
  const float* Wk    = (const float*)d_in[9];
  const float* Wv    = (const float*)d_in[10];
  const float* Wo    = (const float*)d_in[11];
  const float* Ww    = (const float*)d_in[12];
  const float* logbw = (const float*)d_in[13];
  const float* rffb  = (const float*)d_in[14];
  float* out = (float*)d_out;

  char* wsb = (char*)d_ws;
  char* qrh = wsb;
  char* qrl = wsb + (4u << 20);
  char* krh = wsb + (8u << 20);
  char* krl = wsb + (12u << 20);
  char* vthi = wsb + (16u << 20);
  char* vtlo = wsb + (32u << 20);
  float* ao = (float*)(wsb + (48u << 20));

  const dim3 blk(256);
  k_proj_rff<<<dim3(16, 8, 4), blk, 0, stream>>>(q_atoms, q_logw, k_atoms, k_logw,
                                                 Wq, Wk, rffb, logbw, cosT, sinT,
                                                 qrh, qrl, krh, krl);
  k_proj_v  <<<dim3(16, 8, 2), blk, 0, stream>>>(v_atoms, Wv, vthi, vtlo);
  k_flash   <<<dim3(512), blk, 0, stream>>>((const unsigned short*)qrh, (const unsigned short*)qrl,
                                            krh, krl, vthi, vtlo, ao);
  k_out     <<<dim3(128), blk, 0, stream>>>(ao, Wo, Ww, q_logw, out);
}

// Round 13
// 174.025 us; speedup vs baseline: 4.7098x; 1.0440x over previous
//
#include <hip/hip_runtime.h>
#include <math.h>

// KME attention. B=2 S=1024 M=8 D=64 H=8 NF=64
// Round 13: k_flash exploits |q_rff|,|k_rff| <= 1 (RFF norm bound) ->
// scores in [-1,1] -> P = exp(s) directly, NO online softmax (no max tree,
// no rescale, no m_run chain). Producer pipelines P(ch+1) while all waves
// PV(ch) (P double-buffered); producer wave staggered per block (qb&3).
// Other kernels unchanged from R12.
//
// ws layout (bytes), 80 MiB total:
//   qrh  @ 0MB   4MB  ushort [bh][s][128]          (natural)
//   qrl  @ 4MB   4MB
//   krh  @ 8MB   4MB  swizzled-chunk layout [bh][ch=32][8192B]
//   krl  @12MB   4MB
//   vthi @16MB  16MB  [bh][ch=32][half=2][c=512][32B], inner=c*32+part2*16
//   vtlo @32MB  16MB
//   ao   @48MB  32MB  f32 [b][s][m][512]

#define B_ 2
#define S_ 1024
#define H_ 8

typedef __attribute__((ext_vector_type(8))) short short8;
typedef __attribute__((ext_vector_type(16))) float f32x16;
union U4B8 { uint4 u; short8 v; };

#define SBAR() __builtin_amdgcn_s_barrier()
#define SCHED0() __builtin_amdgcn_sched_barrier(0)
#define MEMFENCE() asm volatile("" ::: "memory")

__device__ inline unsigned cvt_pk_bf16(float a, float b) {
  unsigned r;
  asm("v_cvt_pk_bf16_f32 %0, %1, %2" : "=v"(r) : "v"(a), "v"(b));
  return r;
}
__device__ inline void bsplit(float v, unsigned short &h, unsigned short &l) {
  unsigned hw = cvt_pk_bf16(v, 0.f);
  float hf = __uint_as_float(hw << 16);
  unsigned lw = cvt_pk_bf16(v - hf, 0.f);
  h = (unsigned short)hw; l = (unsigned short)lw;
}
__device__ inline void split8(const float* v, unsigned* hw, unsigned* lw) {
#pragma unroll
  for (int p = 0; p < 4; ++p) {
    const float a = v[2 * p], b = v[2 * p + 1];
    const unsigned h = cvt_pk_bf16(a, b);
    const float ra = a - __uint_as_float(h << 16);
    const float rb = b - __uint_as_float(h & 0xffff0000u);
    hw[p] = h;
    lw[p] = cvt_pk_bf16(ra, rb);
  }
}

// ---------------------------------------------------------------------------
// MFMA projection + RoPE + RFF encode (unchanged from R8).
// ---------------------------------------------------------------------------
__global__ __launch_bounds__(256, 2) void k_proj_rff(
    const float* __restrict__ q_atoms, const float* __restrict__ q_logw,
    const float* __restrict__ k_atoms, const float* __restrict__ k_logw,
    const float* __restrict__ Wq, const float* __restrict__ Wk,
    const float* __restrict__ freqb, const float* __restrict__ logbw,
    const float* __restrict__ cosT, const float* __restrict__ sinT,
    char* __restrict__ qoh, char* __restrict__ qol,
    char* __restrict__ koh, char* __restrict__ kol)
{
  const int sblk = blockIdx.x * 64;
  const int h = blockIdx.y, z = blockIdx.z;
  const int qk = z >> 1, b = z & 1;
  const float* atoms = qk ? k_atoms : q_atoms;
  const float* logw  = qk ? k_logw : q_logw;
  const float* W     = qk ? Wk : Wq;
  char* oh = qk ? koh : qoh;
  char* ol = qk ? kol : qol;

  const int tid = threadIdx.x;
  const int w = tid >> 6, lane = tid & 63;
  const int lrow = lane & 31, lhi = lane >> 5;

  __shared__ float Cs[64 * 65];
  __shared__ float Sn[64 * 65];
  __shared__ float Wm[64 * 8];
  __shared__ __align__(16) char FT[2][4][2][1024];
  __shared__ __align__(16) char Ob[4][2][1024];

  for (int i = tid; i < 4096; i += 256) {
    const int sl = i >> 6, d = i & 63;
    Cs[sl * 65 + d] = cosT[(sblk + sl) * 64 + d];
    Sn[sl * 65 + d] = sinT[(sblk + sl) * 64 + d];
  }
  if (tid < 64) {
    const float* lw = logw + (size_t)(b * S_ + sblk + tid) * 8;
    float mx = lw[0];
    for (int m = 1; m < 8; ++m) mx = fmaxf(mx, lw[m]);
    float e[8], sum = 0.f;
    for (int m = 0; m < 8; ++m) { e[m] = __expf(lw[m] - mx); sum += e[m]; }
    const float inv = 1.0f / sum;
    for (int m = 0; m < 8; ++m) Wm[tid * 8 + m] = e[m] * inv;
  }
  const float fscale = __expf(-logbw[h]);
  {
    const int ftw = w & 1;
#pragma unroll
    for (int kk = 0; kk < 2; ++kk) {
      const int ks2 = (w >> 1) + kk * 2;
      float v[8];
#pragma unroll
      for (int j = 0; j < 8; ++j)
        v[j] = freqb[h * 4096 + (ks2 * 16 + lhi * 8 + j) * 64 + ftw * 32 + lrow] * fscale;
      unsigned hw[4], lw2[4];
      split8(v, hw, lw2);
      *(uint4*)&FT[ftw][ks2][0][lane * 16] = make_uint4(hw[0], hw[1], hw[2], hw[3]);
      *(uint4*)&FT[ftw][ks2][1][lane * 16] = make_uint4(lw2[0], lw2[1], lw2[2], lw2[3]);
    }
  }
  unsigned wAh[2][4][4], wAl[2][4][4];
#pragma unroll
  for (int wt = 0; wt < 2; ++wt)
#pragma unroll
    for (int ks = 0; ks < 4; ++ks) {
      const float* wp = W + h * 4096 + (wt * 32 + lrow) * 64 + ks * 16 + lhi * 8;
      float v[8];
      const float4 a = *(const float4*)wp;
      const float4 b2 = *(const float4*)(wp + 4);
      v[0] = a.x; v[1] = a.y; v[2] = a.z; v[3] = a.w;
      v[4] = b2.x; v[5] = b2.y; v[6] = b2.z; v[7] = b2.w;
      split8(v, wAh[wt][ks], wAl[wt][ks]);
    }
  __syncthreads();

  const int bh = b * H_ + h;
  char* obh = &Ob[w][0][0];
  char* obl = &Ob[w][1][0];

  for (int it = 0; it < 4; ++it) {
    const int t = w * 4 + it;
    const float* arow = atoms + ((size_t)(b * S_ + sblk) * 8 + t * 32 + lrow) * 64;
    unsigned aBh[4][4], aBl[4][4];
#pragma unroll
    for (int ks = 0; ks < 4; ++ks) {
      float v[8];
      const float4 a = *(const float4*)(arow + ks * 16 + lhi * 8);
      const float4 b2 = *(const float4*)(arow + ks * 16 + lhi * 8 + 4);
      v[0] = a.x; v[1] = a.y; v[2] = a.z; v[3] = a.w;
      v[4] = b2.x; v[5] = b2.y; v[6] = b2.z; v[7] = b2.w;
      split8(v, aBh[ks], aBl[ks]);
    }

    f32x16 y0, y1;
#pragma unroll
    for (int r = 0; r < 16; ++r) { y0[r] = 0.f; y1[r] = 0.f; }
    __builtin_amdgcn_s_setprio(1);
#pragma unroll
    for (int ks = 0; ks < 4; ++ks) {
      U4B8 a0h, a0l, a1h, a1l, bh2, bl2;
      a0h.u = make_uint4(wAh[0][ks][0], wAh[0][ks][1], wAh[0][ks][2], wAh[0][ks][3]);
      a0l.u = make_uint4(wAl[0][ks][0], wAl[0][ks][1], wAl[0][ks][2], wAl[0][ks][3]);
      a1h.u = make_uint4(wAh[1][ks][0], wAh[1][ks][1], wAh[1][ks][2], wAh[1][ks][3]);
      a1l.u = make_uint4(wAl[1][ks][0], wAl[1][ks][1], wAl[1][ks][2], wAl[1][ks][3]);
      bh2.u = make_uint4(aBh[ks][0], aBh[ks][1], aBh[ks][2], aBh[ks][3]);
      bl2.u = make_uint4(aBl[ks][0], aBl[ks][1], aBl[ks][2], aBl[ks][3]);
      y0 = __builtin_amdgcn_mfma_f32_32x32x16_bf16(a0h.v, bh2.v, y0, 0, 0, 0);
      y1 = __builtin_amdgcn_mfma_f32_32x32x16_bf16(a1h.v, bh2.v, y1, 0, 0, 0);
      y0 = __builtin_amdgcn_mfma_f32_32x32x16_bf16(a0l.v, bh2.v, y0, 0, 0, 0);
      y1 = __builtin_amdgcn_mfma_f32_32x32x16_bf16(a1l.v, bh2.v, y1, 0, 0, 0);
      y0 = __builtin_amdgcn_mfma_f32_32x32x16_bf16(a0h.v, bl2.v, y0, 0, 0, 0);
      y1 = __builtin_amdgcn_mfma_f32_32x32x16_bf16(a1h.v, bl2.v, y1, 0, 0, 0);
    }
    __builtin_amdgcn_s_setprio(0);

    const int sloc = t * 4 + (lrow >> 3);
    const int sld = sloc * 65;
    float yr0[16], yr1[16];
#pragma unroll
    for (int r = 0; r < 16; ++r) {
      const int dd = (r & 3) + 8 * (r >> 2) + 4 * lhi;
      const float c0 = Cs[sld + dd],      s0v = Sn[sld + dd];
      const float c1 = Cs[sld + dd + 32], s1v = Sn[sld + dd + 32];
      yr0[r] = y0[r] * c0 - y1[r] * s0v;
      yr1[r] = y1[r] * c1 + y0[r] * s1v;
    }

    unsigned Bh[4][4], Bl[4][4];
    {
      const float* src[2] = { yr0, yr1 };
#pragma unroll
      for (int st = 0; st < 2; ++st) {
#pragma unroll
        for (int half = 0; half < 2; ++half) {
          const int ks2 = st * 2 + half;
          const float* q = src[st] + half * 8;
          unsigned ph[4], pl[4];
          split8(q, ph, pl);
          {
            const unsigned t0 = lhi ? ph[0] : ph[2];
            const unsigned r0 = (unsigned)__shfl_xor((int)t0, 32);
            const unsigned t1 = lhi ? ph[1] : ph[3];
            const unsigned r1 = (unsigned)__shfl_xor((int)t1, 32);
            Bh[ks2][0] = lhi ? r0 : ph[0];
            Bh[ks2][1] = lhi ? r1 : ph[1];
            Bh[ks2][2] = lhi ? ph[2] : r0;
            Bh[ks2][3] = lhi ? ph[3] : r1;
          }
          {
            const unsigned t0 = lhi ? pl[0] : pl[2];
            const unsigned r0 = (unsigned)__shfl_xor((int)t0, 32);
            const unsigned t1 = lhi ? pl[1] : pl[3];
            const unsigned r1 = (unsigned)__shfl_xor((int)t1, 32);
            Bl[ks2][0] = lhi ? r0 : pl[0];
            Bl[ks2][1] = lhi ? r1 : pl[1];
            Bl[ks2][2] = lhi ? pl[2] : r0;
            Bl[ks2][3] = lhi ? pl[3] : r1;
          }
        }
      }
    }

    f32x16 d0, d1;
#pragma unroll
    for (int r = 0; r < 16; ++r) { d0[r] = 0.f; d1[r] = 0.f; }
    __builtin_amdgcn_s_setprio(1);
#pragma unroll
    for (int ks2 = 0; ks2 < 4; ++ks2) {
      U4B8 a0h, a0l, a1h, a1l, bh2, bl2;
      a0h.u = *(const uint4*)&FT[0][ks2][0][lane * 16];
      a0l.u = *(const uint4*)&FT[0][ks2][1][lane * 16];
      a1h.u = *(const uint4*)&FT[1][ks2][0][lane * 16];
      a1l.u = *(const uint4*)&FT[1][ks2][1][lane * 16];
      bh2.u = make_uint4(Bh[ks2][0], Bh[ks2][1], Bh[ks2][2], Bh[ks2][3]);
      bl2.u = make_uint4(Bl[ks2][0], Bl[ks2][1], Bl[ks2][2], Bl[ks2][3]);
      d0 = __builtin_amdgcn_mfma_f32_32x32x16_bf16(a0h.v, bh2.v, d0, 0, 0, 0);
      d1 = __builtin_amdgcn_mfma_f32_32x32x16_bf16(a1h.v, bh2.v, d1, 0, 0, 0);
      d0 = __builtin_amdgcn_mfma_f32_32x32x16_bf16(a0l.v, bh2.v, d0, 0, 0, 0);
      d1 = __builtin_amdgcn_mfma_f32_32x32x16_bf16(a1l.v, bh2.v, d1, 0, 0, 0);
      d0 = __builtin_amdgcn_mfma_f32_32x32x16_bf16(a0h.v, bl2.v, d0, 0, 0, 0);
      d1 = __builtin_amdgcn_mfma_f32_32x32x16_bf16(a1h.v, bl2.v, d1, 0, 0, 0);
    }
    __builtin_amdgcn_s_setprio(0);

    const float wt = Wm[sloc * 8 + (lrow & 7)];
    float oc[32], os[32];
#pragma unroll
    for (int r = 0; r < 32; ++r) {
      const float pr = (r < 16) ? d0[r] : d1[r - 16];
      float sv, cv;
      __sincosf(pr, &sv, &cv);
      oc[r] = wt * cv;
      os[r] = wt * sv;
    }
#pragma unroll
    for (int r = 0; r < 32; ++r) {
      oc[r] += __shfl_xor(oc[r], 1); os[r] += __shfl_xor(os[r], 1);
      oc[r] += __shfl_xor(oc[r], 2); os[r] += __shfl_xor(os[r], 2);
      oc[r] += __shfl_xor(oc[r], 4); os[r] += __shfl_xor(os[r], 4);
    }

    const int m = lrow & 7, srel = lrow >> 3;
#pragma unroll
    for (int rr2 = 0; rr2 < 4; ++rr2) {
      const int r = m * 4 + rr2;
      const int f = (r & 3) + 8 * ((r >> 2) & 3) + 4 * lhi + ((r >> 4) << 5);
      unsigned short hh, ll;
      bsplit(oc[r] * 0.125f, hh, ll);
      *(unsigned short*)(obh + srel * 256 + f * 2) = hh;
      *(unsigned short*)(obl + srel * 256 + f * 2) = ll;
      bsplit(os[r] * 0.125f, hh, ll);
      *(unsigned short*)(obh + srel * 256 + 128 + f * 2) = hh;
      *(unsigned short*)(obl + srel * 256 + 128 + f * 2) = ll;
    }
    const uint4 vh = *(const uint4*)(obh + lane * 16);
    const uint4 vl = *(const uint4*)(obl + lane * 16);
    const int srow = sblk + t * 4 + (lane >> 4);
    if (!qk) {
      const size_t off = ((size_t)bh * S_ + srow) * 256 + (lane & 15) * 16;
      *(uint4*)(oh + off) = vh;
      *(uint4*)(ol + off) = vl;
    } else {
      const int klr = srow & 31, ch = srow >> 5;
      const unsigned inner = (unsigned)(((klr << 8) + (lane & 15) * 16) ^ ((klr & 7) << 4));
      const size_t off = (size_t)bh * 262144 + (size_t)ch * 8192 + inner;
      *(uint4*)(oh + off) = vh;
      *(uint4*)(ol + off) = vl;
    }
  }
}

// ---------------------------------------------------------------------------
// V projection, MFMA (unchanged from R12).
// ---------------------------------------------------------------------------
__global__ __launch_bounds__(256) void k_proj_v(
    const float* __restrict__ atoms, const float* __restrict__ W,
    char* __restrict__ vthi, char* __restrict__ vtlo)
{
  const int sblk = blockIdx.x * 64;
  const int h = blockIdx.y, b = blockIdx.z;
  const int tid = threadIdx.x;
  const int w = tid >> 6, lane = tid & 63;
  const int lrow = lane & 31, lhi = lane >> 5;

  __shared__ __align__(16) float T[4][8 * 520];

  unsigned wAh[2][4][4], wAl[2][4][4];
#pragma unroll
  for (int wt = 0; wt < 2; ++wt)
#pragma unroll
    for (int ks = 0; ks < 4; ++ks) {
      const float* wp = W + h * 4096 + (wt * 32 + lrow) * 64 + ks * 16 + lhi * 8;
      float v[8];
      const float4 a = *(const float4*)wp;
      const float4 b2 = *(const float4*)(wp + 4);
      v[0] = a.x; v[1] = a.y; v[2] = a.z; v[3] = a.w;
      v[4] = b2.x; v[5] = b2.y; v[6] = b2.z; v[7] = b2.w;
      split8(v, wAh[wt][ks], wAl[wt][ks]);
    }

  const int bh = b * H_ + h;
  float* Tw = &T[w][0];

  for (int p = 0; p < 2; ++p) {
#pragma unroll
    for (int half8 = 0; half8 < 2; ++half8) {
      const int t = w * 4 + p * 2 + half8;
      const float* arow = atoms + ((size_t)(b * S_ + sblk) * 8 + t * 32 + lrow) * 64;
      unsigned aBh[4][4], aBl[4][4];
#pragma unroll
      for (int ks = 0; ks < 4; ++ks) {
        float v[8];
        const float4 a = *(const float4*)(arow + ks * 16 + lhi * 8);
        const float4 b2 = *(const float4*)(arow + ks * 16 + lhi * 8 + 4);
        v[0] = a.x; v[1] = a.y; v[2] = a.z; v[3] = a.w;
        v[4] = b2.x; v[5] = b2.y; v[6] = b2.z; v[7] = b2.w;
        split8(v, aBh[ks], aBl[ks]);
      }

      f32x16 y0, y1;
#pragma unroll
      for (int r = 0; r < 16; ++r) { y0[r] = 0.f; y1[r] = 0.f; }
      __builtin_amdgcn_s_setprio(1);
#pragma unroll
      for (int ks = 0; ks < 4; ++ks) {
        U4B8 a0h, a0l, a1h, a1l, bh2, bl2;
        a0h.u = make_uint4(wAh[0][ks][0], wAh[0][ks][1], wAh[0][ks][2], wAh[0][ks][3]);
        a0l.u = make_uint4(wAl[0][ks][0], wAl[0][ks][1], wAl[0][ks][2], wAl[0][ks][3]);
        a1h.u = make_uint4(wAh[1][ks][0], wAh[1][ks][1], wAh[1][ks][2], wAh[1][ks][3]);
        a1l.u = make_uint4(wAl[1][ks][0], wAl[1][ks][1], wAl[1][ks][2], wAl[1][ks][3]);
        bh2.u = make_uint4(aBh[ks][0], aBh[ks][1], aBh[ks][2], aBh[ks][3]);
        bl2.u = make_uint4(aBl[ks][0], aBl[ks][1], aBl[ks][2], aBl[ks][3]);
        y0 = __builtin_amdgcn_mfma_f32_32x32x16_bf16(a0h.v, bh2.v, y0, 0, 0, 0);
        y1 = __builtin_amdgcn_mfma_f32_32x32x16_bf16(a1h.v, bh2.v, y1, 0, 0, 0);
        y0 = __builtin_amdgcn_mfma_f32_32x32x16_bf16(a0l.v, bh2.v, y0, 0, 0, 0);
        y1 = __builtin_amdgcn_mfma_f32_32x32x16_bf16(a1l.v, bh2.v, y1, 0, 0, 0);
        y0 = __builtin_amdgcn_mfma_f32_32x32x16_bf16(a0h.v, bl2.v, y0, 0, 0, 0);
        y1 = __builtin_amdgcn_mfma_f32_32x32x16_bf16(a1h.v, bl2.v, y1, 0, 0, 0);
      }
      __builtin_amdgcn_s_setprio(0);

      const int s_in = half8 * 4 + (lrow >> 3);
      const int m = lrow & 7;
#pragma unroll
      for (int r = 0; r < 16; ++r) {
        const int dd = (r & 3) + 8 * (r >> 2) + 4 * lhi;
        Tw[s_in * 520 + m * 64 + dd] = y0[r];
        Tw[s_in * 520 + m * 64 + dd + 32] = y1[r];
      }
    }
    const int s0 = sblk + w * 16 + p * 8;
    const int ch = s0 >> 5, half = (s0 >> 4) & 1, part2 = (s0 >> 3) & 1;
    const size_t base = (size_t)bh * 1048576 + (size_t)ch * 32768 + half * 16384;
#pragma unroll
    for (int j = 0; j < 8; ++j) {
      const int c = j * 64 + lane;
      float v[8];
#pragma unroll
      for (int s = 0; s < 8; ++s) v[s] = Tw[s * 520 + c];
      unsigned hw[4], lw[4];
      split8(v, hw, lw);
      const unsigned inner = (unsigned)(c * 32 + part2 * 16);
      *(uint4*)(vthi + base + inner) = make_uint4(hw[0], hw[1], hw[2], hw[3]);
      *(uint4*)(vtlo + base + inner) = make_uint4(lw[0], lw[1], lw[2], lw[3]);
    }
  }
}

// ---------------------------------------------------------------------------
// MFMA flash attention, bounded-score softmax (P = exp(s) direct), P-pipeline.
// 512 blocks x 256 threads: block = (bh, 32 q rows). Producer wave pw=qb&3
// computes P(ch+1) while all 4 waves PV(ch) from P[ch&1]. K DMA depth 2.
// ---------------------------------------------------------------------------
__global__ __launch_bounds__(256, 2) void k_flash(
    const unsigned short* __restrict__ qrh, const unsigned short* __restrict__ qrl,
    const char* __restrict__ krh, const char* __restrict__ krl,
    const char* __restrict__ vthi, const char* __restrict__ vtlo,
    float* __restrict__ ao)
{
  __shared__ __align__(16) char Ksm[32768];
  __shared__ __align__(16) char PAsm[2][4096];
  __shared__ float Slinv[32];

  char* Khi0 = Ksm;
  char* Klo0 = Ksm + 8192;
  char* Khi1 = Ksm + 16384;
  char* Klo1 = Ksm + 24576;

  const int tid = threadIdx.x;
  const int w = tid >> 6, lane = tid & 63;
  const int lrow = lane & 31, lhi = lane >> 5;

  const int phys = blockIdx.x;
  const int x = phys & 7, j = phys >> 3;          // x = XCD
  const int bh = (x << 1) | (j >> 5);             // 2 bh per XCD
  const int qb = j & 31;
  const int b = bh >> 3, h = bh & 7;
  const int qbase = qb * 32;
  const int pw = qb & 3;                          // staggered producer wave
  const bool prod = (w == pw);

  // Q fragments: producer only
  uint4 qfh[8], qfl[8];
  if (prod) {
    const size_t rowb = ((size_t)bh * S_ + qbase + lrow) * 128;
#pragma unroll
    for (int fs = 0; fs < 8; ++fs) {
      const size_t e = rowb + fs * 16 + lhi * 8;
      qfh[fs] = *(const uint4*)(qrh + e);
      qfl[fs] = *(const uint4*)(qrl + e);
    }
  }

  const char* vh_c = vthi + (size_t)bh * 1048576;
  const char* vl_c = vtlo + (size_t)bh * 1048576;
  const char* kh_c = krh + (size_t)bh * 262144;
  const char* kl_c = krl + (size_t)bh * 262144;

  auto issue_k = [&](int ch) {                    // dst buf = ch&1
    char* dh = (ch & 1) ? Khi1 : Khi0;
    char* dl = (ch & 1) ? Klo1 : Klo0;
    const size_t g = (size_t)ch * 8192;
#pragma unroll
    for (int i = 0; i < 2; ++i) {
      __builtin_amdgcn_global_load_lds(kh_c + g + i * 4096 + tid * 16, dh + i * 4096 + (w << 10), 16, 0, 0);
      __builtin_amdgcn_global_load_lds(kl_c + g + i * 4096 + tid * 16, dl + i * 4096 + (w << 10), 16, 0, 0);
    }
  };

  const unsigned vbase = (unsigned)((w * 128 + lrow) * 32 + lhi * 16);
  uint4 vAh[4], vAl[4], vBh[4], vBl[4];
  auto load_vA = [&](int ch) {
    const size_t g = (size_t)ch * 32768 + vbase;
#pragma unroll
    for (int cf = 0; cf < 4; ++cf) {
      vAh[cf] = *(const uint4*)(vh_c + g + cf * 1024);
      vAl[cf] = *(const uint4*)(vl_c + g + cf * 1024);
    }
  };
  auto load_vB = [&](int ch) {
    const size_t g = (size_t)ch * 32768 + 16384 + vbase;
#pragma unroll
    for (int cf = 0; cf < 4; ++cf) {
      vBh[cf] = *(const uint4*)(vh_c + g + cf * 1024);
      vBl[cf] = *(const uint4*)(vl_c + g + cf * 1024);
    }
  };

  f32x16 acc[4];
#pragma unroll
  for (int i = 0; i < 4; ++i)
#pragma unroll
    for (int r = 0; r < 16; ++r) acc[i][r] = 0.f;
  float l_run = 0.f;

  // Producer: scores(chp) from K buf chp&1; P = exp(s); publish to PAsm[chp&1].
  auto produce = [&](int chp) {
    const char* kh = (chp & 1) ? Khi1 : Khi0;
    const char* kl = (chp & 1) ? Klo1 : Klo0;
    f32x16 s0, s1;
#pragma unroll
    for (int r = 0; r < 16; ++r) { s0[r] = 0.f; s1[r] = 0.f; }
    __builtin_amdgcn_s_setprio(1);
#pragma unroll
    for (int fs = 0; fs < 8; ++fs) {
      const unsigned kaddr = (unsigned)((lrow * 256 + fs * 32 + lhi * 16) ^ ((lrow & 7) << 4));
      U4B8 khf, klf, qh, ql;
      khf.u = *(const uint4*)(kh + kaddr);
      klf.u = *(const uint4*)(kl + kaddr);
      qh.u = qfh[fs]; ql.u = qfl[fs];
      if (fs & 1) {
        s1 = __builtin_amdgcn_mfma_f32_32x32x16_bf16(khf.v, qh.v, s1, 0, 0, 0);
        s1 = __builtin_amdgcn_mfma_f32_32x32x16_bf16(klf.v, qh.v, s1, 0, 0, 0);
        s1 = __builtin_amdgcn_mfma_f32_32x32x16_bf16(khf.v, ql.v, s1, 0, 0, 0);
      } else {
        s0 = __builtin_amdgcn_mfma_f32_32x32x16_bf16(khf.v, qh.v, s0, 0, 0, 0);
        s0 = __builtin_amdgcn_mfma_f32_32x32x16_bf16(klf.v, qh.v, s0, 0, 0, 0);
        s0 = __builtin_amdgcn_mfma_f32_32x32x16_bf16(khf.v, ql.v, s0, 0, 0, 0);
      }
    }
    __builtin_amdgcn_s_setprio(0);
    // Bounded scores: |s| <= 1 -> P = exp(s) directly (no max subtraction).
    float p[16];
#pragma unroll
    for (int r = 0; r < 16; ++r) p[r] = __expf(s0[r] + s1[r]);
    float rs = 0.f;
#pragma unroll
    for (int r = 0; r < 16; ++r) rs += p[r];
    rs += __shfl_xor(rs, 32);
    l_run += rs;

    unsigned wh[8], wl[8];
#pragma unroll
    for (int i = 0; i < 8; ++i) {
      const float a = p[2 * i], c2 = p[2 * i + 1];
      const unsigned hword = cvt_pk_bf16(a, c2);
      const float ra = a - __uint_as_float(hword << 16);
      const float rc = c2 - __uint_as_float(hword & 0xffff0000u);
      wh[i] = hword;
      wl[i] = cvt_pk_bf16(ra, rc);
    }
    auto mix = [&](unsigned &lo_w, unsigned &hi_w) {
      const unsigned t = lhi ? lo_w : hi_w;
      const unsigned r = (unsigned)__shfl_xor((int)t, 32);
      lo_w = lhi ? r : lo_w;
      hi_w = lhi ? hi_w : r;
    };
    mix(wh[0], wh[2]); mix(wh[1], wh[3]); mix(wh[4], wh[6]); mix(wh[5], wh[7]);
    mix(wl[0], wl[2]); mix(wl[1], wl[3]); mix(wl[4], wl[6]); mix(wl[5], wl[7]);

    char* pb = &PAsm[chp & 1][0];
    *(uint4*)(pb + 0 * 1024 + lane * 16) = make_uint4(wh[0], wh[1], wh[2], wh[3]);
    *(uint4*)(pb + 1 * 1024 + lane * 16) = make_uint4(wh[4], wh[5], wh[6], wh[7]);
    *(uint4*)(pb + 2 * 1024 + lane * 16) = make_uint4(wl[0], wl[1], wl[2], wl[3]);
    *(uint4*)(pb + 3 * 1024 + lane * 16) = make_uint4(wl[4], wl[5], wl[6], wl[7]);
  };

  // ---- prologue ----
  issue_k(0);                        // 4 loads, buf0 (oldest)
  issue_k(1);                        // 4 loads, buf1
  load_vA(0);                        // 8
  load_vB(0);                        // 8
  asm volatile("s_waitcnt vmcnt(16)" ::: "memory");   // K(0) landed
  SBAR(); MEMFENCE();
  if (prod) produce(0);
  asm volatile("s_waitcnt lgkmcnt(0)" ::: "memory");
  SCHED0(); SBAR(); MEMFENCE();      // P(0) visible; K(1) still in flight

  // K(1) must land before produce(1) at ch=0: drain it (only vA/vB newer).
  asm volatile("s_waitcnt vmcnt(16)" ::: "memory");

  for (int ch = 0; ch < 32; ++ch) {
    if (ch < 30) { SCHED0(); issue_k(ch + 2); SCHED0(); }

    if (prod && ch < 31) produce(ch + 1);

    // ---- all waves: PV(ch) from PAsm[ch&1] ----
    U4B8 pah0, pah1, pal0, pal1;
    {
      const char* pb = &PAsm[ch & 1][0];
      pah0.u = *(const uint4*)(pb + 0 * 1024 + lane * 16);
      pah1.u = *(const uint4*)(pb + 1 * 1024 + lane * 16);
      pal0.u = *(const uint4*)(pb + 2 * 1024 + lane * 16);
      pal1.u = *(const uint4*)(pb + 3 * 1024 + lane * 16);
    }

    __builtin_amdgcn_s_setprio(1);
#pragma unroll
    for (int cf = 0; cf < 4; ++cf) {
      U4B8 vh, vl2;
      vh.u = vAh[cf]; vl2.u = vAl[cf];
      acc[cf] = __builtin_amdgcn_mfma_f32_32x32x16_bf16(pah0.v, vh.v,  acc[cf], 0, 0, 0);
      acc[cf] = __builtin_amdgcn_mfma_f32_32x32x16_bf16(pal0.v, vh.v,  acc[cf], 0, 0, 0);
      acc[cf] = __builtin_amdgcn_mfma_f32_32x32x16_bf16(pah0.v, vl2.v, acc[cf], 0, 0, 0);
    }
    __builtin_amdgcn_s_setprio(0);
    if (ch < 31) load_vA(ch + 1);

    __builtin_amdgcn_s_setprio(1);
#pragma unroll
    for (int cf = 0; cf < 4; ++cf) {
      U4B8 vh, vl2;
      vh.u = vBh[cf]; vl2.u = vBl[cf];
      acc[cf] = __builtin_amdgcn_mfma_f32_32x32x16_bf16(pah1.v, vh.v,  acc[cf], 0, 0, 0);
      acc[cf] = __builtin_amdgcn_mfma_f32_32x32x16_bf16(pal1.v, vh.v,  acc[cf], 0, 0, 0);
      acc[cf] = __builtin_amdgcn_mfma_f32_32x32x16_bf16(pah1.v, vl2.v, acc[cf], 0, 0, 0);
    }
    __builtin_amdgcn_s_setprio(0);

    if (ch < 31) {
      load_vB(ch + 1);
      // Drain K(ch+2) (oldest 4 of the 20 outstanding) is NOT needed yet;
      // but K(ch+1) (needed by produce(ch+2) next chunk) was issued last
      // chunk and is drained by vmcnt(16): newest 16 = vA8+vB8.
      SCHED0();
      asm volatile("s_waitcnt vmcnt(16)" ::: "memory");
      asm volatile("s_waitcnt lgkmcnt(0)" ::: "memory");   // P(ch+1) writes
      SBAR(); MEMFENCE();
    }
  }

  // ---- epilogue ----
  if (prod && lane < 32) Slinv[lrow] = 1.0f / l_run;
  asm volatile("s_waitcnt lgkmcnt(0)" ::: "memory");
  SBAR(); MEMFENCE();
  float lr[16];
#pragma unroll
  for (int r = 0; r < 16; ++r)
    lr[r] = Slinv[(r & 3) + 8 * (r >> 2) + 4 * lhi];
#pragma unroll
  for (int cf = 0; cf < 4; ++cf) {
    const int c = w * 128 + cf * 32 + lrow;
    const int m = c >> 6, dd = c & 63;
#pragma unroll
    for (int r = 0; r < 16; ++r) {
      const int qr = (r & 3) + 8 * (r >> 2) + 4 * lhi;
      const int srow = qbase + qr;
      const size_t off = (((size_t)(b * S_ + srow)) * 8 + m) * 512 + h * 64 + dd;
      ao[off] = acc[cf][r] * lr[r];
    }
  }
}

// ---------------------------------------------------------------------------
// k_out MFMA (unchanged from R10).
// ---------------------------------------------------------------------------
__global__ __launch_bounds__(256) void k_out(
    const float* __restrict__ ao, const float* __restrict__ Wo,
    const float* __restrict__ Ww, const float* __restrict__ qlw,
    float* __restrict__ out)
{
  const int tid = threadIdx.x;
  const int w = tid >> 6, lane = tid & 63;
  const int lrow = lane & 31, lhi = lane >> 5;
  const int Rblk = blockIdx.x * 128;

  __shared__ __align__(16) char WoF[4][2][2][1024];
  __shared__ __align__(16) float Os[128 * 68];

  f32x16 acc[2];
#pragma unroll
  for (int i = 0; i < 2; ++i)
#pragma unroll
    for (int r = 0; r < 16; ++r) acc[i][r] = 0.f;

  const float* brow = ao + (size_t)(Rblk + w * 32 + lrow) * 512;

  for (int chunk = 0; chunk < 8; ++chunk) {
    __syncthreads();
#pragma unroll
    for (int dt = 0; dt < 2; ++dt) {
      const float* wp = Wo + (size_t)(dt * 32 + lrow) * 512 + (chunk * 4 + w) * 16 + lhi * 8;
      float v[8];
      const float4 a = *(const float4*)wp;
      const float4 b2 = *(const float4*)(wp + 4);
      v[0] = a.x; v[1] = a.y; v[2] = a.z; v[3] = a.w;
      v[4] = b2.x; v[5] = b2.y; v[6] = b2.z; v[7] = b2.w;
      unsigned hw[4], lw2[4];
      split8(v, hw, lw2);
      *(uint4*)&WoF[w][dt][0][lane * 16] = make_uint4(hw[0], hw[1], hw[2], hw[3]);
      *(uint4*)&WoF[w][dt][1][lane * 16] = make_uint4(lw2[0], lw2[1], lw2[2], lw2[3]);
    }
    __syncthreads();

#pragma unroll
    for (int kl = 0; kl < 4; ++kl) {
      float v[8];
      const float4 a = *(const float4*)(brow + (chunk * 4 + kl) * 16 + lhi * 8);
      const float4 b2 = *(const float4*)(brow + (chunk * 4 + kl) * 16 + lhi * 8 + 4);
      v[0] = a.x; v[1] = a.y; v[2] = a.z; v[3] = a.w;
      v[4] = b2.x; v[5] = b2.y; v[6] = b2.z; v[7] = b2.w;
      unsigned bhw[4], blw[4];
      split8(v, bhw, blw);
      U4B8 bh2, bl2;
      bh2.u = make_uint4(bhw[0], bhw[1], bhw[2], bhw[3]);
      bl2.u = make_uint4(blw[0], blw[1], blw[2], blw[3]);
      __builtin_amdgcn_s_setprio(1);
#pragma unroll
      for (int dt = 0; dt < 2; ++dt) {
        U4B8 ah, al;
        ah.u = *(const uint4*)&WoF[kl][dt][0][lane * 16];
        al.u = *(const uint4*)&WoF[kl][dt][1][lane * 16];
        acc[dt] = __builtin_amdgcn_mfma_f32_32x32x16_bf16(ah.v, bh2.v, acc[dt], 0, 0, 0);
        acc[dt] = __builtin_amdgcn_mfma_f32_32x32x16_bf16(al.v, bh2.v, acc[dt], 0, 0, 0);
        acc[dt] = __builtin_amdgcn_mfma_f32_32x32x16_bf16(ah.v, bl2.v, acc[dt], 0, 0, 0);
      }
      __builtin_amdgcn_s_setprio(0);
    }
  }

  __syncthreads();
#pragma unroll
  for (int dt = 0; dt < 2; ++dt)
#pragma unroll
    for (int r = 0; r < 16; ++r) {
      const int d = dt * 32 + (r & 3) + 8 * (r >> 2) + 4 * lhi;
      Os[(w * 32 + lrow) * 68 + d] = acc[dt][r];
    }
  __syncthreads();

#pragma unroll
  for (int jj = 0; jj < 8; ++jj) {
    const int i = tid + 256 * jj;
    const int r = i >> 4, c4 = (i & 15) * 4;
    const float4 v = *(const float4*)&Os[r * 68 + c4];
    *(float4*)&out[(size_t)(Rblk + r) * 64 + c4] = v;
  }

#pragma unroll
  for (int gi = 0; gi < 4; ++gi) {
    const int g = w * 4 + gi;
    float mean = 0.f;
#pragma unroll
    for (int m = 0; m < 8; ++m) mean += Os[(g * 8 + m) * 68 + lane];
    mean *= 0.125f;
    float dsel = 0.f;
#pragma unroll
    for (int mw = 0; mw < 8; ++mw) {
      float part = mean * Ww[mw * 64 + lane];
      part += __shfl_xor(part, 1);
      part += __shfl_xor(part, 2);
      part += __shfl_xor(part, 4);
      part += __shfl_xor(part, 8);
      part += __shfl_xor(part, 16);
      part += __shfl_xor(part, 32);
      if (lane == mw) dsel = part;
    }
    if (lane < 8) {
      const int idx = Rblk + g * 8 + lane;
      out[1048576 + idx] = qlw[idx] + dsel;
    }
  }
}

// ---------------------------------------------------------------------------
extern "C" void kernel_launch(void* const* d_in, const int* in_sizes, int n_in,
                              void* d_out, int out_size, void* d_ws, size_t ws_size,
                              hipStream_t stream)
{
  const float* q_atoms = (const float*)d_in[0];
  const float* q_logw  = (const float*)d_in[1];
  const float* k_atoms = (const float*)d_in[2];
  const float* k_logw  = (const float*)d_in[3];
  const float* v_atoms = (const float*)d_in[4];
  const float* cosT  = (const float*)d_in[6];
  const float* sinT  = (const float*)d_in[7];
  const float* Wq    = (const float*)d_in[8];
  const float* Wk    = (const float*)d_in[9];
  const float* Wv    = (const float*)d_in[10];
  const float* Wo    = (const float*)d_in[11];
  const float* Ww    = (const float*)d_in[12];
  const float* logbw = (const float*)d_in[13];
  const float* rffb  = (const float*)d_in[14];
  float* out = (float*)d_out;

  char* wsb = (char*)d_ws;
  char* qrh = wsb;
  char* qrl = wsb + (4u << 20);
  char* krh = wsb + (8u << 20);
  char* krl = wsb + (12u << 20);
  char* vthi = wsb + (16u << 20);
  char* vtlo = wsb + (32u << 20);
  float* ao = (float*)(wsb + (48u << 20));

  const dim3 blk(256);
  k_proj_rff<<<dim3(16, 8, 4), blk, 0, stream>>>(q_atoms, q_logw, k_atoms, k_logw,
                                                 Wq, Wk, rffb, logbw, cosT, sinT,
                                                 qrh, qrl, krh, krl);
  k_proj_v  <<<dim3(16, 8, 2), blk, 0, stream>>>(v_atoms, Wv, vthi, vtlo);
  k_flash   <<<dim3(512), blk, 0, stream>>>((const unsigned short*)qrh, (const unsigned short*)qrl,
                                            krh, krl, vthi, vtlo, ao);
  k_out     <<<dim3(128), blk, 0, stream>>>(ao, Wo, Ww, q_logw, out);
}

// Round 14
// 149.401 us; speedup vs baseline: 5.4860x; 1.1648x over previous
//
#include <hip/hip_runtime.h>
#include <math.h>

// KME attention. B=2 S=1024 M=8 D=64 H=8 NF=64
// Round 14 (on R13): error-budgeted term drops in k_flash:
//  - scores: drop kh*q_lo term (err ~1e-4) -> no qrl loads, 16 MFMA/chunk
//  - PV: drop pah*v_lo term + entire vtlo plane (err ~1e-4..3e-4):
//    V L2 bytes halved, PV 16 MFMA/wave/chunk
//  - producer-wave stagger fixed for co-resident blocks (phys bit mix)
//  - k_proj_v writes only vthi.
//
// ws layout (bytes), 80 MiB total:
//   qrh  @ 0MB   4MB  ushort [bh][s][128]          (natural)
//   qrl  @ 4MB   4MB  (written by proj_rff, unused by k_flash now)
//   krh  @ 8MB   4MB  swizzled-chunk layout [bh][ch=32][8192B]
//   krl  @12MB   4MB
//   vthi @16MB  16MB  [bh][ch=32][half=2][c=512][32B], inner=c*32+part2*16
//   vtlo @32MB  16MB  (unused now)
//   ao   @48MB  32MB  f32 [b][s][m][512]

#define B_ 2
#define S_ 1024
#define H_ 8

typedef __attribute__((ext_vector_type(8))) short short8;
typedef __attribute__((ext_vector_type(16))) float f32x16;
union U4B8 { uint4 u; short8 v; };

#define SBAR() __builtin_amdgcn_s_barrier()
#define SCHED0() __builtin_amdgcn_sched_barrier(0)
#define MEMFENCE() asm volatile("" ::: "memory")

__device__ inline unsigned cvt_pk_bf16(float a, float b) {
  unsigned r;
  asm("v_cvt_pk_bf16_f32 %0, %1, %2" : "=v"(r) : "v"(a), "v"(b));
  return r;
}
__device__ inline void bsplit(float v, unsigned short &h, unsigned short &l) {
  unsigned hw = cvt_pk_bf16(v, 0.f);
  float hf = __uint_as_float(hw << 16);
  unsigned lw = cvt_pk_bf16(v - hf, 0.f);
  h = (unsigned short)hw; l = (unsigned short)lw;
}
__device__ inline void split8(const float* v, unsigned* hw, unsigned* lw) {
#pragma unroll
  for (int p = 0; p < 4; ++p) {
    const float a = v[2 * p], b = v[2 * p + 1];
    const unsigned h = cvt_pk_bf16(a, b);
    const float ra = a - __uint_as_float(h << 16);
    const float rb = b - __uint_as_float(h & 0xffff0000u);
    hw[p] = h;
    lw[p] = cvt_pk_bf16(ra, rb);
  }
}

// ---------------------------------------------------------------------------
// MFMA projection + RoPE + RFF encode (unchanged from R8).
// ---------------------------------------------------------------------------
__global__ __launch_bounds__(256, 2) void k_proj_rff(
    const float* __restrict__ q_atoms, const float* __restrict__ q_logw,
    const float* __restrict__ k_atoms, const float* __restrict__ k_logw,
    const float* __restrict__ Wq, const float* __restrict__ Wk,
    const float* __restrict__ freqb, const float* __restrict__ logbw,
    const float* __restrict__ cosT, const float* __restrict__ sinT,
    char* __restrict__ qoh, char* __restrict__ qol,
    char* __restrict__ koh, char* __restrict__ kol)
{
  const int sblk = blockIdx.x * 64;
  const int h = blockIdx.y, z = blockIdx.z;
  const int qk = z >> 1, b = z & 1;
  const float* atoms = qk ? k_atoms : q_atoms;
  const float* logw  = qk ? k_logw : q_logw;
  const float* W     = qk ? Wk : Wq;
  char* oh = qk ? koh : qoh;
  char* ol = qk ? kol : qol;

  const int tid = threadIdx.x;
  const int w = tid >> 6, lane = tid & 63;
  const int lrow = lane & 31, lhi = lane >> 5;

  __shared__ float Cs[64 * 65];
  __shared__ float Sn[64 * 65];
  __shared__ float Wm[64 * 8];
  __shared__ __align__(16) char FT[2][4][2][1024];
  __shared__ __align__(16) char Ob[4][2][1024];

  for (int i = tid; i < 4096; i += 256) {
    const int sl = i >> 6, d = i & 63;
    Cs[sl * 65 + d] = cosT[(sblk + sl) * 64 + d];
    Sn[sl * 65 + d] = sinT[(sblk + sl) * 64 + d];
  }
  if (tid < 64) {
    const float* lw = logw + (size_t)(b * S_ + sblk + tid) * 8;
    float mx = lw[0];
    for (int m = 1; m < 8; ++m) mx = fmaxf(mx, lw[m]);
    float e[8], sum = 0.f;
    for (int m = 0; m < 8; ++m) { e[m] = __expf(lw[m] - mx); sum += e[m]; }
    const float inv = 1.0f / sum;
    for (int m = 0; m < 8; ++m) Wm[tid * 8 + m] = e[m] * inv;
  }
  const float fscale = __expf(-logbw[h]);
  {
    const int ftw = w & 1;
#pragma unroll
    for (int kk = 0; kk < 2; ++kk) {
      const int ks2 = (w >> 1) + kk * 2;
      float v[8];
#pragma unroll
      for (int j = 0; j < 8; ++j)
        v[j] = freqb[h * 4096 + (ks2 * 16 + lhi * 8 + j) * 64 + ftw * 32 + lrow] * fscale;
      unsigned hw[4], lw2[4];
      split8(v, hw, lw2);
      *(uint4*)&FT[ftw][ks2][0][lane * 16] = make_uint4(hw[0], hw[1], hw[2], hw[3]);
      *(uint4*)&FT[ftw][ks2][1][lane * 16] = make_uint4(lw2[0], lw2[1], lw2[2], lw2[3]);
    }
  }
  unsigned wAh[2][4][4], wAl[2][4][4];
#pragma unroll
  for (int wt = 0; wt < 2; ++wt)
#pragma unroll
    for (int ks = 0; ks < 4; ++ks) {
      const float* wp = W + h * 4096 + (wt * 32 + lrow) * 64 + ks * 16 + lhi * 8;
      float v[8];
      const float4 a = *(const float4*)wp;
      const float4 b2 = *(const float4*)(wp + 4);
      v[0] = a.x; v[1] = a.y; v[2] = a.z; v[3] = a.w;
      v[4] = b2.x; v[5] = b2.y; v[6] = b2.z; v[7] = b2.w;
      split8(v, wAh[wt][ks], wAl[wt][ks]);
    }
  __syncthreads();

  const int bh = b * H_ + h;
  char* obh = &Ob[w][0][0];
  char* obl = &Ob[w][1][0];

  for (int it = 0; it < 4; ++it) {
    const int t = w * 4 + it;
    const float* arow = atoms + ((size_t)(b * S_ + sblk) * 8 + t * 32 + lrow) * 64;
    unsigned aBh[4][4], aBl[4][4];
#pragma unroll
    for (int ks = 0; ks < 4; ++ks) {
      float v[8];
      const float4 a = *(const float4*)(arow + ks * 16 + lhi * 8);
      const float4 b2 = *(const float4*)(arow + ks * 16 + lhi * 8 + 4);
      v[0] = a.x; v[1] = a.y; v[2] = a.z; v[3] = a.w;
      v[4] = b2.x; v[5] = b2.y; v[6] = b2.z; v[7] = b2.w;
      split8(v, aBh[ks], aBl[ks]);
    }

    f32x16 y0, y1;
#pragma unroll
    for (int r = 0; r < 16; ++r) { y0[r] = 0.f; y1[r] = 0.f; }
    __builtin_amdgcn_s_setprio(1);
#pragma unroll
    for (int ks = 0; ks < 4; ++ks) {
      U4B8 a0h, a0l, a1h, a1l, bh2, bl2;
      a0h.u = make_uint4(wAh[0][ks][0], wAh[0][ks][1], wAh[0][ks][2], wAh[0][ks][3]);
      a0l.u = make_uint4(wAl[0][ks][0], wAl[0][ks][1], wAl[0][ks][2], wAl[0][ks][3]);
      a1h.u = make_uint4(wAh[1][ks][0], wAh[1][ks][1], wAh[1][ks][2], wAh[1][ks][3]);
      a1l.u = make_uint4(wAl[1][ks][0], wAl[1][ks][1], wAl[1][ks][2], wAl[1][ks][3]);
      bh2.u = make_uint4(aBh[ks][0], aBh[ks][1], aBh[ks][2], aBh[ks][3]);
      bl2.u = make_uint4(aBl[ks][0], aBl[ks][1], aBl[ks][2], aBl[ks][3]);
      y0 = __builtin_amdgcn_mfma_f32_32x32x16_bf16(a0h.v, bh2.v, y0, 0, 0, 0);
      y1 = __builtin_amdgcn_mfma_f32_32x32x16_bf16(a1h.v, bh2.v, y1, 0, 0, 0);
      y0 = __builtin_amdgcn_mfma_f32_32x32x16_bf16(a0l.v, bh2.v, y0, 0, 0, 0);
      y1 = __builtin_amdgcn_mfma_f32_32x32x16_bf16(a1l.v, bh2.v, y1, 0, 0, 0);
      y0 = __builtin_amdgcn_mfma_f32_32x32x16_bf16(a0h.v, bl2.v, y0, 0, 0, 0);
      y1 = __builtin_amdgcn_mfma_f32_32x32x16_bf16(a1h.v, bl2.v, y1, 0, 0, 0);
    }
    __builtin_amdgcn_s_setprio(0);

    const int sloc = t * 4 + (lrow >> 3);
    const int sld = sloc * 65;
    float yr0[16], yr1[16];
#pragma unroll
    for (int r = 0; r < 16; ++r) {
      const int dd = (r & 3) + 8 * (r >> 2) + 4 * lhi;
      const float c0 = Cs[sld + dd],      s0v = Sn[sld + dd];
      const float c1 = Cs[sld + dd + 32], s1v = Sn[sld + dd + 32];
      yr0[r] = y0[r] * c0 - y1[r] * s0v;
      yr1[r] = y1[r] * c1 + y0[r] * s1v;
    }

    unsigned Bh[4][4], Bl[4][4];
    {
      const float* src[2] = { yr0, yr1 };
#pragma unroll
      for (int st = 0; st < 2; ++st) {
#pragma unroll
        for (int half = 0; half < 2; ++half) {
          const int ks2 = st * 2 + half;
          const float* q = src[st] + half * 8;
          unsigned ph[4], pl[4];
          split8(q, ph, pl);
          {
            const unsigned t0 = lhi ? ph[0] : ph[2];
            const unsigned r0 = (unsigned)__shfl_xor((int)t0, 32);
            const unsigned t1 = lhi ? ph[1] : ph[3];
            const unsigned r1 = (unsigned)__shfl_xor((int)t1, 32);
            Bh[ks2][0] = lhi ? r0 : ph[0];
            Bh[ks2][1] = lhi ? r1 : ph[1];
            Bh[ks2][2] = lhi ? ph[2] : r0;
            Bh[ks2][3] = lhi ? ph[3] : r1;
          }
          {
            const unsigned t0 = lhi ? pl[0] : pl[2];
            const unsigned r0 = (unsigned)__shfl_xor((int)t0, 32);
            const unsigned t1 = lhi ? pl[1] : pl[3];
            const unsigned r1 = (unsigned)__shfl_xor((int)t1, 32);
            Bl[ks2][0] = lhi ? r0 : pl[0];
            Bl[ks2][1] = lhi ? r1 : pl[1];
            Bl[ks2][2] = lhi ? pl[2] : r0;
            Bl[ks2][3] = lhi ? pl[3] : r1;
          }
        }
      }
    }

    f32x16 d0, d1;
#pragma unroll
    for (int r = 0; r < 16; ++r) { d0[r] = 0.f; d1[r] = 0.f; }
    __builtin_amdgcn_s_setprio(1);
#pragma unroll
    for (int ks2 = 0; ks2 < 4; ++ks2) {
      U4B8 a0h, a0l, a1h, a1l, bh2, bl2;
      a0h.u = *(const uint4*)&FT[0][ks2][0][lane * 16];
      a0l.u = *(const uint4*)&FT[0][ks2][1][lane * 16];
      a1h.u = *(const uint4*)&FT[1][ks2][0][lane * 16];
      a1l.u = *(const uint4*)&FT[1][ks2][1][lane * 16];
      bh2.u = make_uint4(Bh[ks2][0], Bh[ks2][1], Bh[ks2][2], Bh[ks2][3]);
      bl2.u = make_uint4(Bl[ks2][0], Bl[ks2][1], Bl[ks2][2], Bl[ks2][3]);
      d0 = __builtin_amdgcn_mfma_f32_32x32x16_bf16(a0h.v, bh2.v, d0, 0, 0, 0);
      d1 = __builtin_amdgcn_mfma_f32_32x32x16_bf16(a1h.v, bh2.v, d1, 0, 0, 0);
      d0 = __builtin_amdgcn_mfma_f32_32x32x16_bf16(a0l.v, bh2.v, d0, 0, 0, 0);
      d1 = __builtin_amdgcn_mfma_f32_32x32x16_bf16(a1l.v, bh2.v, d1, 0, 0, 0);
      d0 = __builtin_amdgcn_mfma_f32_32x32x16_bf16(a0h.v, bl2.v, d0, 0, 0, 0);
      d1 = __builtin_amdgcn_mfma_f32_32x32x16_bf16(a1h.v, bl2.v, d1, 0, 0, 0);
    }
    __builtin_amdgcn_s_setprio(0);

    const float wt = Wm[sloc * 8 + (lrow & 7)];
    float oc[32], os[32];
#pragma unroll
    for (int r = 0; r < 32; ++r) {
      const float pr = (r < 16) ? d0[r] : d1[r - 16];
      float sv, cv;
      __sincosf(pr, &sv, &cv);
      oc[r] = wt * cv;
      os[r] = wt * sv;
    }
#pragma unroll
    for (int r = 0; r < 32; ++r) {
      oc[r] += __shfl_xor(oc[r], 1); os[r] += __shfl_xor(os[r], 1);
      oc[r] += __shfl_xor(oc[r], 2); os[r] += __shfl_xor(os[r], 2);
      oc[r] += __shfl_xor(oc[r], 4); os[r] += __shfl_xor(os[r], 4);
    }

    const int m = lrow & 7, srel = lrow >> 3;
#pragma unroll
    for (int rr2 = 0; rr2 < 4; ++rr2) {
      const int r = m * 4 + rr2;
      const int f = (r & 3) + 8 * ((r >> 2) & 3) + 4 * lhi + ((r >> 4) << 5);
      unsigned short hh, ll;
      bsplit(oc[r] * 0.125f, hh, ll);
      *(unsigned short*)(obh + srel * 256 + f * 2) = hh;
      *(unsigned short*)(obl + srel * 256 + f * 2) = ll;
      bsplit(os[r] * 0.125f, hh, ll);
      *(unsigned short*)(obh + srel * 256 + 128 + f * 2) = hh;
      *(unsigned short*)(obl + srel * 256 + 128 + f * 2) = ll;
    }
    const uint4 vh = *(const uint4*)(obh + lane * 16);
    const uint4 vl = *(const uint4*)(obl + lane * 16);
    const int srow = sblk + t * 4 + (lane >> 4);
    if (!qk) {
      const size_t off = ((size_t)bh * S_ + srow) * 256 + (lane & 15) * 16;
      *(uint4*)(oh + off) = vh;
      *(uint4*)(ol + off) = vl;
    } else {
      const int klr = srow & 31, ch = srow >> 5;
      const unsigned inner = (unsigned)(((klr << 8) + (lane & 15) * 16) ^ ((klr & 7) << 4));
      const size_t off = (size_t)bh * 262144 + (size_t)ch * 8192 + inner;
      *(uint4*)(oh + off) = vh;
      *(uint4*)(ol + off) = vl;
    }
  }
}

// ---------------------------------------------------------------------------
// V projection, MFMA; writes ONLY the hi plane now.
// ---------------------------------------------------------------------------
__global__ __launch_bounds__(256) void k_proj_v(
    const float* __restrict__ atoms, const float* __restrict__ W,
    char* __restrict__ vthi)
{
  const int sblk = blockIdx.x * 64;
  const int h = blockIdx.y, b = blockIdx.z;
  const int tid = threadIdx.x;
  const int w = tid >> 6, lane = tid & 63;
  const int lrow = lane & 31, lhi = lane >> 5;

  __shared__ __align__(16) float T[4][8 * 520];

  unsigned wAh[2][4][4], wAl[2][4][4];
#pragma unroll
  for (int wt = 0; wt < 2; ++wt)
#pragma unroll
    for (int ks = 0; ks < 4; ++ks) {
      const float* wp = W + h * 4096 + (wt * 32 + lrow) * 64 + ks * 16 + lhi * 8;
      float v[8];
      const float4 a = *(const float4*)wp;
      const float4 b2 = *(const float4*)(wp + 4);
      v[0] = a.x; v[1] = a.y; v[2] = a.z; v[3] = a.w;
      v[4] = b2.x; v[5] = b2.y; v[6] = b2.z; v[7] = b2.w;
      split8(v, wAh[wt][ks], wAl[wt][ks]);
    }

  const int bh = b * H_ + h;
  float* Tw = &T[w][0];

  for (int p = 0; p < 2; ++p) {
#pragma unroll
    for (int half8 = 0; half8 < 2; ++half8) {
      const int t = w * 4 + p * 2 + half8;
      const float* arow = atoms + ((size_t)(b * S_ + sblk) * 8 + t * 32 + lrow) * 64;
      unsigned aBh[4][4], aBl[4][4];
#pragma unroll
      for (int ks = 0; ks < 4; ++ks) {
        float v[8];
        const float4 a = *(const float4*)(arow + ks * 16 + lhi * 8);
        const float4 b2 = *(const float4*)(arow + ks * 16 + lhi * 8 + 4);
        v[0] = a.x; v[1] = a.y; v[2] = a.z; v[3] = a.w;
        v[4] = b2.x; v[5] = b2.y; v[6] = b2.z; v[7] = b2.w;
        split8(v, aBh[ks], aBl[ks]);
      }

      f32x16 y0, y1;
#pragma unroll
      for (int r = 0; r < 16; ++r) { y0[r] = 0.f; y1[r] = 0.f; }
      __builtin_amdgcn_s_setprio(1);
#pragma unroll
      for (int ks = 0; ks < 4; ++ks) {
        U4B8 a0h, a0l, a1h, a1l, bh2, bl2;
        a0h.u = make_uint4(wAh[0][ks][0], wAh[0][ks][1], wAh[0][ks][2], wAh[0][ks][3]);
        a0l.u = make_uint4(wAl[0][ks][0], wAl[0][ks][1], wAl[0][ks][2], wAl[0][ks][3]);
        a1h.u = make_uint4(wAh[1][ks][0], wAh[1][ks][1], wAh[1][ks][2], wAh[1][ks][3]);
        a1l.u = make_uint4(wAl[1][ks][0], wAl[1][ks][1], wAl[1][ks][2], wAl[1][ks][3]);
        bh2.u = make_uint4(aBh[ks][0], aBh[ks][1], aBh[ks][2], aBh[ks][3]);
        bl2.u = make_uint4(aBl[ks][0], aBl[ks][1], aBl[ks][2], aBl[ks][3]);
        y0 = __builtin_amdgcn_mfma_f32_32x32x16_bf16(a0h.v, bh2.v, y0, 0, 0, 0);
        y1 = __builtin_amdgcn_mfma_f32_32x32x16_bf16(a1h.v, bh2.v, y1, 0, 0, 0);
        y0 = __builtin_amdgcn_mfma_f32_32x32x16_bf16(a0l.v, bh2.v, y0, 0, 0, 0);
        y1 = __builtin_amdgcn_mfma_f32_32x32x16_bf16(a1l.v, bh2.v, y1, 0, 0, 0);
        y0 = __builtin_amdgcn_mfma_f32_32x32x16_bf16(a0h.v, bl2.v, y0, 0, 0, 0);
        y1 = __builtin_amdgcn_mfma_f32_32x32x16_bf16(a1h.v, bl2.v, y1, 0, 0, 0);
      }
      __builtin_amdgcn_s_setprio(0);

      const int s_in = half8 * 4 + (lrow >> 3);
      const int m = lrow & 7;
#pragma unroll
      for (int r = 0; r < 16; ++r) {
        const int dd = (r & 3) + 8 * (r >> 2) + 4 * lhi;
        Tw[s_in * 520 + m * 64 + dd] = y0[r];
        Tw[s_in * 520 + m * 64 + dd + 32] = y1[r];
      }
    }
    const int s0 = sblk + w * 16 + p * 8;
    const int ch = s0 >> 5, half = (s0 >> 4) & 1, part2 = (s0 >> 3) & 1;
    const size_t base = (size_t)bh * 1048576 + (size_t)ch * 32768 + half * 16384;
#pragma unroll
    for (int j = 0; j < 8; ++j) {
      const int c = j * 64 + lane;
      float v[8];
#pragma unroll
      for (int s = 0; s < 8; ++s) v[s] = Tw[s * 520 + c];
      unsigned hw[4];
#pragma unroll
      for (int pq = 0; pq < 4; ++pq)
        hw[pq] = cvt_pk_bf16(v[2 * pq], v[2 * pq + 1]);
      const unsigned inner = (unsigned)(c * 32 + part2 * 16);
      *(uint4*)(vthi + base + inner) = make_uint4(hw[0], hw[1], hw[2], hw[3]);
    }
  }
}

// ---------------------------------------------------------------------------
// MFMA flash attention, bounded-score softmax, P-pipeline, hi-only V,
// 2-term scores. 512 blocks x 256 threads; producer wave = phys-bit mix.
// ---------------------------------------------------------------------------
__global__ __launch_bounds__(256, 2) void k_flash(
    const unsigned short* __restrict__ qrh,
    const char* __restrict__ krh, const char* __restrict__ krl,
    const char* __restrict__ vthi,
    float* __restrict__ ao)
{
  __shared__ __align__(16) char Ksm[32768];
  __shared__ __align__(16) char PAsm[2][4096];
  __shared__ float Slinv[32];

  char* Khi0 = Ksm;
  char* Klo0 = Ksm + 8192;
  char* Khi1 = Ksm + 16384;
  char* Klo1 = Ksm + 24576;

  const int tid = threadIdx.x;
  const int w = tid >> 6, lane = tid & 63;
  const int lrow = lane & 31, lhi = lane >> 5;

  const int phys = blockIdx.x;
  const int x = phys & 7, j = phys >> 3;          // x = XCD
  const int bh = (x << 1) | (j >> 5);             // 2 bh per XCD
  const int qb = j & 31;
  const int b = bh >> 3, h = bh & 7;
  const int qbase = qb * 32;
  const int pw = (phys ^ (phys >> 2) ^ (phys >> 8)) & 3;  // stagger incl. co-resident
  const bool prod = (w == pw);

  // Q fragments (hi only): producer only
  uint4 qfh[8];
  if (prod) {
    const size_t rowb = ((size_t)bh * S_ + qbase + lrow) * 128;
#pragma unroll
    for (int fs = 0; fs < 8; ++fs)
      qfh[fs] = *(const uint4*)(qrh + rowb + fs * 16 + lhi * 8);
  }

  const char* vh_c = vthi + (size_t)bh * 1048576;
  const char* kh_c = krh + (size_t)bh * 262144;
  const char* kl_c = krl + (size_t)bh * 262144;

  auto issue_k = [&](int ch) {                    // dst buf = ch&1
    char* dh = (ch & 1) ? Khi1 : Khi0;
    char* dl = (ch & 1) ? Klo1 : Klo0;
    const size_t g = (size_t)ch * 8192;
#pragma unroll
    for (int i = 0; i < 2; ++i) {
      __builtin_amdgcn_global_load_lds(kh_c + g + i * 4096 + tid * 16, dh + i * 4096 + (w << 10), 16, 0, 0);
      __builtin_amdgcn_global_load_lds(kl_c + g + i * 4096 + tid * 16, dl + i * 4096 + (w << 10), 16, 0, 0);
    }
  };

  const unsigned vbase = (unsigned)((w * 128 + lrow) * 32 + lhi * 16);
  uint4 vAh[4], vBh[4];
  auto load_vA = [&](int ch) {
    const size_t g = (size_t)ch * 32768 + vbase;
#pragma unroll
    for (int cf = 0; cf < 4; ++cf)
      vAh[cf] = *(const uint4*)(vh_c + g + cf * 1024);
  };
  auto load_vB = [&](int ch) {
    const size_t g = (size_t)ch * 32768 + 16384 + vbase;
#pragma unroll
    for (int cf = 0; cf < 4; ++cf)
      vBh[cf] = *(const uint4*)(vh_c + g + cf * 1024);
  };

  f32x16 acc[4];
#pragma unroll
  for (int i = 0; i < 4; ++i)
#pragma unroll
    for (int r = 0; r < 16; ++r) acc[i][r] = 0.f;
  float l_run = 0.f;

  // Producer: scores(chp) = (Kh+Kl)·Qh from K buf chp&1; P = exp(s).
  auto produce = [&](int chp) {
    const char* kh = (chp & 1) ? Khi1 : Khi0;
    const char* kl = (chp & 1) ? Klo1 : Klo0;
    f32x16 s0, s1;
#pragma unroll
    for (int r = 0; r < 16; ++r) { s0[r] = 0.f; s1[r] = 0.f; }
    __builtin_amdgcn_s_setprio(1);
#pragma unroll
    for (int fs = 0; fs < 8; ++fs) {
      const unsigned kaddr = (unsigned)((lrow * 256 + fs * 32 + lhi * 16) ^ ((lrow & 7) << 4));
      U4B8 khf, klf, qh;
      khf.u = *(const uint4*)(kh + kaddr);
      klf.u = *(const uint4*)(kl + kaddr);
      qh.u = qfh[fs];
      if (fs & 1) {
        s1 = __builtin_amdgcn_mfma_f32_32x32x16_bf16(khf.v, qh.v, s1, 0, 0, 0);
        s1 = __builtin_amdgcn_mfma_f32_32x32x16_bf16(klf.v, qh.v, s1, 0, 0, 0);
      } else {
        s0 = __builtin_amdgcn_mfma_f32_32x32x16_bf16(khf.v, qh.v, s0, 0, 0, 0);
        s0 = __builtin_amdgcn_mfma_f32_32x32x16_bf16(klf.v, qh.v, s0, 0, 0, 0);
      }
    }
    __builtin_amdgcn_s_setprio(0);
    float p[16];
#pragma unroll
    for (int r = 0; r < 16; ++r) p[r] = __expf(s0[r] + s1[r]);
    float rs = 0.f;
#pragma unroll
    for (int r = 0; r < 16; ++r) rs += p[r];
    rs += __shfl_xor(rs, 32);
    l_run += rs;

    unsigned wh[8], wl[8];
#pragma unroll
    for (int i = 0; i < 8; ++i) {
      const float a = p[2 * i], c2 = p[2 * i + 1];
      const unsigned hword = cvt_pk_bf16(a, c2);
      const float ra = a - __uint_as_float(hword << 16);
      const float rc = c2 - __uint_as_float(hword & 0xffff0000u);
      wh[i] = hword;
      wl[i] = cvt_pk_bf16(ra, rc);
    }
    auto mix = [&](unsigned &lo_w, unsigned &hi_w) {
      const unsigned t = lhi ? lo_w : hi_w;
      const unsigned r = (unsigned)__shfl_xor((int)t, 32);
      lo_w = lhi ? r : lo_w;
      hi_w = lhi ? hi_w : r;
    };
    mix(wh[0], wh[2]); mix(wh[1], wh[3]); mix(wh[4], wh[6]); mix(wh[5], wh[7]);
    mix(wl[0], wl[2]); mix(wl[1], wl[3]); mix(wl[4], wl[6]); mix(wl[5], wl[7]);

    char* pb = &PAsm[chp & 1][0];
    *(uint4*)(pb + 0 * 1024 + lane * 16) = make_uint4(wh[0], wh[1], wh[2], wh[3]);
    *(uint4*)(pb + 1 * 1024 + lane * 16) = make_uint4(wh[4], wh[5], wh[6], wh[7]);
    *(uint4*)(pb + 2 * 1024 + lane * 16) = make_uint4(wl[0], wl[1], wl[2], wl[3]);
    *(uint4*)(pb + 3 * 1024 + lane * 16) = make_uint4(wl[4], wl[5], wl[6], wl[7]);
  };

  // ---- prologue ----
  issue_k(0);                        // 4
  issue_k(1);                        // 4
  load_vA(0);                        // 4
  load_vB(0);                        // 4
  asm volatile("s_waitcnt vmcnt(12)" ::: "memory");   // K(0) landed
  SBAR(); MEMFENCE();
  if (prod) produce(0);
  asm volatile("s_waitcnt lgkmcnt(0)" ::: "memory");
  SCHED0(); SBAR(); MEMFENCE();      // P(0) visible
  asm volatile("s_waitcnt vmcnt(8)" ::: "memory");    // K(1) landed

  for (int ch = 0; ch < 32; ++ch) {
    if (ch < 30) { SCHED0(); issue_k(ch + 2); SCHED0(); }

    if (prod && ch < 31) produce(ch + 1);

    // ---- all waves: PV(ch) from PAsm[ch&1], hi-V only ----
    U4B8 pah0, pah1, pal0, pal1;
    {
      const char* pb = &PAsm[ch & 1][0];
      pah0.u = *(const uint4*)(pb + 0 * 1024 + lane * 16);
      pah1.u = *(const uint4*)(pb + 1 * 1024 + lane * 16);
      pal0.u = *(const uint4*)(pb + 2 * 1024 + lane * 16);
      pal1.u = *(const uint4*)(pb + 3 * 1024 + lane * 16);
    }

    __builtin_amdgcn_s_setprio(1);
#pragma unroll
    for (int cf = 0; cf < 4; ++cf) {
      U4B8 vh;
      vh.u = vAh[cf];
      acc[cf] = __builtin_amdgcn_mfma_f32_32x32x16_bf16(pah0.v, vh.v, acc[cf], 0, 0, 0);
      acc[cf] = __builtin_amdgcn_mfma_f32_32x32x16_bf16(pal0.v, vh.v, acc[cf], 0, 0, 0);
    }
    __builtin_amdgcn_s_setprio(0);
    if (ch < 31) load_vA(ch + 1);

    __builtin_amdgcn_s_setprio(1);
#pragma unroll
    for (int cf = 0; cf < 4; ++cf) {
      U4B8 vh;
      vh.u = vBh[cf];
      acc[cf] = __builtin_amdgcn_mfma_f32_32x32x16_bf16(pah1.v, vh.v, acc[cf], 0, 0, 0);
      acc[cf] = __builtin_amdgcn_mfma_f32_32x32x16_bf16(pal1.v, vh.v, acc[cf], 0, 0, 0);
    }
    __builtin_amdgcn_s_setprio(0);

    if (ch < 31) {
      load_vB(ch + 1);
      // outstanding: K(ch+2)4 oldest + vA4 + vB4 -> drain K only
      SCHED0();
      asm volatile("s_waitcnt vmcnt(8)" ::: "memory");
      asm volatile("s_waitcnt lgkmcnt(0)" ::: "memory");
      SBAR(); MEMFENCE();
    }
  }

  // ---- epilogue ----
  if (prod && lane < 32) Slinv[lrow] = 1.0f / l_run;
  asm volatile("s_waitcnt lgkmcnt(0)" ::: "memory");
  SBAR(); MEMFENCE();
  float lr[16];
#pragma unroll
  for (int r = 0; r < 16; ++r)
    lr[r] = Slinv[(r & 3) + 8 * (r >> 2) + 4 * lhi];
#pragma unroll
  for (int cf = 0; cf < 4; ++cf) {
    const int c = w * 128 + cf * 32 + lrow;
    const int m = c >> 6, dd = c & 63;
#pragma unroll
    for (int r = 0; r < 16; ++r) {
      const int qr = (r & 3) + 8 * (r >> 2) + 4 * lhi;
      const int srow = qbase + qr;
      const size_t off = (((size_t)(b * S_ + srow)) * 8 + m) * 512 + h * 64 + dd;
      ao[off] = acc[cf][r] * lr[r];
    }
  }
}

// ---------------------------------------------------------------------------
// k_out MFMA (unchanged from R10).
// ---------------------------------------------------------------------------
__global__ __launch_bounds__(256) void k_out(
    const float* __restrict__ ao, const float* __restrict__ Wo,
    const float* __restrict__ Ww, const float* __restrict__ qlw,
    float* __restrict__ out)
{
  const int tid = threadIdx.x;
  const int w = tid >> 6, lane = tid & 63;
  const int lrow = lane & 31, lhi = lane >> 5;
  const int Rblk = blockIdx.x * 128;

  __shared__ __align__(16) char WoF[4][2][2][1024];
  __shared__ __align__(16) float Os[128 * 68];

  f32x16 acc[2];
#pragma unroll
  for (int i = 0; i < 2; ++i)
#pragma unroll
    for (int r = 0; r < 16; ++r) acc[i][r] = 0.f;

  const float* brow = ao + (size_t)(Rblk + w * 32 + lrow) * 512;

  for (int chunk = 0; chunk < 8; ++chunk) {
    __syncthreads();
#pragma unroll
    for (int dt = 0; dt < 2; ++dt) {
      const float* wp = Wo + (size_t)(dt * 32 + lrow) * 512 + (chunk * 4 + w) * 16 + lhi * 8;
      float v[8];
      const float4 a = *(const float4*)wp;
      const float4 b2 = *(const float4*)(wp + 4);
      v[0] = a.x; v[1] = a.y; v[2] = a.z; v[3] = a.w;
      v[4] = b2.x; v[5] = b2.y; v[6] = b2.z; v[7] = b2.w;
      unsigned hw[4], lw2[4];
      split8(v, hw, lw2);
      *(uint4*)&WoF[w][dt][0][lane * 16] = make_uint4(hw[0], hw[1], hw[2], hw[3]);
      *(uint4*)&WoF[w][dt][1][lane * 16] = make_uint4(lw2[0], lw2[1], lw2[2], lw2[3]);
    }
    __syncthreads();

#pragma unroll
    for (int kl = 0; kl < 4; ++kl) {
      float v[8];
      const float4 a = *(const float4*)(brow + (chunk * 4 + kl) * 16 + lhi * 8);
      const float4 b2 = *(const float4*)(brow + (chunk * 4 + kl) * 16 + lhi * 8 + 4);
      v[0] = a.x; v[1] = a.y; v[2] = a.z; v[3] = a.w;
      v[4] = b2.x; v[5] = b2.y; v[6] = b2.z; v[7] = b2.w;
      unsigned bhw[4], blw[4];
      split8(v, bhw, blw);
      U4B8 bh2, bl2;
      bh2.u = make_uint4(bhw[0], bhw[1], bhw[2], bhw[3]);
      bl2.u = make_uint4(blw[0], blw[1], blw[2], blw[3]);
      __builtin_amdgcn_s_setprio(1);
#pragma unroll
      for (int dt = 0; dt < 2; ++dt) {
        U4B8 ah, al;
        ah.u = *(const uint4*)&WoF[kl][dt][0][lane * 16];
        al.u = *(const uint4*)&WoF[kl][dt][1][lane * 16];
        acc[dt] = __builtin_amdgcn_mfma_f32_32x32x16_bf16(ah.v, bh2.v, acc[dt], 0, 0, 0);
        acc[dt] = __builtin_amdgcn_mfma_f32_32x32x16_bf16(al.v, bh2.v, acc[dt], 0, 0, 0);
        acc[dt] = __builtin_amdgcn_mfma_f32_32x32x16_bf16(ah.v, bl2.v, acc[dt], 0, 0, 0);
      }
      __builtin_amdgcn_s_setprio(0);
    }
  }

  __syncthreads();
#pragma unroll
  for (int dt = 0; dt < 2; ++dt)
#pragma unroll
    for (int r = 0; r < 16; ++r) {
      const int d = dt * 32 + (r & 3) + 8 * (r >> 2) + 4 * lhi;
      Os[(w * 32 + lrow) * 68 + d] = acc[dt][r];
    }
  __syncthreads();

#pragma unroll
  for (int jj = 0; jj < 8; ++jj) {
    const int i = tid + 256 * jj;
    const int r = i >> 4, c4 = (i & 15) * 4;
    const float4 v = *(const float4*)&Os[r * 68 + c4];
    *(float4*)&out[(size_t)(Rblk + r) * 64 + c4] = v;
  }

#pragma unroll
  for (int gi = 0; gi < 4; ++gi) {
    const int g = w * 4 + gi;
    float mean = 0.f;
#pragma unroll
    for (int m = 0; m < 8; ++m) mean += Os[(g * 8 + m) * 68 + lane];
    mean *= 0.125f;
    float dsel = 0.f;
#pragma unroll
    for (int mw = 0; mw < 8; ++mw) {
      float part = mean * Ww[mw * 64 + lane];
      part += __shfl_xor(part, 1);
      part += __shfl_xor(part, 2);
      part += __shfl_xor(part, 4);
      part += __shfl_xor(part, 8);
      part += __shfl_xor(part, 16);
      part += __shfl_xor(part, 32);
      if (lane == mw) dsel = part;
    }
    if (lane < 8) {
      const int idx = Rblk + g * 8 + lane;
      out[1048576 + idx] = qlw[idx] + dsel;
    }
  }
}

// ---------------------------------------------------------------------------
extern "C" void kernel_launch(void* const* d_in, const int* in_sizes, int n_in,
                              void* d_out, int out_size, void* d_ws, size_t ws_size,
                              hipStream_t stream)
{
  const float* q_atoms = (const float*)d_in[0];
  const float* q_logw  = (const float*)d_in[1];
  const float* k_atoms = (const float*)d_in[2];
  const float* k_logw  = (const float*)d_in[3];
  const float* v_atoms = (const float*)d_in[4];
  const float* cosT  = (const float*)d_in[6];
  const float* sinT  = (const float*)d_in[7];
  const float* Wq    = (const float*)d_in[8];
  const float* Wk    = (const float*)d_in[9];
  const float* Wv    = (const float*)d_in[10];
  const float* Wo    = (const float*)d_in[11];
  const float* Ww    = (const float*)d_in[12];
  const float* logbw = (const float*)d_in[13];
  const float* rffb  = (const float*)d_in[14];
  float* out = (float*)d_out;

  char* wsb = (char*)d_ws;
  char* qrh = wsb;
  char* qrl = wsb + (4u << 20);
  char* krh = wsb + (8u << 20);
  char* krl = wsb + (12u << 20);
  char* vthi = wsb + (16u << 20);
  float* ao = (float*)(wsb + (48u << 20));

  const dim3 blk(256);
  k_proj_rff<<<dim3(16, 8, 4), blk, 0, stream>>>(q_atoms, q_logw, k_atoms, k_logw,
                                                 Wq, Wk, rffb, logbw, cosT, sinT,
                                                 qrh, qrl, krh, krl);
  k_proj_v  <<<dim3(16, 8, 2), blk, 0, stream>>>(v_atoms, Wv, vthi);
  k_flash   <<<dim3(512), blk, 0, stream>>>((const unsigned short*)qrh,
                                            krh, krl, vthi, ao);
  k_out     <<<dim3(128), blk, 0, stream>>>(ao, Wo, Ww, q_logw, out);
}